// Round 5
// baseline (2748.432 us; speedup 1.0000x reference)
//
#include <hip/hip_runtime.h>

typedef __attribute__((ext_vector_type(8))) short short8;
typedef __attribute__((ext_vector_type(4))) float f32x4;
typedef __attribute__((ext_vector_type(8))) unsigned short u16x8;
typedef unsigned short u16;

#define V_SIZE 32000
#define D_MODEL 1024
#define HFF 4096
#define NHEAD 16
#define HDIM 64
#define NLAYER 4
#define BT 4096   // B*T tokens
#define TSEQ 2048
#define QKV_STRIDE 3072
#define GU_STRIDE 8192

__device__ __forceinline__ u16 f2bf(float f) {
  union { float f; unsigned u; } v; v.f = f;
  unsigned r = v.u + 0x7fffu + ((v.u >> 16) & 1u);
  return (u16)(r >> 16);
}
__device__ __forceinline__ float bf2f(u16 h) {
  union { unsigned u; float f; } v; v.u = ((unsigned)h) << 16;
  return v.f;
}

__device__ __forceinline__ void gload_lds16(const void* g, void* l) {
  __builtin_amdgcn_global_load_lds((__attribute__((address_space(1))) void*)g,
                                   (__attribute__((address_space(3))) void*)l, 16, 0, 0);
}

// ---------------- elementwise / small kernels ----------------

__global__ void rope_table_kernel(float* __restrict__ cosb, float* __restrict__ sinb) {
  int i = blockIdx.x * 256 + threadIdx.x;       // 2048*32 = 65536 items
  int t = i >> 5, fi = i & 31;
  float freq = exp2f(-(2.0f * (float)fi / 64.0f) * log2f(10000.0f));
  float ang = (float)t * freq;
  cosb[i] = cosf(ang);
  sinb[i] = sinf(ang);
}

__global__ void convert_bf16_kernel(const float* __restrict__ src, u16* __restrict__ dst, long n8) {
  long i = (long)blockIdx.x * 256 + threadIdx.x;
  long stride = (long)gridDim.x * 256;
  for (; i < n8; i += stride) {
    const float4* s = (const float4*)(src + i * 8);
    float4 a = s[0], b = s[1];
    u16x8 r;
    r[0] = f2bf(a.x); r[1] = f2bf(a.y); r[2] = f2bf(a.z); r[3] = f2bf(a.w);
    r[4] = f2bf(b.x); r[5] = f2bf(b.y); r[6] = f2bf(b.z); r[7] = f2bf(b.w);
    *(u16x8*)(dst + i * 8) = r;
  }
}

// src [R][C] fp32 -> dst bf16 at dst[(c*rowMul+rowAdd)*R + r], batched over blockIdx.z
__global__ __launch_bounds__(256) void transpose_bf16_kernel(const float* __restrict__ src0,
                                                             u16* __restrict__ dst0, int R, int C,
                                                             long srcStride, long dstStride,
                                                             int rowMul, int rowAdd) {
  __shared__ float tile[32][33];
  const float* src = src0 + (size_t)blockIdx.z * srcStride;
  u16* dst = dst0 + (size_t)blockIdx.z * dstStride;
  int tx = threadIdx.x & 31, ty = threadIdx.x >> 5;  // 32 x 8
  int bx = blockIdx.x, by = blockIdx.y;
#pragma unroll
  for (int i = 0; i < 32; i += 8) {
    int r = by * 32 + ty + i, c = bx * 32 + tx;
    tile[ty + i][tx] = src[(size_t)r * C + c];
  }
  __syncthreads();
#pragma unroll
  for (int i = 0; i < 32; i += 8) {
    int c = bx * 32 + ty + i;   // dst logical row (source col)
    int r = by * 32 + tx;       // dst col (source row)
    dst[(size_t)(c * rowMul + rowAdd) * R + r] = f2bf(tile[tx][ty + i]);
  }
}

__global__ void embed_gather_kernel(const int* __restrict__ idx, const float* __restrict__ embed,
                                    float* __restrict__ x) {
  int t = blockIdx.x;
  int id = idx[t];
  ((float4*)x)[(size_t)t * 256 + threadIdx.x] = ((const float4*)embed)[(size_t)id * 256 + threadIdx.x];
}

// x fp32 [4096][1024] -> h bf16, h = x * rsqrt(mean(x^2)+eps) * w
__global__ __launch_bounds__(256) void rmsnorm_kernel(const float* __restrict__ x,
                                                      const float* __restrict__ w,
                                                      u16* __restrict__ h) {
  int row = blockIdx.x;
  const float4* xr = (const float4*)(x + (size_t)row * D_MODEL);
  float4 v = xr[threadIdx.x];
  float ss = v.x * v.x + v.y * v.y + v.z * v.z + v.w * v.w;
#pragma unroll
  for (int m = 32; m > 0; m >>= 1) ss += __shfl_xor(ss, m, 64);
  __shared__ float wsum[4];
  if ((threadIdx.x & 63) == 0) wsum[threadIdx.x >> 6] = ss;
  __syncthreads();
  float tot = wsum[0] + wsum[1] + wsum[2] + wsum[3];
  float rinv = rsqrtf(tot * (1.0f / (float)D_MODEL) + 1e-6f);
  float4 wv = ((const float4*)w)[threadIdx.x];
  u16 out[4];
  out[0] = f2bf(v.x * rinv * wv.x);
  out[1] = f2bf(v.y * rinv * wv.y);
  out[2] = f2bf(v.z * rinv * wv.z);
  out[3] = f2bf(v.w * rinv * wv.w);
  u16* hp = h + (size_t)row * D_MODEL + threadIdx.x * 4;
  hp[0] = out[0]; hp[1] = out[1]; hp[2] = out[2]; hp[3] = out[3];
}

// ---------------- GEMM 256x256, BK=64, deep-lead 8-phase (T2+T3+T4+T5) ----------------
// C[M,N] = A[M,K](bf16) * B[N,K](bf16)^T. 512 threads = 8 waves (2M x 4N).
// LDS 128 KiB: 2 K-tile buffers x (A[256x64] + B[256x64]), chunk^(row&7) swizzle
// (0 conflicts measured R3). Tile t+2 is staged into buf[t&1] DURING tile t
// (B-halves at P3, A-halves at P4 — after that region's last read), so the
// steady-state wait is vmcnt(8) with 5-8 phases of lead (> HBM latency).
// Quadrant order per tile: (m0n0, m0n1, m1n1, m1n0); every ds_read is consumed
// by MFMA in its own phase, so reads complete before the phase-end barrier.
// EPI: 0 = fp32 store + per-(row,64col) LSE partials; 1 = bf16 store;
//      3 = silu-mul pairing (B rows interleaved gate/up), bf16 store at N/2 width.
template <int EPI>
__global__ __launch_bounds__(512, 2) void gemm256_kernel(const u16* __restrict__ A,
                                                         const u16* __restrict__ B, void* Cp,
                                                         float* __restrict__ partM,
                                                         float* __restrict__ partS,
                                                         int M, int N, int K) {
  __shared__ u16 As[2][256 * 64];
  __shared__ u16 Bs[2][256 * 64];
  const int tid = threadIdx.x;
  const int lane = tid & 63, wid = tid >> 6;
  const int wm = wid >> 2, wn = wid & 3;          // 2 x 4 wave grid
  const int q = lane >> 4, l15 = lane & 15;
  const int nbn = N >> 8;
  const int cpx = (int)gridDim.x >> 3;
  const int swz = ((int)blockIdx.x & 7) * cpx + ((int)blockIdx.x >> 3);
  const int bm = swz / nbn, bn = swz % nbn;
  const u16* Ab = A + (size_t)bm * 256 * K;
  const u16* Bb = B + (size_t)bn * 256 * K;

  // stage half h (rows h*128..+127) of tile t's operand; 2 gload_lds per call.
  auto stA = [&](int t, int h) {
    const int buf = t & 1, k0 = t << 6;
#pragma unroll
    for (int rnd = 0; rnd < 2; rnd++) {
      int idx = ((h << 1) + rnd) * 512 + tid;   // 16B-chunk index, linear dest
      int row = idx >> 3, ch = idx & 7;
      int sc = (ch ^ (row & 7)) << 3;           // pre-swizzled source col
      gload_lds16(Ab + (size_t)row * K + k0 + sc, &As[buf][idx * 8]);
    }
  };
  auto stB = [&](int t, int h) {
    const int buf = t & 1, k0 = t << 6;
#pragma unroll
    for (int rnd = 0; rnd < 2; rnd++) {
      int idx = ((h << 1) + rnd) * 512 + tid;
      int row = idx >> 3, ch = idx & 7;
      int sc = (ch ^ (row & 7)) << 3;
      gload_lds16(Bb + (size_t)row * K + k0 + sc, &Bs[buf][idx * 8]);
    }
  };

  f32x4 acc[8][4] = {};
  short8 af[4][2], bf0[2][2], bf1[2][2];
  const int NT = K >> 6;   // >= 3 at all call sites (K=1024 -> 16)

  // prologue: tiles 0 and 1 fully staged; wait tile 0 resident (8 left in flight)
  stA(0, 0); stA(0, 1); stB(0, 0); stB(0, 1);
  stA(1, 0); stA(1, 1); stB(1, 0); stB(1, 1);
  asm volatile("s_waitcnt vmcnt(8)" ::: "memory");
  __builtin_amdgcn_s_barrier();

  for (int kt = 0; kt < NT; kt++) {
    const u16* LA = &As[kt & 1][0];
    const u16* LB = &Bs[kt & 1][0];
    // ---- P1: read af0 (m-half0) + bf0 (n-quad 0-1); MFMA m0 x n0
#pragma unroll
    for (int mi = 0; mi < 4; mi++) {
      int row = wm * 128 + mi * 16 + l15;
#pragma unroll
      for (int ks = 0; ks < 2; ks++)
        af[mi][ks] = *(const short8*)&LA[row * 64 + (((ks * 4 + q) ^ (row & 7)) << 3)];
    }
#pragma unroll
    for (int ni = 0; ni < 2; ni++) {
      int row = wn * 64 + ni * 16 + l15;
#pragma unroll
      for (int ks = 0; ks < 2; ks++)
        bf0[ni][ks] = *(const short8*)&LB[row * 64 + (((ks * 4 + q) ^ (row & 7)) << 3)];
    }
    __builtin_amdgcn_s_barrier();
    __builtin_amdgcn_s_setprio(1);
#pragma unroll
    for (int mi = 0; mi < 4; mi++)
#pragma unroll
      for (int ni = 0; ni < 2; ni++)
#pragma unroll
        for (int ks = 0; ks < 2; ks++)
          acc[mi][ni] = __builtin_amdgcn_mfma_f32_16x16x32_bf16(af[mi][ks], bf0[ni][ks], acc[mi][ni], 0, 0, 0);
    __builtin_amdgcn_s_setprio(0);
    __builtin_amdgcn_s_barrier();
    // ---- P2: read bf1 (n-quad 2-3); MFMA m0 x n1  (B-region reads complete here)
#pragma unroll
    for (int ni = 0; ni < 2; ni++) {
      int row = wn * 64 + (ni + 2) * 16 + l15;
#pragma unroll
      for (int ks = 0; ks < 2; ks++)
        bf1[ni][ks] = *(const short8*)&LB[row * 64 + (((ks * 4 + q) ^ (row & 7)) << 3)];
    }
    __builtin_amdgcn_s_barrier();
    __builtin_amdgcn_s_setprio(1);
#pragma unroll
    for (int mi = 0; mi < 4; mi++)
#pragma unroll
      for (int ni = 0; ni < 2; ni++)
#pragma unroll
        for (int ks = 0; ks < 2; ks++)
          acc[mi][ni + 2] = __builtin_amdgcn_mfma_f32_16x16x32_bf16(af[mi][ks], bf1[ni][ks], acc[mi][ni + 2], 0, 0, 0);
    __builtin_amdgcn_s_setprio(0);
    __builtin_amdgcn_s_barrier();
    // ---- P3: issue B(t+2) into this buf (B-region free); read af1; MFMA m1 x n1
    if (kt + 2 < NT) { stB(kt + 2, 0); stB(kt + 2, 1); }
#pragma unroll
    for (int mi = 0; mi < 4; mi++) {
      int row = wm * 128 + (mi + 4) * 16 + l15;
#pragma unroll
      for (int ks = 0; ks < 2; ks++)
        af[mi][ks] = *(const short8*)&LA[row * 64 + (((ks * 4 + q) ^ (row & 7)) << 3)];
    }
    __builtin_amdgcn_s_barrier();
    __builtin_amdgcn_s_setprio(1);
#pragma unroll
    for (int mi = 0; mi < 4; mi++)
#pragma unroll
      for (int ni = 0; ni < 2; ni++)
#pragma unroll
        for (int ks = 0; ks < 2; ks++)
          acc[mi + 4][ni + 2] = __builtin_amdgcn_mfma_f32_16x16x32_bf16(af[mi][ks], bf1[ni][ks], acc[mi + 4][ni + 2], 0, 0, 0);
    __builtin_amdgcn_s_setprio(0);
    __builtin_amdgcn_s_barrier();
    // ---- P4: issue A(t+2) (A-region free); MFMA m1 x n0; counted wait; barrier
    if (kt + 2 < NT) { stA(kt + 2, 0); stA(kt + 2, 1); }
    __builtin_amdgcn_s_setprio(1);
#pragma unroll
    for (int mi = 0; mi < 4; mi++)
#pragma unroll
      for (int ni = 0; ni < 2; ni++)
#pragma unroll
        for (int ks = 0; ks < 2; ks++)
          acc[mi + 4][ni] = __builtin_amdgcn_mfma_f32_16x16x32_bf16(af[mi][ks], bf0[ni][ks], acc[mi + 4][ni], 0, 0, 0);
    __builtin_amdgcn_s_setprio(0);
    if (kt + 1 < NT) {
      if (kt + 2 < NT) asm volatile("s_waitcnt vmcnt(8)" ::: "memory");
      else             asm volatile("s_waitcnt vmcnt(0)" ::: "memory");
    }
    __builtin_amdgcn_s_barrier();
  }

  // epilogue
  const int row0 = bm * 256 + wm * 128;
  const int col0 = bn * 256 + wn * 64;
#pragma unroll
  for (int mi = 0; mi < 8; mi++)
#pragma unroll
    for (int j = 0; j < 4; j++) {
      int rr = row0 + mi * 16 + q * 4 + j;
      if (EPI == 0) {
        float mx = -1e30f;
#pragma unroll
        for (int ni = 0; ni < 4; ni++) mx = fmaxf(mx, acc[mi][ni][j]);
        mx = fmaxf(mx, __shfl_xor(mx, 1, 64));
        mx = fmaxf(mx, __shfl_xor(mx, 2, 64));
        mx = fmaxf(mx, __shfl_xor(mx, 4, 64));
        mx = fmaxf(mx, __shfl_xor(mx, 8, 64));
        float sm = 0.f;
#pragma unroll
        for (int ni = 0; ni < 4; ni++) sm += expf(acc[mi][ni][j] - mx);
        sm += __shfl_xor(sm, 1, 64);
        sm += __shfl_xor(sm, 2, 64);
        sm += __shfl_xor(sm, 4, 64);
        sm += __shfl_xor(sm, 8, 64);
        if (l15 == 0) {
          int nt = (N >> 6);
          partM[(size_t)rr * nt + (bn << 2) + wn] = mx;
          partS[(size_t)rr * nt + (bn << 2) + wn] = sm;
        }
      }
#pragma unroll
      for (int ni = 0; ni < 4; ni++) {
        int cn = col0 + ni * 16 + l15;
        float vv = acc[mi][ni][j];
        if (EPI == 0) {
          ((float*)Cp)[(size_t)rr * N + cn] = vv;
        } else if (EPI == 1) {
          ((u16*)Cp)[(size_t)rr * N + cn] = f2bf(vv);
        } else if (EPI == 3) {
          float other = __shfl_xor(vv, 1, 64);
          if ((l15 & 1) == 0) {
            float g = vv, u = other;
            float r = g / (1.0f + expf(-g)) * u;
            ((u16*)Cp)[(size_t)rr * (N >> 1) + (cn >> 1)] = f2bf(r);
          }
        }
      }
    }
}

// ---------------- GEMM 128x128 (m97 structure + both-sides swizzle) ----------------
// EPI: 2 = fp32 residual add (C = resid + acc)
template <int EPI>
__global__ __launch_bounds__(256, 2) void gemm_nt_kernel(const u16* __restrict__ A,
                                                         const u16* __restrict__ B, void* Cp,
                                                         const float* resid, int M, int N, int K) {
  __shared__ u16 As[128 * 64];
  __shared__ u16 Bs[128 * 64];
  const int tid = threadIdx.x;
  const int lane = tid & 63, wid = tid >> 6;
  const int wr = wid >> 1, wc = wid & 1;
  const int nbx = N >> 7;
  const int cpx = gridDim.x >> 3;
  const int swz = (blockIdx.x & 7) * cpx + (blockIdx.x >> 3);
  const int bm = swz / nbx, bn = swz - bm * nbx;
  const size_t abase = (size_t)bm * 128 * K;
  const size_t bbase = (size_t)bn * 128 * K;
  f32x4 acc[4][4] = {};
  for (int k0 = 0; k0 < K; k0 += 64) {
#pragma unroll
    for (int i = 0; i < 4; i++) {
      int idx8 = i * 256 + tid;
      int row = idx8 >> 3, ch = idx8 & 7;
      int sc = (ch ^ (row & 7)) << 3;
      gload_lds16(A + abase + (size_t)row * K + k0 + sc, As + idx8 * 8);
      gload_lds16(B + bbase + (size_t)row * K + k0 + sc, Bs + idx8 * 8);
    }
    __syncthreads();
#pragma unroll
    for (int ks = 0; ks < 2; ks++) {
      short8 af[4], bfr[4];
      int chunk = ks * 4 + (lane >> 4);
#pragma unroll
      for (int mi = 0; mi < 4; mi++) {
        int row = wr * 64 + mi * 16 + (lane & 15);
        af[mi] = *(const short8*)&As[row * 64 + ((chunk ^ (row & 7)) << 3)];
      }
#pragma unroll
      for (int ni = 0; ni < 4; ni++) {
        int row = wc * 64 + ni * 16 + (lane & 15);
        bfr[ni] = *(const short8*)&Bs[row * 64 + ((chunk ^ (row & 7)) << 3)];
      }
#pragma unroll
      for (int mi = 0; mi < 4; mi++)
#pragma unroll
        for (int ni = 0; ni < 4; ni++)
          acc[mi][ni] = __builtin_amdgcn_mfma_f32_16x16x32_bf16(af[mi], bfr[ni], acc[mi][ni], 0, 0, 0);
    }
    __syncthreads();
  }
#pragma unroll
  for (int mi = 0; mi < 4; mi++)
#pragma unroll
    for (int ni = 0; ni < 4; ni++)
#pragma unroll
      for (int j = 0; j < 4; j++) {
        int r = bm * 128 + wr * 64 + mi * 16 + (lane >> 4) * 4 + j;
        int cn = bn * 128 + wc * 64 + ni * 16 + (lane & 15);
        size_t off = (size_t)r * N + cn;
        float vv = acc[mi][ni][j];
        if (EPI == 0) ((float*)Cp)[off] = vv;
        else if (EPI == 1) ((u16*)Cp)[off] = f2bf(vv);
        else ((float*)Cp)[off] = resid[off] + vv;
      }
}

// ---------------- flash attention (RoPE fused for Q and K) ----------------
// q/k/v live in the fused QKV buffer (row stride 3072, offsets 0/1024/2048), PRE-rope.
// grid: (qtile 0..15, bh 0..31), block 256 (4 waves x 32 q-rows)
__global__ __launch_bounds__(256) void attn_kernel(const u16* __restrict__ qkv,
                                                   const float* __restrict__ cosb,
                                                   const float* __restrict__ sinb,
                                                   u16* __restrict__ o) {
  __shared__ u16 Ks[64 * 64];
  __shared__ u16 Vt[64 * 64];
  __shared__ u16 Ps[4][32 * 64];
  const u16* q = qkv;
  const u16* k = qkv + D_MODEL;
  const u16* v = qkv + 2 * D_MODEL;
  const int tid = threadIdx.x, lane = tid & 63, wid = tid >> 6;
  const int qg = lane >> 4, l15 = lane & 15;
  const int qt = blockIdx.x;
  const int bh = blockIdx.y;
  const int b = bh >> 4, h = bh & 15;
  const int tok0 = b * TSEQ;
  const int hoff = h * HDIM;
  const int qrow0 = qt * 128 + wid * 32;

  // load Q fragments and apply RoPE in-register (ks0/ks1 hold the rotation pair)
  short8 aq[2][2];
#pragma unroll
  for (int mi = 0; mi < 2; mi++) {
    int r = qrow0 + mi * 16 + l15;
#pragma unroll
    for (int ks = 0; ks < 2; ks++)
      aq[mi][ks] = *(const short8*)(q + (size_t)(tok0 + r) * QKV_STRIDE + hoff + ks * 32 + qg * 8);
#pragma unroll
    for (int j = 0; j < 8; j++) {
      int fi = qg * 8 + j;
      float cc = cosb[r * 32 + fi], ss = sinb[r * 32 + fi];
      float x1 = bf2f((u16)aq[mi][0][j]), x2 = bf2f((u16)aq[mi][1][j]);
      aq[mi][0][j] = (short)f2bf(x1 * cc - x2 * ss);
      aq[mi][1][j] = (short)f2bf(x2 * cc + x1 * ss);
    }
  }
  f32x4 oacc[2][4] = {};
  float mrow[2][4], lrow[2][4];
#pragma unroll
  for (int mi = 0; mi < 2; mi++)
#pragma unroll
    for (int j = 0; j < 4; j++) { mrow[mi][j] = -1e30f; lrow[mi][j] = 0.f; }

  const int nkt = (qt + 1) * 2;
  for (int kt = 0; kt < nkt; kt++) {
    const int kv0 = kt * 64;
    // stage K [64][64] with fused RoPE (swizzled)
    {
      int rr = tid >> 2;            // 0..63
      int cp = (tid & 3) << 3;      // 0,8,16,24
      int t = kv0 + rr;
      const u16* kr = k + (size_t)(tok0 + t) * QKV_STRIDE + hoff;
      short8 k1 = *(const short8*)(kr + cp);
      short8 k2 = *(const short8*)(kr + cp + 32);
      u16x8 o1, o2;
#pragma unroll
      for (int j = 0; j < 8; j++) {
        float cc = cosb[t * 32 + cp + j], ss = sinb[t * 32 + cp + j];
        float a = bf2f((u16)k1[j]), bb = bf2f((u16)k2[j]);
        o1[j] = f2bf(a * cc - bb * ss);
        o2[j] = f2bf(bb * cc + a * ss);
      }
      int ch1 = cp >> 3, ch2 = ch1 + 4;
      *(u16x8*)&Ks[rr * 64 + ((ch1 ^ (rr & 7)) << 3)] = o1;
      *(u16x8*)&Ks[rr * 64 + ((ch2 ^ (rr & 7)) << 3)] = o2;
    }
    // stage V^T: Vt[d][t] (swizzled)
    {
      int d = tid & 63, t4 = (tid >> 6) * 8;
#pragma unroll
      for (int half = 0; half < 2; half++) {
        int t0 = t4 + half * 32;
        short8 pk;
#pragma unroll
        for (int jj = 0; jj < 8; jj++)
          pk[jj] = (short)v[(size_t)(tok0 + kv0 + t0 + jj) * QKV_STRIDE + hoff + d];
        *(short8*)&Vt[d * 64 + (t0 ^ ((d & 7) << 3))] = pk;
      }
    }
    __syncthreads();
    f32x4 sc[2][4] = {};
#pragma unroll
    for (int ks = 0; ks < 2; ks++) {
      short8 bk[4];
      int chunk = ks * 4 + qg;
#pragma unroll
      for (int ni = 0; ni < 4; ni++) {
        int r = ni * 16 + l15;
        bk[ni] = *(const short8*)&Ks[r * 64 + ((chunk ^ (r & 7)) << 3)];
      }
#pragma unroll
      for (int mi = 0; mi < 2; mi++)
#pragma unroll
        for (int ni = 0; ni < 4; ni++)
          sc[mi][ni] = __builtin_amdgcn_mfma_f32_16x16x32_bf16(aq[mi][ks], bk[ni], sc[mi][ni], 0, 0, 0);
    }
    float pm[2][4];
#pragma unroll
    for (int mi = 0; mi < 2; mi++)
#pragma unroll
      for (int j = 0; j < 4; j++) pm[mi][j] = -1e30f;
#pragma unroll
    for (int mi = 0; mi < 2; mi++)
#pragma unroll
      for (int ni = 0; ni < 4; ni++)
#pragma unroll
        for (int j = 0; j < 4; j++) {
          int rq = qrow0 + mi * 16 + qg * 4 + j;
          int ck = kv0 + ni * 16 + l15;
          float s = sc[mi][ni][j] * 0.125f;
          if (ck > rq) s = -1e30f;
          sc[mi][ni][j] = s;
          pm[mi][j] = fmaxf(pm[mi][j], s);
        }
#pragma unroll
    for (int mi = 0; mi < 2; mi++)
#pragma unroll
      for (int j = 0; j < 4; j++) {
        float t = pm[mi][j];
        t = fmaxf(t, __shfl_xor(t, 1, 64));
        t = fmaxf(t, __shfl_xor(t, 2, 64));
        t = fmaxf(t, __shfl_xor(t, 4, 64));
        t = fmaxf(t, __shfl_xor(t, 8, 64));
        pm[mi][j] = t;
      }
#pragma unroll
    for (int mi = 0; mi < 2; mi++)
#pragma unroll
      for (int j = 0; j < 4; j++) {
        float mn = fmaxf(mrow[mi][j], pm[mi][j]);
        float fac = expf(mrow[mi][j] - mn);
        lrow[mi][j] *= fac;
#pragma unroll
        for (int df = 0; df < 4; df++) oacc[mi][df][j] *= fac;
        mrow[mi][j] = mn;
      }
    float psum[2][4] = {};
#pragma unroll
    for (int mi = 0; mi < 2; mi++)
#pragma unroll
      for (int ni = 0; ni < 4; ni++)
#pragma unroll
        for (int j = 0; j < 4; j++) {
          float p = expf(sc[mi][ni][j] - mrow[mi][j]);
          psum[mi][j] += p;
          int r32 = mi * 16 + qg * 4 + j;
          int cc = ni * 16 + l15;
          Ps[wid][r32 * 64 + (cc ^ ((r32 & 7) << 3))] = f2bf(p);
        }
#pragma unroll
    for (int mi = 0; mi < 2; mi++)
#pragma unroll
      for (int j = 0; j < 4; j++) {
        float t = psum[mi][j];
        t += __shfl_xor(t, 1, 64);
        t += __shfl_xor(t, 2, 64);
        t += __shfl_xor(t, 4, 64);
        t += __shfl_xor(t, 8, 64);
        lrow[mi][j] += t;
      }
#pragma unroll
    for (int kf = 0; kf < 2; kf++) {
      short8 pa[2], bv[4];
      int kcol = kf * 32 + qg * 8;
#pragma unroll
      for (int mi = 0; mi < 2; mi++) {
        int r = mi * 16 + l15;
        pa[mi] = *(const short8*)&Ps[wid][r * 64 + (kcol ^ ((r & 7) << 3))];
      }
#pragma unroll
      for (int df = 0; df < 4; df++) {
        int r = df * 16 + l15;
        bv[df] = *(const short8*)&Vt[r * 64 + (kcol ^ ((r & 7) << 3))];
      }
#pragma unroll
      for (int mi = 0; mi < 2; mi++)
#pragma unroll
        for (int df = 0; df < 4; df++)
          oacc[mi][df] = __builtin_amdgcn_mfma_f32_16x16x32_bf16(pa[mi], bv[df], oacc[mi][df], 0, 0, 0);
    }
    __syncthreads();
  }
#pragma unroll
  for (int mi = 0; mi < 2; mi++)
#pragma unroll
    for (int df = 0; df < 4; df++)
#pragma unroll
      for (int j = 0; j < 4; j++) {
        int r = qrow0 + mi * 16 + qg * 4 + j;
        int d = df * 16 + l15;
        float val = oacc[mi][df][j] / lrow[mi][j];
        o[(size_t)(tok0 + r) * D_MODEL + hoff + d] = f2bf(val);
      }
}

// ---------------- loss ----------------

__global__ void nll_finalize_kernel(const float* __restrict__ partM, const float* __restrict__ partS,
                                    const float* __restrict__ logits, const int* __restrict__ targets,
                                    float* __restrict__ nll) {
  int tok = blockIdx.x;
  int lane = threadIdx.x;    // 64
  const int NTL = V_SIZE >> 6;  // 500
  float m = -1e30f, s = 0.f;
  for (int i = lane; i < NTL; i += 64) {
    float m2 = partM[(size_t)tok * NTL + i];
    float s2 = partS[(size_t)tok * NTL + i];
    float nm = fmaxf(m, m2);
    s = s * expf(m - nm) + s2 * expf(m2 - nm);
    m = nm;
  }
#pragma unroll
  for (int mask = 1; mask < 64; mask <<= 1) {
    float m2 = __shfl_xor(m, mask, 64);
    float s2 = __shfl_xor(s, mask, 64);
    float nm = fmaxf(m, m2);
    s = s * expf(m - nm) + s2 * expf(m2 - nm);
    m = nm;
  }
  if (lane == 0)
    nll[tok] = m + logf(s) - logits[(size_t)tok * V_SIZE + targets[tok]];
}

__global__ void loss_reduce_kernel(const float* __restrict__ nll, float* __restrict__ out) {
  float s = 0.f;
  for (int i = threadIdx.x; i < BT; i += 256) s += nll[i];
#pragma unroll
  for (int mask = 1; mask < 64; mask <<= 1) s += __shfl_xor(s, mask, 64);
  __shared__ float sm[4];
  if ((threadIdx.x & 63) == 0) sm[threadIdx.x >> 6] = s;
  __syncthreads();
  if (threadIdx.x == 0) out[0] = (sm[0] + sm[1] + sm[2] + sm[3]) / (float)BT;
}

// ---------------- host launcher ----------------

extern "C" void kernel_launch(void* const* d_in, const int* in_sizes, int n_in,
                              void* d_out, int out_size, void* d_ws, size_t ws_size,
                              hipStream_t stream) {
  const int* idx = (const int*)d_in[0];
  const int* targets = (const int*)d_in[1];
  const float* embed = (const float*)d_in[2];
  const float* wq = (const float*)d_in[3];
  const float* wk = (const float*)d_in[4];
  const float* wv = (const float*)d_in[5];
  const float* wo = (const float*)d_in[6];
  const float* w_gate = (const float*)d_in[7];
  const float* w_up = (const float*)d_in[8];
  const float* w_down = (const float*)d_in[9];
  const float* attn_norm = (const float*)d_in[10];
  const float* mlp_norm = (const float*)d_in[11];
  const float* final_norm = (const float*)d_in[12];
  const float* lm_head = (const float*)d_in[13];
  float* out = (float*)d_out;

  char* ws = (char*)d_ws;
  size_t off = 0;
  auto alloc = [&](size_t bytes) {
    void* p = ws + off;
    off += (bytes + 255) & ~(size_t)255;
    return p;
  };
  const size_t DD = (size_t)D_MODEL * D_MODEL;
  float* rope_cos = (float*)alloc((size_t)TSEQ * 32 * 4);
  float* rope_sin = (float*)alloc((size_t)TSEQ * 32 * 4);
  float* X = (float*)alloc((size_t)BT * D_MODEL * 4);
  u16* Hb = (u16*)alloc((size_t)BT * D_MODEL * 2);
  u16* QKVb = (u16*)alloc((size_t)BT * QKV_STRIDE * 2);
  u16* Ob = (u16*)alloc((size_t)BT * D_MODEL * 2);
  u16* Gb = (u16*)alloc((size_t)BT * HFF * 2);
  u16* WQKVT = (u16*)alloc((size_t)NLAYER * QKV_STRIDE * D_MODEL * 2);
  u16* WOT = (u16*)alloc((size_t)NLAYER * DD * 2);
  u16* WGU = (u16*)alloc((size_t)NLAYER * GU_STRIDE * D_MODEL * 2);
  u16* WDT = (u16*)alloc((size_t)NLAYER * D_MODEL * HFF * 2);
  u16* LMH = (u16*)alloc((size_t)V_SIZE * D_MODEL * 2);
  float* NLLb = (float*)alloc((size_t)BT * 4);
  float* PartM = (float*)alloc((size_t)BT * (V_SIZE >> 6) * 4);
  float* PartS = (float*)alloc((size_t)BT * (V_SIZE >> 6) * 4);

  rope_table_kernel<<<256, 256, 0, stream>>>(rope_cos, rope_sin);
  convert_bf16_kernel<<<4096, 256, 0, stream>>>(lm_head, LMH, (long)V_SIZE * D_MODEL / 8);
  embed_gather_kernel<<<BT, 256, 0, stream>>>(idx, embed, X);

  const long QKVW = (long)QKV_STRIDE * D_MODEL;
  const long GUW = (long)GU_STRIDE * D_MODEL;
  const long DW = (long)D_MODEL * HFF;
  transpose_bf16_kernel<<<dim3(32, 32, NLAYER), 256, 0, stream>>>(wq, WQKVT, D_MODEL, D_MODEL, DD, QKVW, 1, 0);
  transpose_bf16_kernel<<<dim3(32, 32, NLAYER), 256, 0, stream>>>(wk, WQKVT + DD, D_MODEL, D_MODEL, DD, QKVW, 1, 0);
  transpose_bf16_kernel<<<dim3(32, 32, NLAYER), 256, 0, stream>>>(wv, WQKVT + 2 * DD, D_MODEL, D_MODEL, DD, QKVW, 1, 0);
  transpose_bf16_kernel<<<dim3(32, 32, NLAYER), 256, 0, stream>>>(wo, WOT, D_MODEL, D_MODEL, DD, DD, 1, 0);
  // gate/up interleaved: B row 2j = gate col j, row 2j+1 = up col j
  transpose_bf16_kernel<<<dim3(128, 32, NLAYER), 256, 0, stream>>>(w_gate, WGU, D_MODEL, HFF, DW, GUW, 2, 0);
  transpose_bf16_kernel<<<dim3(128, 32, NLAYER), 256, 0, stream>>>(w_up, WGU, D_MODEL, HFF, DW, GUW, 2, 1);
  transpose_bf16_kernel<<<dim3(32, 128, NLAYER), 256, 0, stream>>>(w_down, WDT, HFF, D_MODEL, DW, DW, 1, 0);

  for (int l = 0; l < NLAYER; l++) {
    rmsnorm_kernel<<<BT, 256, 0, stream>>>(X, attn_norm + (size_t)l * D_MODEL, Hb);
    gemm256_kernel<1><<<(QKV_STRIDE / 256) * (BT / 256), 512, 0, stream>>>(
        Hb, WQKVT + (size_t)l * QKVW, QKVb, nullptr, nullptr, BT, QKV_STRIDE, D_MODEL);
    attn_kernel<<<dim3(16, 32), 256, 0, stream>>>(QKVb, rope_cos, rope_sin, Ob);
    gemm_nt_kernel<2><<<(D_MODEL / 128) * (BT / 128), 256, 0, stream>>>(
        Ob, WOT + (size_t)l * DD, X, X, BT, D_MODEL, D_MODEL);

    rmsnorm_kernel<<<BT, 256, 0, stream>>>(X, mlp_norm + (size_t)l * D_MODEL, Hb);
    gemm256_kernel<3><<<(GU_STRIDE / 256) * (BT / 256), 512, 0, stream>>>(
        Hb, WGU + (size_t)l * GUW, Gb, nullptr, nullptr, BT, GU_STRIDE, D_MODEL);
    gemm_nt_kernel<2><<<(D_MODEL / 128) * (BT / 128), 256, 0, stream>>>(
        Gb, WDT + (size_t)l * DW, X, X, BT, D_MODEL, HFF);
  }

  rmsnorm_kernel<<<BT, 256, 0, stream>>>(X, final_norm, Hb);
  gemm256_kernel<0><<<(V_SIZE / 256) * (BT / 256), 512, 0, stream>>>(
      Hb, LMH, out, PartM, PartS, BT, V_SIZE, D_MODEL);
  nll_finalize_kernel<<<BT, 64, 0, stream>>>(PartM, PartS, out, targets, NLLb);
  loss_reduce_kernel<<<1, 256, 0, stream>>>(NLLb, out + (size_t)BT * V_SIZE);
}

// Round 6
// 2739.760 us; speedup vs baseline: 1.0032x; 1.0032x over previous
//
#include <hip/hip_runtime.h>

typedef __attribute__((ext_vector_type(8))) short short8;
typedef __attribute__((ext_vector_type(4))) float f32x4;
typedef __attribute__((ext_vector_type(8))) unsigned short u16x8;
typedef unsigned short u16;

#define V_SIZE 32000
#define D_MODEL 1024
#define HFF 4096
#define NHEAD 16
#define HDIM 64
#define NLAYER 4
#define BT 4096   // B*T tokens
#define TSEQ 2048
#define QKV_STRIDE 3072
#define GU_STRIDE 8192

__device__ __forceinline__ u16 f2bf(float f) {
  union { float f; unsigned u; } v; v.f = f;
  unsigned r = v.u + 0x7fffu + ((v.u >> 16) & 1u);
  return (u16)(r >> 16);
}
__device__ __forceinline__ float bf2f(u16 h) {
  union { unsigned u; float f; } v; v.u = ((unsigned)h) << 16;
  return v.f;
}

__device__ __forceinline__ void gload_lds16(const void* g, void* l) {
  __builtin_amdgcn_global_load_lds((__attribute__((address_space(1))) void*)g,
                                   (__attribute__((address_space(3))) void*)l, 16, 0, 0);
}

// ---------------- elementwise / small kernels ----------------

__global__ void rope_table_kernel(float* __restrict__ cosb, float* __restrict__ sinb) {
  int i = blockIdx.x * 256 + threadIdx.x;       // 2048*32 = 65536 items
  int t = i >> 5, fi = i & 31;
  float freq = exp2f(-(2.0f * (float)fi / 64.0f) * log2f(10000.0f));
  float ang = (float)t * freq;
  cosb[i] = cosf(ang);
  sinb[i] = sinf(ang);
}

__global__ void convert_bf16_kernel(const float* __restrict__ src, u16* __restrict__ dst, long n8) {
  long i = (long)blockIdx.x * 256 + threadIdx.x;
  long stride = (long)gridDim.x * 256;
  for (; i < n8; i += stride) {
    const float4* s = (const float4*)(src + i * 8);
    float4 a = s[0], b = s[1];
    u16x8 r;
    r[0] = f2bf(a.x); r[1] = f2bf(a.y); r[2] = f2bf(a.z); r[3] = f2bf(a.w);
    r[4] = f2bf(b.x); r[5] = f2bf(b.y); r[6] = f2bf(b.z); r[7] = f2bf(b.w);
    *(u16x8*)(dst + i * 8) = r;
  }
}

// src [R][C] fp32 -> dst bf16 at dst[(c*rowMul+rowAdd)*R + r], batched over blockIdx.z
__global__ __launch_bounds__(256) void transpose_bf16_kernel(const float* __restrict__ src0,
                                                             u16* __restrict__ dst0, int R, int C,
                                                             long srcStride, long dstStride,
                                                             int rowMul, int rowAdd) {
  __shared__ float tile[32][33];
  const float* src = src0 + (size_t)blockIdx.z * srcStride;
  u16* dst = dst0 + (size_t)blockIdx.z * dstStride;
  int tx = threadIdx.x & 31, ty = threadIdx.x >> 5;  // 32 x 8
  int bx = blockIdx.x, by = blockIdx.y;
#pragma unroll
  for (int i = 0; i < 32; i += 8) {
    int r = by * 32 + ty + i, c = bx * 32 + tx;
    tile[ty + i][tx] = src[(size_t)r * C + c];
  }
  __syncthreads();
#pragma unroll
  for (int i = 0; i < 32; i += 8) {
    int c = bx * 32 + ty + i;   // dst logical row (source col)
    int r = by * 32 + tx;       // dst col (source row)
    dst[(size_t)(c * rowMul + rowAdd) * R + r] = f2bf(tile[tx][ty + i]);
  }
}

__global__ void embed_gather_kernel(const int* __restrict__ idx, const float* __restrict__ embed,
                                    float* __restrict__ x) {
  int t = blockIdx.x;
  int id = idx[t];
  ((float4*)x)[(size_t)t * 256 + threadIdx.x] = ((const float4*)embed)[(size_t)id * 256 + threadIdx.x];
}

// x fp32 [4096][1024] -> h bf16, h = x * rsqrt(mean(x^2)+eps) * w
__global__ __launch_bounds__(256) void rmsnorm_kernel(const float* __restrict__ x,
                                                      const float* __restrict__ w,
                                                      u16* __restrict__ h) {
  int row = blockIdx.x;
  const float4* xr = (const float4*)(x + (size_t)row * D_MODEL);
  float4 v = xr[threadIdx.x];
  float ss = v.x * v.x + v.y * v.y + v.z * v.z + v.w * v.w;
#pragma unroll
  for (int m = 32; m > 0; m >>= 1) ss += __shfl_xor(ss, m, 64);
  __shared__ float wsum[4];
  if ((threadIdx.x & 63) == 0) wsum[threadIdx.x >> 6] = ss;
  __syncthreads();
  float tot = wsum[0] + wsum[1] + wsum[2] + wsum[3];
  float rinv = rsqrtf(tot * (1.0f / (float)D_MODEL) + 1e-6f);
  float4 wv = ((const float4*)w)[threadIdx.x];
  u16 out[4];
  out[0] = f2bf(v.x * rinv * wv.x);
  out[1] = f2bf(v.y * rinv * wv.y);
  out[2] = f2bf(v.z * rinv * wv.z);
  out[3] = f2bf(v.w * rinv * wv.w);
  u16* hp = h + (size_t)row * D_MODEL + threadIdx.x * 4;
  hp[0] = out[0]; hp[1] = out[1]; hp[2] = out[2]; hp[3] = out[3];
}

// ---------------- GEMM 256x256, BK=64, m201-faithful 4-phase/K-tile ----------------
// C[M,N] = A[M,K](bf16) * B[N,K](bf16)^T. 512 threads = 8 waves (2M x 4N).
// LDS 128 KiB: As[2 buf][2 half][128x64] + Bs[...]. One half-tile stage (2 gloads)
// per phase; per phase: {ds_reads; stage; [lgkmcnt(8) if 12 reads]; barrier;
// lgkmcnt(0); setprio(1); 16 MFMA; setprio(0); barrier}. vmcnt(4) once per K-tile
// at Ph4 (B(kt+2) pair stays in flight; 3-6 phase lead per half-tile).
// Invariants: A halves of buf[(kt+1)&1] last read Ph1/Ph3(kt-1); B halves of
// buf[kt&1] freed after Ph2(kt); swizzle chunk^(row&7) both-sides (0 conflicts).
// EPI: 0 = fp32 store + per-(row,64col) LSE partials; 1 = bf16 store;
//      3 = silu-mul pairing (B rows interleaved gate/up), bf16 store at N/2 width.
template <int EPI>
__global__ __launch_bounds__(512, 2) void gemm256_kernel(const u16* __restrict__ A,
                                                         const u16* __restrict__ B, void* Cp,
                                                         float* __restrict__ partM,
                                                         float* __restrict__ partS,
                                                         int M, int N, int K) {
  __shared__ u16 As[2][2][128 * 64];   // [buf][half][row*64+col]
  __shared__ u16 Bs[2][2][128 * 64];
  const int tid = threadIdx.x;
  const int lane = tid & 63, wid = tid >> 6;
  const int wm = wid >> 2, wn = wid & 3;          // 2 x 4 wave grid
  const int q = lane >> 4, l15 = lane & 15;
  const int nbn = N >> 8;
  const int cpx = (int)gridDim.x >> 3;
  const int swz = ((int)blockIdx.x & 7) * cpx + ((int)blockIdx.x >> 3);
  const int bm = swz / nbn, bn = swz % nbn;
  const u16* Ab = A + (size_t)bm * 256 * K;
  const u16* Bb = B + (size_t)bn * 256 * K;

  // stage half h (local rows 0..127 = global rows h*128..) of tile t
  auto stA = [&](int t, int h) {
    const int k0 = t << 6;
    u16* dst = &As[t & 1][h][0];
    const u16* src = Ab + (size_t)(h << 7) * K + k0;
#pragma unroll
    for (int rnd = 0; rnd < 2; rnd++) {
      int idx = (rnd << 9) + tid;                 // 16B chunk 0..1023, linear dest
      int row = idx >> 3, ch = idx & 7;
      gload_lds16(src + (size_t)row * K + ((ch ^ (row & 7)) << 3), dst + idx * 8);
    }
  };
  auto stB = [&](int t, int h) {
    const int k0 = t << 6;
    u16* dst = &Bs[t & 1][h][0];
    const u16* src = Bb + (size_t)(h << 7) * K + k0;
#pragma unroll
    for (int rnd = 0; rnd < 2; rnd++) {
      int idx = (rnd << 9) + tid;
      int row = idx >> 3, ch = idx & 7;
      gload_lds16(src + (size_t)row * K + ((ch ^ (row & 7)) << 3), dst + idx * 8);
    }
  };

  f32x4 acc[8][4] = {};
  short8 af[4][2], bf0[2][2], bf1[2][2];
  const int NT = K >> 6;   // 16 at all call sites

  // prologue == steady state at end of a virtual Ph4(-1)
  stB(0, 0); stB(0, 1); stA(0, 0); stA(0, 1); stB(1, 0); stB(1, 1);
  asm volatile("s_waitcnt vmcnt(4)" ::: "memory");   // tile0 resident; B(1) pair in flight
  __builtin_amdgcn_s_barrier();

  for (int kt = 0; kt < NT; kt++) {
    const u16* law = &As[kt & 1][wm][0];                       // wave's A half
    const u16* lbw = &Bs[kt & 1][wn >> 1][(wn & 1) * 64 * 64]; // wave's 64-row B slice
    // ---- Ph1: read af-lo(8) + bf0(4); stage A(kt+1)h0; MFMA q0 (mi0-3 x ni0-1)
#pragma unroll
    for (int mi = 0; mi < 4; mi++) {
      int row = mi * 16 + l15;
#pragma unroll
      for (int ks = 0; ks < 2; ks++)
        af[mi][ks] = *(const short8*)&law[row * 64 + (((ks * 4 + q) ^ (row & 7)) << 3)];
    }
#pragma unroll
    for (int ni = 0; ni < 2; ni++) {
      int row = ni * 16 + l15;
#pragma unroll
      for (int ks = 0; ks < 2; ks++)
        bf0[ni][ks] = *(const short8*)&lbw[row * 64 + (((ks * 4 + q) ^ (row & 7)) << 3)];
    }
    if (kt + 1 < NT) stA(kt + 1, 0);
    asm volatile("s_waitcnt lgkmcnt(8)" ::: "memory");
    __builtin_amdgcn_s_barrier();
    asm volatile("s_waitcnt lgkmcnt(0)" ::: "memory");
    __builtin_amdgcn_s_setprio(1);
#pragma unroll
    for (int mi = 0; mi < 4; mi++)
#pragma unroll
      for (int ni = 0; ni < 2; ni++)
#pragma unroll
        for (int ks = 0; ks < 2; ks++)
          acc[mi][ni] = __builtin_amdgcn_mfma_f32_16x16x32_bf16(af[mi][ks], bf0[ni][ks], acc[mi][ni], 0, 0, 0);
    __builtin_amdgcn_s_setprio(0);
    __builtin_amdgcn_s_barrier();
    // ---- Ph2: read bf1(4); stage A(kt+1)h1; MFMA q1 (mi0-3 x ni2-3)
#pragma unroll
    for (int ni = 0; ni < 2; ni++) {
      int row = (ni + 2) * 16 + l15;
#pragma unroll
      for (int ks = 0; ks < 2; ks++)
        bf1[ni][ks] = *(const short8*)&lbw[row * 64 + (((ks * 4 + q) ^ (row & 7)) << 3)];
    }
    if (kt + 1 < NT) stA(kt + 1, 1);
    __builtin_amdgcn_s_barrier();
    asm volatile("s_waitcnt lgkmcnt(0)" ::: "memory");
    __builtin_amdgcn_s_setprio(1);
#pragma unroll
    for (int mi = 0; mi < 4; mi++)
#pragma unroll
      for (int ni = 0; ni < 2; ni++)
#pragma unroll
        for (int ks = 0; ks < 2; ks++)
          acc[mi][ni + 2] = __builtin_amdgcn_mfma_f32_16x16x32_bf16(af[mi][ks], bf1[ni][ks], acc[mi][ni + 2], 0, 0, 0);
    __builtin_amdgcn_s_setprio(0);
    __builtin_amdgcn_s_barrier();
    // ---- Ph3: read af-hi(8, reuse regs); stage B(kt+2)h0 (B regions freed at Ph2); MFMA q2
#pragma unroll
    for (int mi = 0; mi < 4; mi++) {
      int row = (mi + 4) * 16 + l15;
#pragma unroll
      for (int ks = 0; ks < 2; ks++)
        af[mi][ks] = *(const short8*)&law[row * 64 + (((ks * 4 + q) ^ (row & 7)) << 3)];
    }
    if (kt + 2 < NT) stB(kt + 2, 0);
    __builtin_amdgcn_s_barrier();
    asm volatile("s_waitcnt lgkmcnt(0)" ::: "memory");
    __builtin_amdgcn_s_setprio(1);
#pragma unroll
    for (int mi = 0; mi < 4; mi++)
#pragma unroll
      for (int ni = 0; ni < 2; ni++)
#pragma unroll
        for (int ks = 0; ks < 2; ks++)
          acc[mi + 4][ni + 2] = __builtin_amdgcn_mfma_f32_16x16x32_bf16(af[mi][ks], bf1[ni][ks], acc[mi + 4][ni + 2], 0, 0, 0);
    __builtin_amdgcn_s_setprio(0);
    __builtin_amdgcn_s_barrier();
    // ---- Ph4: stage B(kt+2)h1; MFMA q3; counted vmcnt; barrier
    if (kt + 2 < NT) stB(kt + 2, 1);
    __builtin_amdgcn_s_setprio(1);
#pragma unroll
    for (int mi = 0; mi < 4; mi++)
#pragma unroll
      for (int ni = 0; ni < 2; ni++)
#pragma unroll
        for (int ks = 0; ks < 2; ks++)
          acc[mi + 4][ni] = __builtin_amdgcn_mfma_f32_16x16x32_bf16(af[mi][ks], bf0[ni][ks], acc[mi + 4][ni], 0, 0, 0);
    __builtin_amdgcn_s_setprio(0);
    if (kt + 2 < NT)      asm volatile("s_waitcnt vmcnt(4)" ::: "memory");
    else if (kt + 1 < NT) asm volatile("s_waitcnt vmcnt(0)" ::: "memory");
    __builtin_amdgcn_s_barrier();
  }

  // epilogue
  const int row0 = bm * 256 + wm * 128;
  const int col0 = bn * 256 + wn * 64;
#pragma unroll
  for (int mi = 0; mi < 8; mi++)
#pragma unroll
    for (int j = 0; j < 4; j++) {
      int rr = row0 + mi * 16 + q * 4 + j;
      if (EPI == 0) {
        float mx = -1e30f;
#pragma unroll
        for (int ni = 0; ni < 4; ni++) mx = fmaxf(mx, acc[mi][ni][j]);
        mx = fmaxf(mx, __shfl_xor(mx, 1, 64));
        mx = fmaxf(mx, __shfl_xor(mx, 2, 64));
        mx = fmaxf(mx, __shfl_xor(mx, 4, 64));
        mx = fmaxf(mx, __shfl_xor(mx, 8, 64));
        float sm = 0.f;
#pragma unroll
        for (int ni = 0; ni < 4; ni++) sm += expf(acc[mi][ni][j] - mx);
        sm += __shfl_xor(sm, 1, 64);
        sm += __shfl_xor(sm, 2, 64);
        sm += __shfl_xor(sm, 4, 64);
        sm += __shfl_xor(sm, 8, 64);
        if (l15 == 0) {
          int nt = (N >> 6);
          partM[(size_t)rr * nt + (bn << 2) + wn] = mx;
          partS[(size_t)rr * nt + (bn << 2) + wn] = sm;
        }
      }
#pragma unroll
      for (int ni = 0; ni < 4; ni++) {
        int cn = col0 + ni * 16 + l15;
        float vv = acc[mi][ni][j];
        if (EPI == 0) {
          ((float*)Cp)[(size_t)rr * N + cn] = vv;
        } else if (EPI == 1) {
          ((u16*)Cp)[(size_t)rr * N + cn] = f2bf(vv);
        } else if (EPI == 3) {
          float other = __shfl_xor(vv, 1, 64);
          if ((l15 & 1) == 0) {
            float g = vv, u = other;
            float r = g / (1.0f + expf(-g)) * u;
            ((u16*)Cp)[(size_t)rr * (N >> 1) + (cn >> 1)] = f2bf(r);
          }
        }
      }
    }
}

// ---------------- GEMM 128x128 (m97 structure + both-sides swizzle) ----------------
// EPI: 2 = fp32 residual add (C = resid + acc)
template <int EPI>
__global__ __launch_bounds__(256, 2) void gemm_nt_kernel(const u16* __restrict__ A,
                                                         const u16* __restrict__ B, void* Cp,
                                                         const float* resid, int M, int N, int K) {
  __shared__ u16 As[128 * 64];
  __shared__ u16 Bs[128 * 64];
  const int tid = threadIdx.x;
  const int lane = tid & 63, wid = tid >> 6;
  const int wr = wid >> 1, wc = wid & 1;
  const int nbx = N >> 7;
  const int cpx = gridDim.x >> 3;
  const int swz = (blockIdx.x & 7) * cpx + (blockIdx.x >> 3);
  const int bm = swz / nbx, bn = swz - bm * nbx;
  const size_t abase = (size_t)bm * 128 * K;
  const size_t bbase = (size_t)bn * 128 * K;
  f32x4 acc[4][4] = {};
  for (int k0 = 0; k0 < K; k0 += 64) {
#pragma unroll
    for (int i = 0; i < 4; i++) {
      int idx8 = i * 256 + tid;
      int row = idx8 >> 3, ch = idx8 & 7;
      int sc = (ch ^ (row & 7)) << 3;
      gload_lds16(A + abase + (size_t)row * K + k0 + sc, As + idx8 * 8);
      gload_lds16(B + bbase + (size_t)row * K + k0 + sc, Bs + idx8 * 8);
    }
    __syncthreads();
#pragma unroll
    for (int ks = 0; ks < 2; ks++) {
      short8 af[4], bfr[4];
      int chunk = ks * 4 + (lane >> 4);
#pragma unroll
      for (int mi = 0; mi < 4; mi++) {
        int row = wr * 64 + mi * 16 + (lane & 15);
        af[mi] = *(const short8*)&As[row * 64 + ((chunk ^ (row & 7)) << 3)];
      }
#pragma unroll
      for (int ni = 0; ni < 4; ni++) {
        int row = wc * 64 + ni * 16 + (lane & 15);
        bfr[ni] = *(const short8*)&Bs[row * 64 + ((chunk ^ (row & 7)) << 3)];
      }
#pragma unroll
      for (int mi = 0; mi < 4; mi++)
#pragma unroll
        for (int ni = 0; ni < 4; ni++)
          acc[mi][ni] = __builtin_amdgcn_mfma_f32_16x16x32_bf16(af[mi], bfr[ni], acc[mi][ni], 0, 0, 0);
    }
    __syncthreads();
  }
#pragma unroll
  for (int mi = 0; mi < 4; mi++)
#pragma unroll
    for (int ni = 0; ni < 4; ni++)
#pragma unroll
      for (int j = 0; j < 4; j++) {
        int r = bm * 128 + wr * 64 + mi * 16 + (lane >> 4) * 4 + j;
        int cn = bn * 128 + wc * 64 + ni * 16 + (lane & 15);
        size_t off = (size_t)r * N + cn;
        float vv = acc[mi][ni][j];
        if (EPI == 0) ((float*)Cp)[off] = vv;
        else if (EPI == 1) ((u16*)Cp)[off] = f2bf(vv);
        else ((float*)Cp)[off] = resid[off] + vv;
      }
}

// ---------------- flash attention (RoPE fused for Q and K) ----------------
__global__ __launch_bounds__(256) void attn_kernel(const u16* __restrict__ qkv,
                                                   const float* __restrict__ cosb,
                                                   const float* __restrict__ sinb,
                                                   u16* __restrict__ o) {
  __shared__ u16 Ks[64 * 64];
  __shared__ u16 Vt[64 * 64];
  __shared__ u16 Ps[4][32 * 64];
  const u16* q = qkv;
  const u16* k = qkv + D_MODEL;
  const u16* v = qkv + 2 * D_MODEL;
  const int tid = threadIdx.x, lane = tid & 63, wid = tid >> 6;
  const int qg = lane >> 4, l15 = lane & 15;
  const int qt = blockIdx.x;
  const int bh = blockIdx.y;
  const int b = bh >> 4, h = bh & 15;
  const int tok0 = b * TSEQ;
  const int hoff = h * HDIM;
  const int qrow0 = qt * 128 + wid * 32;

  short8 aq[2][2];
#pragma unroll
  for (int mi = 0; mi < 2; mi++) {
    int r = qrow0 + mi * 16 + l15;
#pragma unroll
    for (int ks = 0; ks < 2; ks++)
      aq[mi][ks] = *(const short8*)(q + (size_t)(tok0 + r) * QKV_STRIDE + hoff + ks * 32 + qg * 8);
#pragma unroll
    for (int j = 0; j < 8; j++) {
      int fi = qg * 8 + j;
      float cc = cosb[r * 32 + fi], ss = sinb[r * 32 + fi];
      float x1 = bf2f((u16)aq[mi][0][j]), x2 = bf2f((u16)aq[mi][1][j]);
      aq[mi][0][j] = (short)f2bf(x1 * cc - x2 * ss);
      aq[mi][1][j] = (short)f2bf(x2 * cc + x1 * ss);
    }
  }
  f32x4 oacc[2][4] = {};
  float mrow[2][4], lrow[2][4];
#pragma unroll
  for (int mi = 0; mi < 2; mi++)
#pragma unroll
    for (int j = 0; j < 4; j++) { mrow[mi][j] = -1e30f; lrow[mi][j] = 0.f; }

  const int nkt = (qt + 1) * 2;
  for (int kt = 0; kt < nkt; kt++) {
    const int kv0 = kt * 64;
    {
      int rr = tid >> 2;            // 0..63
      int cp = (tid & 3) << 3;      // 0,8,16,24
      int t = kv0 + rr;
      const u16* kr = k + (size_t)(tok0 + t) * QKV_STRIDE + hoff;
      short8 k1 = *(const short8*)(kr + cp);
      short8 k2 = *(const short8*)(kr + cp + 32);
      u16x8 o1, o2;
#pragma unroll
      for (int j = 0; j < 8; j++) {
        float cc = cosb[t * 32 + cp + j], ss = sinb[t * 32 + cp + j];
        float a = bf2f((u16)k1[j]), bb = bf2f((u16)k2[j]);
        o1[j] = f2bf(a * cc - bb * ss);
        o2[j] = f2bf(bb * cc + a * ss);
      }
      int ch1 = cp >> 3, ch2 = ch1 + 4;
      *(u16x8*)&Ks[rr * 64 + ((ch1 ^ (rr & 7)) << 3)] = o1;
      *(u16x8*)&Ks[rr * 64 + ((ch2 ^ (rr & 7)) << 3)] = o2;
    }
    {
      int d = tid & 63, t4 = (tid >> 6) * 8;
#pragma unroll
      for (int half = 0; half < 2; half++) {
        int t0 = t4 + half * 32;
        short8 pk;
#pragma unroll
        for (int jj = 0; jj < 8; jj++)
          pk[jj] = (short)v[(size_t)(tok0 + kv0 + t0 + jj) * QKV_STRIDE + hoff + d];
        *(short8*)&Vt[d * 64 + (t0 ^ ((d & 7) << 3))] = pk;
      }
    }
    __syncthreads();
    f32x4 sc[2][4] = {};
#pragma unroll
    for (int ks = 0; ks < 2; ks++) {
      short8 bk[4];
      int chunk = ks * 4 + qg;
#pragma unroll
      for (int ni = 0; ni < 4; ni++) {
        int r = ni * 16 + l15;
        bk[ni] = *(const short8*)&Ks[r * 64 + ((chunk ^ (r & 7)) << 3)];
      }
#pragma unroll
      for (int mi = 0; mi < 2; mi++)
#pragma unroll
        for (int ni = 0; ni < 4; ni++)
          sc[mi][ni] = __builtin_amdgcn_mfma_f32_16x16x32_bf16(aq[mi][ks], bk[ni], sc[mi][ni], 0, 0, 0);
    }
    float pm[2][4];
#pragma unroll
    for (int mi = 0; mi < 2; mi++)
#pragma unroll
      for (int j = 0; j < 4; j++) pm[mi][j] = -1e30f;
#pragma unroll
    for (int mi = 0; mi < 2; mi++)
#pragma unroll
      for (int ni = 0; ni < 4; ni++)
#pragma unroll
        for (int j = 0; j < 4; j++) {
          int rq = qrow0 + mi * 16 + qg * 4 + j;
          int ck = kv0 + ni * 16 + l15;
          float s = sc[mi][ni][j] * 0.125f;
          if (ck > rq) s = -1e30f;
          sc[mi][ni][j] = s;
          pm[mi][j] = fmaxf(pm[mi][j], s);
        }
#pragma unroll
    for (int mi = 0; mi < 2; mi++)
#pragma unroll
      for (int j = 0; j < 4; j++) {
        float t = pm[mi][j];
        t = fmaxf(t, __shfl_xor(t, 1, 64));
        t = fmaxf(t, __shfl_xor(t, 2, 64));
        t = fmaxf(t, __shfl_xor(t, 4, 64));
        t = fmaxf(t, __shfl_xor(t, 8, 64));
        pm[mi][j] = t;
      }
#pragma unroll
    for (int mi = 0; mi < 2; mi++)
#pragma unroll
      for (int j = 0; j < 4; j++) {
        float mn = fmaxf(mrow[mi][j], pm[mi][j]);
        float fac = expf(mrow[mi][j] - mn);
        lrow[mi][j] *= fac;
#pragma unroll
        for (int df = 0; df < 4; df++) oacc[mi][df][j] *= fac;
        mrow[mi][j] = mn;
      }
    float psum[2][4] = {};
#pragma unroll
    for (int mi = 0; mi < 2; mi++)
#pragma unroll
      for (int ni = 0; ni < 4; ni++)
#pragma unroll
        for (int j = 0; j < 4; j++) {
          float p = expf(sc[mi][ni][j] - mrow[mi][j]);
          psum[mi][j] += p;
          int r32 = mi * 16 + qg * 4 + j;
          int cc = ni * 16 + l15;
          Ps[wid][r32 * 64 + (cc ^ ((r32 & 7) << 3))] = f2bf(p);
        }
#pragma unroll
    for (int mi = 0; mi < 2; mi++)
#pragma unroll
      for (int j = 0; j < 4; j++) {
        float t = psum[mi][j];
        t += __shfl_xor(t, 1, 64);
        t += __shfl_xor(t, 2, 64);
        t += __shfl_xor(t, 4, 64);
        t += __shfl_xor(t, 8, 64);
        lrow[mi][j] += t;
      }
#pragma unroll
    for (int kf = 0; kf < 2; kf++) {
      short8 pa[2], bv[4];
      int kcol = kf * 32 + qg * 8;
#pragma unroll
      for (int mi = 0; mi < 2; mi++) {
        int r = mi * 16 + l15;
        pa[mi] = *(const short8*)&Ps[wid][r * 64 + (kcol ^ ((r & 7) << 3))];
      }
#pragma unroll
      for (int df = 0; df < 4; df++) {
        int r = df * 16 + l15;
        bv[df] = *(const short8*)&Vt[r * 64 + (kcol ^ ((r & 7) << 3))];
      }
#pragma unroll
      for (int mi = 0; mi < 2; mi++)
#pragma unroll
        for (int df = 0; df < 4; df++)
          oacc[mi][df] = __builtin_amdgcn_mfma_f32_16x16x32_bf16(pa[mi], bv[df], oacc[mi][df], 0, 0, 0);
    }
    __syncthreads();
  }
#pragma unroll
  for (int mi = 0; mi < 2; mi++)
#pragma unroll
    for (int df = 0; df < 4; df++)
#pragma unroll
      for (int j = 0; j < 4; j++) {
        int r = qrow0 + mi * 16 + qg * 4 + j;
        int d = df * 16 + l15;
        float val = oacc[mi][df][j] / lrow[mi][j];
        o[(size_t)(tok0 + r) * D_MODEL + hoff + d] = f2bf(val);
      }
}

// ---------------- loss ----------------

__global__ void nll_finalize_kernel(const float* __restrict__ partM, const float* __restrict__ partS,
                                    const float* __restrict__ logits, const int* __restrict__ targets,
                                    float* __restrict__ nll) {
  int tok = blockIdx.x;
  int lane = threadIdx.x;    // 64
  const int NTL = V_SIZE >> 6;  // 500
  float m = -1e30f, s = 0.f;
  for (int i = lane; i < NTL; i += 64) {
    float m2 = partM[(size_t)tok * NTL + i];
    float s2 = partS[(size_t)tok * NTL + i];
    float nm = fmaxf(m, m2);
    s = s * expf(m - nm) + s2 * expf(m2 - nm);
    m = nm;
  }
#pragma unroll
  for (int mask = 1; mask < 64; mask <<= 1) {
    float m2 = __shfl_xor(m, mask, 64);
    float s2 = __shfl_xor(s, mask, 64);
    float nm = fmaxf(m, m2);
    s = s * expf(m - nm) + s2 * expf(m2 - nm);
    m = nm;
  }
  if (lane == 0)
    nll[tok] = m + logf(s) - logits[(size_t)tok * V_SIZE + targets[tok]];
}

__global__ void loss_reduce_kernel(const float* __restrict__ nll, float* __restrict__ out) {
  float s = 0.f;
  for (int i = threadIdx.x; i < BT; i += 256) s += nll[i];
#pragma unroll
  for (int mask = 1; mask < 64; mask <<= 1) s += __shfl_xor(s, mask, 64);
  __shared__ float sm[4];
  if ((threadIdx.x & 63) == 0) sm[threadIdx.x >> 6] = s;
  __syncthreads();
  if (threadIdx.x == 0) out[0] = (sm[0] + sm[1] + sm[2] + sm[3]) / (float)BT;
}

// ---------------- host launcher ----------------

extern "C" void kernel_launch(void* const* d_in, const int* in_sizes, int n_in,
                              void* d_out, int out_size, void* d_ws, size_t ws_size,
                              hipStream_t stream) {
  const int* idx = (const int*)d_in[0];
  const int* targets = (const int*)d_in[1];
  const float* embed = (const float*)d_in[2];
  const float* wq = (const float*)d_in[3];
  const float* wk = (const float*)d_in[4];
  const float* wv = (const float*)d_in[5];
  const float* wo = (const float*)d_in[6];
  const float* w_gate = (const float*)d_in[7];
  const float* w_up = (const float*)d_in[8];
  const float* w_down = (const float*)d_in[9];
  const float* attn_norm = (const float*)d_in[10];
  const float* mlp_norm = (const float*)d_in[11];
  const float* final_norm = (const float*)d_in[12];
  const float* lm_head = (const float*)d_in[13];
  float* out = (float*)d_out;

  char* ws = (char*)d_ws;
  size_t off = 0;
  auto alloc = [&](size_t bytes) {
    void* p = ws + off;
    off += (bytes + 255) & ~(size_t)255;
    return p;
  };
  const size_t DD = (size_t)D_MODEL * D_MODEL;
  float* rope_cos = (float*)alloc((size_t)TSEQ * 32 * 4);
  float* rope_sin = (float*)alloc((size_t)TSEQ * 32 * 4);
  float* X = (float*)alloc((size_t)BT * D_MODEL * 4);
  u16* Hb = (u16*)alloc((size_t)BT * D_MODEL * 2);
  u16* QKVb = (u16*)alloc((size_t)BT * QKV_STRIDE * 2);
  u16* Ob = (u16*)alloc((size_t)BT * D_MODEL * 2);
  u16* Gb = (u16*)alloc((size_t)BT * HFF * 2);
  u16* WQKVT = (u16*)alloc((size_t)NLAYER * QKV_STRIDE * D_MODEL * 2);
  u16* WOT = (u16*)alloc((size_t)NLAYER * DD * 2);
  u16* WGU = (u16*)alloc((size_t)NLAYER * GU_STRIDE * D_MODEL * 2);
  u16* WDT = (u16*)alloc((size_t)NLAYER * D_MODEL * HFF * 2);
  u16* LMH = (u16*)alloc((size_t)V_SIZE * D_MODEL * 2);
  float* NLLb = (float*)alloc((size_t)BT * 4);
  float* PartM = (float*)alloc((size_t)BT * (V_SIZE >> 6) * 4);
  float* PartS = (float*)alloc((size_t)BT * (V_SIZE >> 6) * 4);

  rope_table_kernel<<<256, 256, 0, stream>>>(rope_cos, rope_sin);
  convert_bf16_kernel<<<4096, 256, 0, stream>>>(lm_head, LMH, (long)V_SIZE * D_MODEL / 8);
  embed_gather_kernel<<<BT, 256, 0, stream>>>(idx, embed, X);

  const long QKVW = (long)QKV_STRIDE * D_MODEL;
  const long GUW = (long)GU_STRIDE * D_MODEL;
  const long DW = (long)D_MODEL * HFF;
  transpose_bf16_kernel<<<dim3(32, 32, NLAYER), 256, 0, stream>>>(wq, WQKVT, D_MODEL, D_MODEL, DD, QKVW, 1, 0);
  transpose_bf16_kernel<<<dim3(32, 32, NLAYER), 256, 0, stream>>>(wk, WQKVT + DD, D_MODEL, D_MODEL, DD, QKVW, 1, 0);
  transpose_bf16_kernel<<<dim3(32, 32, NLAYER), 256, 0, stream>>>(wv, WQKVT + 2 * DD, D_MODEL, D_MODEL, DD, QKVW, 1, 0);
  transpose_bf16_kernel<<<dim3(32, 32, NLAYER), 256, 0, stream>>>(wo, WOT, D_MODEL, D_MODEL, DD, DD, 1, 0);
  transpose_bf16_kernel<<<dim3(128, 32, NLAYER), 256, 0, stream>>>(w_gate, WGU, D_MODEL, HFF, DW, GUW, 2, 0);
  transpose_bf16_kernel<<<dim3(128, 32, NLAYER), 256, 0, stream>>>(w_up, WGU, D_MODEL, HFF, DW, GUW, 2, 1);
  transpose_bf16_kernel<<<dim3(32, 128, NLAYER), 256, 0, stream>>>(w_down, WDT, HFF, D_MODEL, DW, DW, 1, 0);

  for (int l = 0; l < NLAYER; l++) {
    rmsnorm_kernel<<<BT, 256, 0, stream>>>(X, attn_norm + (size_t)l * D_MODEL, Hb);
    gemm256_kernel<1><<<(QKV_STRIDE / 256) * (BT / 256), 512, 0, stream>>>(
        Hb, WQKVT + (size_t)l * QKVW, QKVb, nullptr, nullptr, BT, QKV_STRIDE, D_MODEL);
    attn_kernel<<<dim3(16, 32), 256, 0, stream>>>(QKVb, rope_cos, rope_sin, Ob);
    gemm_nt_kernel<2><<<(D_MODEL / 128) * (BT / 128), 256, 0, stream>>>(
        Ob, WOT + (size_t)l * DD, X, X, BT, D_MODEL, D_MODEL);

    rmsnorm_kernel<<<BT, 256, 0, stream>>>(X, mlp_norm + (size_t)l * D_MODEL, Hb);
    gemm256_kernel<3><<<(GU_STRIDE / 256) * (BT / 256), 512, 0, stream>>>(
        Hb, WGU + (size_t)l * GUW, Gb, nullptr, nullptr, BT, GU_STRIDE, D_MODEL);
    gemm_nt_kernel<2><<<(D_MODEL / 128) * (BT / 128), 256, 0, stream>>>(
        Gb, WDT + (size_t)l * DW, X, X, BT, D_MODEL, HFF);
  }

  rmsnorm_kernel<<<BT, 256, 0, stream>>>(X, final_norm, Hb);
  gemm256_kernel<0><<<(V_SIZE / 256) * (BT / 256), 512, 0, stream>>>(
      Hb, LMH, out, PartM, PartS, BT, V_SIZE, D_MODEL);
  nll_finalize_kernel<<<BT, 64, 0, stream>>>(PartM, PartS, out, targets, NLLb);
  loss_reduce_kernel<<<1, 256, 0, stream>>>(NLLb, out + (size_t)BT * V_SIZE);
}

// Round 7
// 2689.508 us; speedup vs baseline: 1.0219x; 1.0187x over previous
//
#include <hip/hip_runtime.h>

typedef __attribute__((ext_vector_type(8))) short short8;
typedef __attribute__((ext_vector_type(4))) float f32x4;
typedef __attribute__((ext_vector_type(8))) unsigned short u16x8;
typedef unsigned short u16;

#define V_SIZE 32000
#define D_MODEL 1024
#define HFF 4096
#define NHEAD 16
#define HDIM 64
#define NLAYER 4
#define BT 4096   // B*T tokens
#define TSEQ 2048
#define QKV_STRIDE 3072
#define GU_STRIDE 8192

__device__ __forceinline__ u16 f2bf(float f) {
  union { float f; unsigned u; } v; v.f = f;
  unsigned r = v.u + 0x7fffu + ((v.u >> 16) & 1u);
  return (u16)(r >> 16);
}
__device__ __forceinline__ float bf2f(u16 h) {
  union { unsigned u; float f; } v; v.u = ((unsigned)h) << 16;
  return v.f;
}

__device__ __forceinline__ void gload_lds16(const void* g, void* l) {
  __builtin_amdgcn_global_load_lds((__attribute__((address_space(1))) void*)g,
                                   (__attribute__((address_space(3))) void*)l, 16, 0, 0);
}

// ---------------- elementwise / small kernels ----------------

__global__ void rope_table_kernel(float* __restrict__ cosb, float* __restrict__ sinb) {
  int i = blockIdx.x * 256 + threadIdx.x;       // 2048*32 = 65536 items
  int t = i >> 5, fi = i & 31;
  float freq = exp2f(-(2.0f * (float)fi / 64.0f) * log2f(10000.0f));
  float ang = (float)t * freq;
  cosb[i] = cosf(ang);
  sinb[i] = sinf(ang);
}

__global__ void convert_bf16_kernel(const float* __restrict__ src, u16* __restrict__ dst, long n8) {
  long i = (long)blockIdx.x * 256 + threadIdx.x;
  long stride = (long)gridDim.x * 256;
  for (; i < n8; i += stride) {
    const float4* s = (const float4*)(src + i * 8);
    float4 a = s[0], b = s[1];
    u16x8 r;
    r[0] = f2bf(a.x); r[1] = f2bf(a.y); r[2] = f2bf(a.z); r[3] = f2bf(a.w);
    r[4] = f2bf(b.x); r[5] = f2bf(b.y); r[6] = f2bf(b.z); r[7] = f2bf(b.w);
    *(u16x8*)(dst + i * 8) = r;
  }
}

// src [R][C] fp32 -> dst bf16 at dst[(c*rowMul+rowAdd)*R + r], batched over blockIdx.z
__global__ __launch_bounds__(256) void transpose_bf16_kernel(const float* __restrict__ src0,
                                                             u16* __restrict__ dst0, int R, int C,
                                                             long srcStride, long dstStride,
                                                             int rowMul, int rowAdd) {
  __shared__ float tile[32][33];
  const float* src = src0 + (size_t)blockIdx.z * srcStride;
  u16* dst = dst0 + (size_t)blockIdx.z * dstStride;
  int tx = threadIdx.x & 31, ty = threadIdx.x >> 5;  // 32 x 8
  int bx = blockIdx.x, by = blockIdx.y;
#pragma unroll
  for (int i = 0; i < 32; i += 8) {
    int r = by * 32 + ty + i, c = bx * 32 + tx;
    tile[ty + i][tx] = src[(size_t)r * C + c];
  }
  __syncthreads();
#pragma unroll
  for (int i = 0; i < 32; i += 8) {
    int c = bx * 32 + ty + i;   // dst logical row (source col)
    int r = by * 32 + tx;       // dst col (source row)
    dst[(size_t)(c * rowMul + rowAdd) * R + r] = f2bf(tile[tx][ty + i]);
  }
}

__global__ void embed_gather_kernel(const int* __restrict__ idx, const float* __restrict__ embed,
                                    float* __restrict__ x) {
  int t = blockIdx.x;
  int id = idx[t];
  ((float4*)x)[(size_t)t * 256 + threadIdx.x] = ((const float4*)embed)[(size_t)id * 256 + threadIdx.x];
}

// x fp32 [4096][1024] -> h bf16, h = x * rsqrt(mean(x^2)+eps) * w
__global__ __launch_bounds__(256) void rmsnorm_kernel(const float* __restrict__ x,
                                                      const float* __restrict__ w,
                                                      u16* __restrict__ h) {
  int row = blockIdx.x;
  const float4* xr = (const float4*)(x + (size_t)row * D_MODEL);
  float4 v = xr[threadIdx.x];
  float ss = v.x * v.x + v.y * v.y + v.z * v.z + v.w * v.w;
#pragma unroll
  for (int m = 32; m > 0; m >>= 1) ss += __shfl_xor(ss, m, 64);
  __shared__ float wsum[4];
  if ((threadIdx.x & 63) == 0) wsum[threadIdx.x >> 6] = ss;
  __syncthreads();
  float tot = wsum[0] + wsum[1] + wsum[2] + wsum[3];
  float rinv = rsqrtf(tot * (1.0f / (float)D_MODEL) + 1e-6f);
  float4 wv = ((const float4*)w)[threadIdx.x];
  u16 out[4];
  out[0] = f2bf(v.x * rinv * wv.x);
  out[1] = f2bf(v.y * rinv * wv.y);
  out[2] = f2bf(v.z * rinv * wv.z);
  out[3] = f2bf(v.w * rinv * wv.w);
  u16* hp = h + (size_t)row * D_MODEL + threadIdx.x * 4;
  hp[0] = out[0]; hp[1] = out[1]; hp[2] = out[2]; hp[3] = out[3];
}

// ---------------- GEMM 128x128 (m97 structure, both-sides swizzle, 4 blocks/CU) ----
// C[M,N] = A[M,K](bf16) * B[N,K](bf16)^T. 256 threads = 4 waves (2x2).
// 32 KiB LDS -> 4+ blocks/CU; inter-block TLP hides barrier drains (m114).
// Swizzle chunk^(row&7) on global source AND ds_read (0 conflicts).
// EPI: 0 = fp32 store + per-(row,64col) LSE partials (lm-head)
//      1 = bf16 store (QKV)
//      2 = fp32 residual add (o-proj / down-proj)
//      3 = silu-mul pairing (B rows interleaved gate/up), bf16 store at N/2 width
template <int EPI>
__global__ __launch_bounds__(256, 4) void gemm128_kernel(const u16* __restrict__ A,
                                                         const u16* __restrict__ B, void* Cp,
                                                         const float* __restrict__ resid,
                                                         float* __restrict__ partM,
                                                         float* __restrict__ partS,
                                                         int M, int N, int K) {
  __shared__ u16 As[128 * 64];
  __shared__ u16 Bs[128 * 64];
  const int tid = threadIdx.x;
  const int lane = tid & 63, wid = tid >> 6;
  const int wr = wid >> 1, wc = wid & 1;
  const int q = lane >> 4, l15 = lane & 15;
  const int nbx = N >> 7;
  const int cpx = gridDim.x >> 3;
  const int swz = (blockIdx.x & 7) * cpx + (blockIdx.x >> 3);
  const int bm = swz / nbx, bn = swz - bm * nbx;
  const size_t abase = (size_t)bm * 128 * K;
  const size_t bbase = (size_t)bn * 128 * K;
  f32x4 acc[4][4] = {};
  for (int k0 = 0; k0 < K; k0 += 64) {
#pragma unroll
    for (int i = 0; i < 4; i++) {
      int idx8 = i * 256 + tid;
      int row = idx8 >> 3, ch = idx8 & 7;
      int sc = (ch ^ (row & 7)) << 3;
      gload_lds16(A + abase + (size_t)row * K + k0 + sc, As + idx8 * 8);
      gload_lds16(B + bbase + (size_t)row * K + k0 + sc, Bs + idx8 * 8);
    }
    __syncthreads();
#pragma unroll
    for (int ks = 0; ks < 2; ks++) {
      short8 af[4], bfr[4];
      int chunk = ks * 4 + q;
#pragma unroll
      for (int mi = 0; mi < 4; mi++) {
        int row = wr * 64 + mi * 16 + l15;
        af[mi] = *(const short8*)&As[row * 64 + ((chunk ^ (row & 7)) << 3)];
      }
#pragma unroll
      for (int ni = 0; ni < 4; ni++) {
        int row = wc * 64 + ni * 16 + l15;
        bfr[ni] = *(const short8*)&Bs[row * 64 + ((chunk ^ (row & 7)) << 3)];
      }
#pragma unroll
      for (int mi = 0; mi < 4; mi++)
#pragma unroll
        for (int ni = 0; ni < 4; ni++)
          acc[mi][ni] = __builtin_amdgcn_mfma_f32_16x16x32_bf16(af[mi], bfr[ni], acc[mi][ni], 0, 0, 0);
    }
    __syncthreads();
  }
  // epilogue
#pragma unroll
  for (int mi = 0; mi < 4; mi++)
#pragma unroll
    for (int j = 0; j < 4; j++) {
      int rr = bm * 128 + wr * 64 + mi * 16 + q * 4 + j;
      if (EPI == 0) {
        // LSE partial over this wave's 64 cols
        float mx = -1e30f;
#pragma unroll
        for (int ni = 0; ni < 4; ni++) mx = fmaxf(mx, acc[mi][ni][j]);
        mx = fmaxf(mx, __shfl_xor(mx, 1, 64));
        mx = fmaxf(mx, __shfl_xor(mx, 2, 64));
        mx = fmaxf(mx, __shfl_xor(mx, 4, 64));
        mx = fmaxf(mx, __shfl_xor(mx, 8, 64));
        float sm = 0.f;
#pragma unroll
        for (int ni = 0; ni < 4; ni++) sm += expf(acc[mi][ni][j] - mx);
        sm += __shfl_xor(sm, 1, 64);
        sm += __shfl_xor(sm, 2, 64);
        sm += __shfl_xor(sm, 4, 64);
        sm += __shfl_xor(sm, 8, 64);
        if (l15 == 0) {
          int nt = (N >> 6);
          partM[(size_t)rr * nt + (bn << 1) + wc] = mx;
          partS[(size_t)rr * nt + (bn << 1) + wc] = sm;
        }
      }
#pragma unroll
      for (int ni = 0; ni < 4; ni++) {
        int cn = bn * 128 + wc * 64 + ni * 16 + l15;
        size_t off = (size_t)rr * N + cn;
        float vv = acc[mi][ni][j];
        if (EPI == 0) {
          ((float*)Cp)[off] = vv;
        } else if (EPI == 1) {
          ((u16*)Cp)[off] = f2bf(vv);
        } else if (EPI == 2) {
          ((float*)Cp)[off] = resid[off] + vv;
        } else if (EPI == 3) {
          float other = __shfl_xor(vv, 1, 64);
          if ((l15 & 1) == 0) {
            float g = vv, u = other;
            float r = g / (1.0f + expf(-g)) * u;
            ((u16*)Cp)[(size_t)rr * (N >> 1) + (cn >> 1)] = f2bf(r);
          }
        }
      }
    }
}

// ---------------- flash attention (RoPE fused for Q and K) ----------------
// q/k/v live in the fused QKV buffer (row stride 3072, offsets 0/1024/2048), PRE-rope.
// grid: (qtile 0..15, bh 0..31), block 256 (4 waves x 32 q-rows)
__global__ __launch_bounds__(256) void attn_kernel(const u16* __restrict__ qkv,
                                                   const float* __restrict__ cosb,
                                                   const float* __restrict__ sinb,
                                                   u16* __restrict__ o) {
  __shared__ u16 Ks[64 * 64];
  __shared__ u16 Vt[64 * 64];
  __shared__ u16 Ps[4][32 * 64];
  const u16* q = qkv;
  const u16* k = qkv + D_MODEL;
  const u16* v = qkv + 2 * D_MODEL;
  const int tid = threadIdx.x, lane = tid & 63, wid = tid >> 6;
  const int qg = lane >> 4, l15 = lane & 15;
  const int qt = blockIdx.x;
  const int bh = blockIdx.y;
  const int b = bh >> 4, h = bh & 15;
  const int tok0 = b * TSEQ;
  const int hoff = h * HDIM;
  const int qrow0 = qt * 128 + wid * 32;

  short8 aq[2][2];
#pragma unroll
  for (int mi = 0; mi < 2; mi++) {
    int r = qrow0 + mi * 16 + l15;
#pragma unroll
    for (int ks = 0; ks < 2; ks++)
      aq[mi][ks] = *(const short8*)(q + (size_t)(tok0 + r) * QKV_STRIDE + hoff + ks * 32 + qg * 8);
#pragma unroll
    for (int j = 0; j < 8; j++) {
      int fi = qg * 8 + j;
      float cc = cosb[r * 32 + fi], ss = sinb[r * 32 + fi];
      float x1 = bf2f((u16)aq[mi][0][j]), x2 = bf2f((u16)aq[mi][1][j]);
      aq[mi][0][j] = (short)f2bf(x1 * cc - x2 * ss);
      aq[mi][1][j] = (short)f2bf(x2 * cc + x1 * ss);
    }
  }
  f32x4 oacc[2][4] = {};
  float mrow[2][4], lrow[2][4];
#pragma unroll
  for (int mi = 0; mi < 2; mi++)
#pragma unroll
    for (int j = 0; j < 4; j++) { mrow[mi][j] = -1e30f; lrow[mi][j] = 0.f; }

  const int nkt = (qt + 1) * 2;
  for (int kt = 0; kt < nkt; kt++) {
    const int kv0 = kt * 64;
    {
      int rr = tid >> 2;            // 0..63
      int cp = (tid & 3) << 3;      // 0,8,16,24
      int t = kv0 + rr;
      const u16* kr = k + (size_t)(tok0 + t) * QKV_STRIDE + hoff;
      short8 k1 = *(const short8*)(kr + cp);
      short8 k2 = *(const short8*)(kr + cp + 32);
      u16x8 o1, o2;
#pragma unroll
      for (int j = 0; j < 8; j++) {
        float cc = cosb[t * 32 + cp + j], ss = sinb[t * 32 + cp + j];
        float a = bf2f((u16)k1[j]), bb = bf2f((u16)k2[j]);
        o1[j] = f2bf(a * cc - bb * ss);
        o2[j] = f2bf(bb * cc + a * ss);
      }
      int ch1 = cp >> 3, ch2 = ch1 + 4;
      *(u16x8*)&Ks[rr * 64 + ((ch1 ^ (rr & 7)) << 3)] = o1;
      *(u16x8*)&Ks[rr * 64 + ((ch2 ^ (rr & 7)) << 3)] = o2;
    }
    {
      int d = tid & 63, t4 = (tid >> 6) * 8;
#pragma unroll
      for (int half = 0; half < 2; half++) {
        int t0 = t4 + half * 32;
        short8 pk;
#pragma unroll
        for (int jj = 0; jj < 8; jj++)
          pk[jj] = (short)v[(size_t)(tok0 + kv0 + t0 + jj) * QKV_STRIDE + hoff + d];
        *(short8*)&Vt[d * 64 + (t0 ^ ((d & 7) << 3))] = pk;
      }
    }
    __syncthreads();
    f32x4 sc[2][4] = {};
#pragma unroll
    for (int ks = 0; ks < 2; ks++) {
      short8 bk[4];
      int chunk = ks * 4 + qg;
#pragma unroll
      for (int ni = 0; ni < 4; ni++) {
        int r = ni * 16 + l15;
        bk[ni] = *(const short8*)&Ks[r * 64 + ((chunk ^ (r & 7)) << 3)];
      }
#pragma unroll
      for (int mi = 0; mi < 2; mi++)
#pragma unroll
        for (int ni = 0; ni < 4; ni++)
          sc[mi][ni] = __builtin_amdgcn_mfma_f32_16x16x32_bf16(aq[mi][ks], bk[ni], sc[mi][ni], 0, 0, 0);
    }
    float pm[2][4];
#pragma unroll
    for (int mi = 0; mi < 2; mi++)
#pragma unroll
      for (int j = 0; j < 4; j++) pm[mi][j] = -1e30f;
#pragma unroll
    for (int mi = 0; mi < 2; mi++)
#pragma unroll
      for (int ni = 0; ni < 4; ni++)
#pragma unroll
        for (int j = 0; j < 4; j++) {
          int rq = qrow0 + mi * 16 + qg * 4 + j;
          int ck = kv0 + ni * 16 + l15;
          float s = sc[mi][ni][j] * 0.125f;
          if (ck > rq) s = -1e30f;
          sc[mi][ni][j] = s;
          pm[mi][j] = fmaxf(pm[mi][j], s);
        }
#pragma unroll
    for (int mi = 0; mi < 2; mi++)
#pragma unroll
      for (int j = 0; j < 4; j++) {
        float t = pm[mi][j];
        t = fmaxf(t, __shfl_xor(t, 1, 64));
        t = fmaxf(t, __shfl_xor(t, 2, 64));
        t = fmaxf(t, __shfl_xor(t, 4, 64));
        t = fmaxf(t, __shfl_xor(t, 8, 64));
        pm[mi][j] = t;
      }
#pragma unroll
    for (int mi = 0; mi < 2; mi++)
#pragma unroll
      for (int j = 0; j < 4; j++) {
        float mn = fmaxf(mrow[mi][j], pm[mi][j]);
        float fac = expf(mrow[mi][j] - mn);
        lrow[mi][j] *= fac;
#pragma unroll
        for (int df = 0; df < 4; df++) oacc[mi][df][j] *= fac;
        mrow[mi][j] = mn;
      }
    float psum[2][4] = {};
#pragma unroll
    for (int mi = 0; mi < 2; mi++)
#pragma unroll
      for (int ni = 0; ni < 4; ni++)
#pragma unroll
        for (int j = 0; j < 4; j++) {
          float p = expf(sc[mi][ni][j] - mrow[mi][j]);
          psum[mi][j] += p;
          int r32 = mi * 16 + qg * 4 + j;
          int cc = ni * 16 + l15;
          Ps[wid][r32 * 64 + (cc ^ ((r32 & 7) << 3))] = f2bf(p);
        }
#pragma unroll
    for (int mi = 0; mi < 2; mi++)
#pragma unroll
      for (int j = 0; j < 4; j++) {
        float t = psum[mi][j];
        t += __shfl_xor(t, 1, 64);
        t += __shfl_xor(t, 2, 64);
        t += __shfl_xor(t, 4, 64);
        t += __shfl_xor(t, 8, 64);
        lrow[mi][j] += t;
      }
#pragma unroll
    for (int kf = 0; kf < 2; kf++) {
      short8 pa[2], bv[4];
      int kcol = kf * 32 + qg * 8;
#pragma unroll
      for (int mi = 0; mi < 2; mi++) {
        int r = mi * 16 + l15;
        pa[mi] = *(const short8*)&Ps[wid][r * 64 + (kcol ^ ((r & 7) << 3))];
      }
#pragma unroll
      for (int df = 0; df < 4; df++) {
        int r = df * 16 + l15;
        bv[df] = *(const short8*)&Vt[r * 64 + (kcol ^ ((r & 7) << 3))];
      }
#pragma unroll
      for (int mi = 0; mi < 2; mi++)
#pragma unroll
        for (int df = 0; df < 4; df++)
          oacc[mi][df] = __builtin_amdgcn_mfma_f32_16x16x32_bf16(pa[mi], bv[df], oacc[mi][df], 0, 0, 0);
    }
    __syncthreads();
  }
#pragma unroll
  for (int mi = 0; mi < 2; mi++)
#pragma unroll
    for (int df = 0; df < 4; df++)
#pragma unroll
      for (int j = 0; j < 4; j++) {
        int r = qrow0 + mi * 16 + qg * 4 + j;
        int d = df * 16 + l15;
        float val = oacc[mi][df][j] / lrow[mi][j];
        o[(size_t)(tok0 + r) * D_MODEL + hoff + d] = f2bf(val);
      }
}

// ---------------- loss ----------------

__global__ void nll_finalize_kernel(const float* __restrict__ partM, const float* __restrict__ partS,
                                    const float* __restrict__ logits, const int* __restrict__ targets,
                                    float* __restrict__ nll) {
  int tok = blockIdx.x;
  int lane = threadIdx.x;    // 64
  const int NTL = V_SIZE >> 6;  // 500
  float m = -1e30f, s = 0.f;
  for (int i = lane; i < NTL; i += 64) {
    float m2 = partM[(size_t)tok * NTL + i];
    float s2 = partS[(size_t)tok * NTL + i];
    float nm = fmaxf(m, m2);
    s = s * expf(m - nm) + s2 * expf(m2 - nm);
    m = nm;
  }
#pragma unroll
  for (int mask = 1; mask < 64; mask <<= 1) {
    float m2 = __shfl_xor(m, mask, 64);
    float s2 = __shfl_xor(s, mask, 64);
    float nm = fmaxf(m, m2);
    s = s * expf(m - nm) + s2 * expf(m2 - nm);
    m = nm;
  }
  if (lane == 0)
    nll[tok] = m + logf(s) - logits[(size_t)tok * V_SIZE + targets[tok]];
}

__global__ void loss_reduce_kernel(const float* __restrict__ nll, float* __restrict__ out) {
  float s = 0.f;
  for (int i = threadIdx.x; i < BT; i += 256) s += nll[i];
#pragma unroll
  for (int mask = 1; mask < 64; mask <<= 1) s += __shfl_xor(s, mask, 64);
  __shared__ float sm[4];
  if ((threadIdx.x & 63) == 0) sm[threadIdx.x >> 6] = s;
  __syncthreads();
  if (threadIdx.x == 0) out[0] = (sm[0] + sm[1] + sm[2] + sm[3]) / (float)BT;
}

// ---------------- host launcher ----------------

extern "C" void kernel_launch(void* const* d_in, const int* in_sizes, int n_in,
                              void* d_out, int out_size, void* d_ws, size_t ws_size,
                              hipStream_t stream) {
  const int* idx = (const int*)d_in[0];
  const int* targets = (const int*)d_in[1];
  const float* embed = (const float*)d_in[2];
  const float* wq = (const float*)d_in[3];
  const float* wk = (const float*)d_in[4];
  const float* wv = (const float*)d_in[5];
  const float* wo = (const float*)d_in[6];
  const float* w_gate = (const float*)d_in[7];
  const float* w_up = (const float*)d_in[8];
  const float* w_down = (const float*)d_in[9];
  const float* attn_norm = (const float*)d_in[10];
  const float* mlp_norm = (const float*)d_in[11];
  const float* final_norm = (const float*)d_in[12];
  const float* lm_head = (const float*)d_in[13];
  float* out = (float*)d_out;

  char* ws = (char*)d_ws;
  size_t off = 0;
  auto alloc = [&](size_t bytes) {
    void* p = ws + off;
    off += (bytes + 255) & ~(size_t)255;
    return p;
  };
  const size_t DD = (size_t)D_MODEL * D_MODEL;
  float* rope_cos = (float*)alloc((size_t)TSEQ * 32 * 4);
  float* rope_sin = (float*)alloc((size_t)TSEQ * 32 * 4);
  float* X = (float*)alloc((size_t)BT * D_MODEL * 4);
  u16* Hb = (u16*)alloc((size_t)BT * D_MODEL * 2);
  u16* QKVb = (u16*)alloc((size_t)BT * QKV_STRIDE * 2);
  u16* Ob = (u16*)alloc((size_t)BT * D_MODEL * 2);
  u16* Gb = (u16*)alloc((size_t)BT * HFF * 2);
  u16* WQKVT = (u16*)alloc((size_t)NLAYER * QKV_STRIDE * D_MODEL * 2);
  u16* WOT = (u16*)alloc((size_t)NLAYER * DD * 2);
  u16* WGU = (u16*)alloc((size_t)NLAYER * GU_STRIDE * D_MODEL * 2);
  u16* WDT = (u16*)alloc((size_t)NLAYER * D_MODEL * HFF * 2);
  u16* LMH = (u16*)alloc((size_t)V_SIZE * D_MODEL * 2);
  float* NLLb = (float*)alloc((size_t)BT * 4);
  float* PartM = (float*)alloc((size_t)BT * (V_SIZE >> 6) * 4);
  float* PartS = (float*)alloc((size_t)BT * (V_SIZE >> 6) * 4);

  rope_table_kernel<<<256, 256, 0, stream>>>(rope_cos, rope_sin);
  convert_bf16_kernel<<<4096, 256, 0, stream>>>(lm_head, LMH, (long)V_SIZE * D_MODEL / 8);
  embed_gather_kernel<<<BT, 256, 0, stream>>>(idx, embed, X);

  const long QKVW = (long)QKV_STRIDE * D_MODEL;
  const long GUW = (long)GU_STRIDE * D_MODEL;
  const long DW = (long)D_MODEL * HFF;
  transpose_bf16_kernel<<<dim3(32, 32, NLAYER), 256, 0, stream>>>(wq, WQKVT, D_MODEL, D_MODEL, DD, QKVW, 1, 0);
  transpose_bf16_kernel<<<dim3(32, 32, NLAYER), 256, 0, stream>>>(wk, WQKVT + DD, D_MODEL, D_MODEL, DD, QKVW, 1, 0);
  transpose_bf16_kernel<<<dim3(32, 32, NLAYER), 256, 0, stream>>>(wv, WQKVT + 2 * DD, D_MODEL, D_MODEL, DD, QKVW, 1, 0);
  transpose_bf16_kernel<<<dim3(32, 32, NLAYER), 256, 0, stream>>>(wo, WOT, D_MODEL, D_MODEL, DD, DD, 1, 0);
  // gate/up interleaved: B row 2j = gate col j, row 2j+1 = up col j
  transpose_bf16_kernel<<<dim3(128, 32, NLAYER), 256, 0, stream>>>(w_gate, WGU, D_MODEL, HFF, DW, GUW, 2, 0);
  transpose_bf16_kernel<<<dim3(128, 32, NLAYER), 256, 0, stream>>>(w_up, WGU, D_MODEL, HFF, DW, GUW, 2, 1);
  transpose_bf16_kernel<<<dim3(32, 128, NLAYER), 256, 0, stream>>>(w_down, WDT, HFF, D_MODEL, DW, DW, 1, 0);

  for (int l = 0; l < NLAYER; l++) {
    rmsnorm_kernel<<<BT, 256, 0, stream>>>(X, attn_norm + (size_t)l * D_MODEL, Hb);
    gemm128_kernel<1><<<(QKV_STRIDE / 128) * (BT / 128), 256, 0, stream>>>(
        Hb, WQKVT + (size_t)l * QKVW, QKVb, nullptr, nullptr, nullptr, BT, QKV_STRIDE, D_MODEL);
    attn_kernel<<<dim3(16, 32), 256, 0, stream>>>(QKVb, rope_cos, rope_sin, Ob);
    gemm128_kernel<2><<<(D_MODEL / 128) * (BT / 128), 256, 0, stream>>>(
        Ob, WOT + (size_t)l * DD, X, X, nullptr, nullptr, BT, D_MODEL, D_MODEL);

    rmsnorm_kernel<<<BT, 256, 0, stream>>>(X, mlp_norm + (size_t)l * D_MODEL, Hb);
    gemm128_kernel<3><<<(GU_STRIDE / 128) * (BT / 128), 256, 0, stream>>>(
        Hb, WGU + (size_t)l * GUW, Gb, nullptr, nullptr, nullptr, BT, GU_STRIDE, D_MODEL);
    gemm128_kernel<2><<<(D_MODEL / 128) * (BT / 128), 256, 0, stream>>>(
        Gb, WDT + (size_t)l * DW, X, X, nullptr, nullptr, BT, D_MODEL, HFF);
  }

  rmsnorm_kernel<<<BT, 256, 0, stream>>>(X, final_norm, Hb);
  gemm128_kernel<0><<<(V_SIZE / 128) * (BT / 128), 256, 0, stream>>>(
      Hb, LMH, out, nullptr, PartM, PartS, BT, V_SIZE, D_MODEL);
  nll_finalize_kernel<<<BT, 64, 0, stream>>>(PartM, PartS, out, targets, NLLb);
  loss_reduce_kernel<<<1, 256, 0, stream>>>(NLLb, out + (size_t)BT * V_SIZE);
}

// Round 8
// 2359.048 us; speedup vs baseline: 1.1651x; 1.1401x over previous
//
#include <hip/hip_runtime.h>

typedef __attribute__((ext_vector_type(8))) short short8;
typedef __attribute__((ext_vector_type(4))) float f32x4;
typedef __attribute__((ext_vector_type(8))) unsigned short u16x8;
typedef unsigned short u16;

#define V_SIZE 32000
#define D_MODEL 1024
#define HFF 4096
#define NHEAD 16
#define HDIM 64
#define NLAYER 4
#define BT 4096   // B*T tokens
#define TSEQ 2048
#define QKV_STRIDE 3072
#define GU_STRIDE 8192

__device__ __forceinline__ u16 f2bf(float f) {
  union { float f; unsigned u; } v; v.f = f;
  unsigned r = v.u + 0x7fffu + ((v.u >> 16) & 1u);
  return (u16)(r >> 16);
}
__device__ __forceinline__ float bf2f(u16 h) {
  union { unsigned u; float f; } v; v.u = ((unsigned)h) << 16;
  return v.f;
}

__device__ __forceinline__ void gload_lds16(const void* g, void* l) {
  __builtin_amdgcn_global_load_lds((__attribute__((address_space(1))) void*)g,
                                   (__attribute__((address_space(3))) void*)l, 16, 0, 0);
}

// ---------------- elementwise / small kernels ----------------

__global__ void rope_table_kernel(float* __restrict__ cosb, float* __restrict__ sinb) {
  int i = blockIdx.x * 256 + threadIdx.x;       // 2048*32 = 65536 items
  int t = i >> 5, fi = i & 31;
  float freq = exp2f(-(2.0f * (float)fi / 64.0f) * log2f(10000.0f));
  float ang = (float)t * freq;
  cosb[i] = cosf(ang);
  sinb[i] = sinf(ang);
}

__global__ void convert_bf16_kernel(const float* __restrict__ src, u16* __restrict__ dst, long n8) {
  long i = (long)blockIdx.x * 256 + threadIdx.x;
  long stride = (long)gridDim.x * 256;
  for (; i < n8; i += stride) {
    const float4* s = (const float4*)(src + i * 8);
    float4 a = s[0], b = s[1];
    u16x8 r;
    r[0] = f2bf(a.x); r[1] = f2bf(a.y); r[2] = f2bf(a.z); r[3] = f2bf(a.w);
    r[4] = f2bf(b.x); r[5] = f2bf(b.y); r[6] = f2bf(b.z); r[7] = f2bf(b.w);
    *(u16x8*)(dst + i * 8) = r;
  }
}

// src [R][C] fp32 -> dst bf16 at dst[c*R + r], batched over blockIdx.z
__global__ __launch_bounds__(256) void transpose_bf16_kernel(const float* __restrict__ src0,
                                                             u16* __restrict__ dst0, int R, int C,
                                                             long srcStride, long dstStride) {
  __shared__ float tile[32][33];
  const float* src = src0 + (size_t)blockIdx.z * srcStride;
  u16* dst = dst0 + (size_t)blockIdx.z * dstStride;
  int tx = threadIdx.x & 31, ty = threadIdx.x >> 5;  // 32 x 8
  int bx = blockIdx.x, by = blockIdx.y;
#pragma unroll
  for (int i = 0; i < 32; i += 8) {
    int r = by * 32 + ty + i, c = bx * 32 + tx;
    tile[ty + i][tx] = src[(size_t)r * C + c];
  }
  __syncthreads();
#pragma unroll
  for (int i = 0; i < 32; i += 8) {
    int c = bx * 32 + ty + i;   // dst row (source col)
    int r = by * 32 + tx;       // dst col (source row)
    dst[(size_t)c * R + r] = f2bf(tile[tx][ty + i]);
  }
}

__global__ void embed_gather_kernel(const int* __restrict__ idx, const float* __restrict__ embed,
                                    float* __restrict__ x) {
  int t = blockIdx.x;
  int id = idx[t];
  ((float4*)x)[(size_t)t * 256 + threadIdx.x] = ((const float4*)embed)[(size_t)id * 256 + threadIdx.x];
}

// x fp32 [4096][1024] -> h bf16, h = x * rsqrt(mean(x^2)+eps) * w
__global__ __launch_bounds__(256) void rmsnorm_kernel(const float* __restrict__ x,
                                                      const float* __restrict__ w,
                                                      u16* __restrict__ h) {
  int row = blockIdx.x;
  const float4* xr = (const float4*)(x + (size_t)row * D_MODEL);
  float4 v = xr[threadIdx.x];
  float ss = v.x * v.x + v.y * v.y + v.z * v.z + v.w * v.w;
#pragma unroll
  for (int m = 32; m > 0; m >>= 1) ss += __shfl_xor(ss, m, 64);
  __shared__ float wsum[4];
  if ((threadIdx.x & 63) == 0) wsum[threadIdx.x >> 6] = ss;
  __syncthreads();
  float tot = wsum[0] + wsum[1] + wsum[2] + wsum[3];
  float rinv = rsqrtf(tot * (1.0f / (float)D_MODEL) + 1e-6f);
  float4 wv = ((const float4*)w)[threadIdx.x];
  u16 out[4];
  out[0] = f2bf(v.x * rinv * wv.x);
  out[1] = f2bf(v.y * rinv * wv.y);
  out[2] = f2bf(v.z * rinv * wv.z);
  out[3] = f2bf(v.w * rinv * wv.w);
  u16* hp = h + (size_t)row * D_MODEL + threadIdx.x * 4;
  hp[0] = out[0]; hp[1] = out[1]; hp[2] = out[2]; hp[3] = out[3];
}

// in-place RoPE on q and k inside the fused QKV buffer (row stride 3072) — ONCE per element
__global__ void rope_apply_kernel(u16* __restrict__ qkv,
                                  const float* __restrict__ cosb, const float* __restrict__ sinb) {
  int i = blockIdx.x * 256 + threadIdx.x;   // 4096*16*32 = 2097152
  int fi = i & 31;
  int h = (i >> 5) & 15;
  int tok = i >> 9;
  int t = tok & (TSEQ - 1);
  float c = cosb[t * 32 + fi], s = sinb[t * 32 + fi];
  size_t base = (size_t)tok * QKV_STRIDE + h * HDIM + fi;
  float q1 = bf2f(qkv[base]), q2 = bf2f(qkv[base + 32]);
  qkv[base] = f2bf(q1 * c - q2 * s);
  qkv[base + 32] = f2bf(q2 * c + q1 * s);
  size_t kb = base + D_MODEL;
  float k1 = bf2f(qkv[kb]), k2 = bf2f(qkv[kb + 32]);
  qkv[kb] = f2bf(k1 * c - k2 * s);
  qkv[kb + 32] = f2bf(k2 * c + k1 * s);
}

// gu [4096][8192] (gate | up halves) -> out [4096][4096] = silu(gate)*up
__global__ void silu_mul_kernel(const u16* __restrict__ gu, u16* __restrict__ out) {
  long i = (long)blockIdx.x * 256 + threadIdx.x;   // 4096*4096/8 items
  int tok = (int)(i >> 9);
  int col = ((int)i & 511) * 8;
  short8 gv = *(const short8*)(gu + (size_t)tok * GU_STRIDE + col);
  short8 uv = *(const short8*)(gu + (size_t)tok * GU_STRIDE + HFF + col);
  u16x8 r;
#pragma unroll
  for (int j = 0; j < 8; j++) {
    float gf = bf2f((u16)gv[j]);
    float uf = bf2f((u16)uv[j]);
    float sl = gf / (1.0f + expf(-gf));
    r[j] = f2bf(sl * uf);
  }
  *(u16x8*)(out + (size_t)tok * HFF + col) = r;
}

// ---------------- GEMM 128x128 (m97 structure, both-sides swizzle, 4 blocks/CU) ----
// C[M,N] = A[M,K](bf16) * B[N,K](bf16)^T. 256 threads = 4 waves (2x2).
// 32 KiB LDS -> 4 blocks/CU; inter-block TLP hides barrier drains (m114).
// Swizzle chunk^(row&7) on global source AND ds_read (0 conflicts measured).
// EPI: 0 = fp32 NONTEMPORAL store + per-(row,64col) LSE partials (lm-head;
//          nontemporal keeps the 64 MB LMH B-matrix L2/L3-resident against the
//          512 MB logit write stream)
//      1 = bf16 store (QKV / GU)
//      2 = fp32 residual add (o-proj / down-proj)
template <int EPI>
__global__ __launch_bounds__(256, 4) void gemm128_kernel(const u16* __restrict__ A,
                                                         const u16* __restrict__ B, void* Cp,
                                                         const float* __restrict__ resid,
                                                         float* __restrict__ partM,
                                                         float* __restrict__ partS,
                                                         int M, int N, int K) {
  __shared__ u16 As[128 * 64];
  __shared__ u16 Bs[128 * 64];
  const int tid = threadIdx.x;
  const int lane = tid & 63, wid = tid >> 6;
  const int wr = wid >> 1, wc = wid & 1;
  const int q = lane >> 4, l15 = lane & 15;
  const int nbx = N >> 7;
  const int cpx = gridDim.x >> 3;
  const int swz = (blockIdx.x & 7) * cpx + (blockIdx.x >> 3);
  const int bm = swz / nbx, bn = swz - bm * nbx;
  const size_t abase = (size_t)bm * 128 * K;
  const size_t bbase = (size_t)bn * 128 * K;
  f32x4 acc[4][4] = {};
  for (int k0 = 0; k0 < K; k0 += 64) {
#pragma unroll
    for (int i = 0; i < 4; i++) {
      int idx8 = i * 256 + tid;
      int row = idx8 >> 3, ch = idx8 & 7;
      int sc = (ch ^ (row & 7)) << 3;
      gload_lds16(A + abase + (size_t)row * K + k0 + sc, As + idx8 * 8);
      gload_lds16(B + bbase + (size_t)row * K + k0 + sc, Bs + idx8 * 8);
    }
    __syncthreads();
#pragma unroll
    for (int ks = 0; ks < 2; ks++) {
      short8 af[4], bfr[4];
      int chunk = ks * 4 + q;
#pragma unroll
      for (int mi = 0; mi < 4; mi++) {
        int row = wr * 64 + mi * 16 + l15;
        af[mi] = *(const short8*)&As[row * 64 + ((chunk ^ (row & 7)) << 3)];
      }
#pragma unroll
      for (int ni = 0; ni < 4; ni++) {
        int row = wc * 64 + ni * 16 + l15;
        bfr[ni] = *(const short8*)&Bs[row * 64 + ((chunk ^ (row & 7)) << 3)];
      }
#pragma unroll
      for (int mi = 0; mi < 4; mi++)
#pragma unroll
        for (int ni = 0; ni < 4; ni++)
          acc[mi][ni] = __builtin_amdgcn_mfma_f32_16x16x32_bf16(af[mi], bfr[ni], acc[mi][ni], 0, 0, 0);
    }
    __syncthreads();
  }
  // epilogue
#pragma unroll
  for (int mi = 0; mi < 4; mi++)
#pragma unroll
    for (int j = 0; j < 4; j++) {
      int rr = bm * 128 + wr * 64 + mi * 16 + q * 4 + j;
      if (EPI == 0) {
        // LSE partial over this wave's 64 cols
        float mx = -1e30f;
#pragma unroll
        for (int ni = 0; ni < 4; ni++) mx = fmaxf(mx, acc[mi][ni][j]);
        mx = fmaxf(mx, __shfl_xor(mx, 1, 64));
        mx = fmaxf(mx, __shfl_xor(mx, 2, 64));
        mx = fmaxf(mx, __shfl_xor(mx, 4, 64));
        mx = fmaxf(mx, __shfl_xor(mx, 8, 64));
        float sm = 0.f;
#pragma unroll
        for (int ni = 0; ni < 4; ni++) sm += expf(acc[mi][ni][j] - mx);
        sm += __shfl_xor(sm, 1, 64);
        sm += __shfl_xor(sm, 2, 64);
        sm += __shfl_xor(sm, 4, 64);
        sm += __shfl_xor(sm, 8, 64);
        if (l15 == 0) {
          int nt = (N >> 6);
          partM[(size_t)rr * nt + (bn << 1) + wc] = mx;
          partS[(size_t)rr * nt + (bn << 1) + wc] = sm;
        }
      }
#pragma unroll
      for (int ni = 0; ni < 4; ni++) {
        int cn = bn * 128 + wc * 64 + ni * 16 + l15;
        size_t off = (size_t)rr * N + cn;
        float vv = acc[mi][ni][j];
        if (EPI == 0) {
          __builtin_nontemporal_store(vv, (float*)Cp + off);
        } else if (EPI == 1) {
          ((u16*)Cp)[off] = f2bf(vv);
        } else if (EPI == 2) {
          ((float*)Cp)[off] = resid[off] + vv;
        }
      }
    }
}

// ---------------- flash attention ----------------
// q/k/v live in the fused QKV buffer (row stride 3072, offsets 0/1024/2048), POST-rope.
// grid: (qtile 0..15, bh 0..31), block 256 (4 waves x 32 q-rows)
__global__ __launch_bounds__(256) void attn_kernel(const u16* __restrict__ qkv,
                                                   u16* __restrict__ o) {
  __shared__ u16 Ks[64 * 64];
  __shared__ u16 Vt[64 * 64];
  __shared__ u16 Ps[4][32 * 64];
  const u16* q = qkv;
  const u16* k = qkv + D_MODEL;
  const u16* v = qkv + 2 * D_MODEL;
  const int tid = threadIdx.x, lane = tid & 63, wid = tid >> 6;
  const int qg = lane >> 4, l15 = lane & 15;
  const int qt = blockIdx.x;
  const int bh = blockIdx.y;
  const int b = bh >> 4, h = bh & 15;
  const int tok0 = b * TSEQ;
  const int hoff = h * HDIM;
  const int qrow0 = qt * 128 + wid * 32;

  short8 aq[2][2];
#pragma unroll
  for (int mi = 0; mi < 2; mi++)
#pragma unroll
    for (int ks = 0; ks < 2; ks++) {
      int r = qrow0 + mi * 16 + l15;
      int d = ks * 32 + qg * 8;
      aq[mi][ks] = *(const short8*)(q + (size_t)(tok0 + r) * QKV_STRIDE + hoff + d);
    }
  f32x4 oacc[2][4] = {};
  float mrow[2][4], lrow[2][4];
#pragma unroll
  for (int mi = 0; mi < 2; mi++)
#pragma unroll
    for (int j = 0; j < 4; j++) { mrow[mi][j] = -1e30f; lrow[mi][j] = 0.f; }

  const int nkt = (qt + 1) * 2;
  for (int kt = 0; kt < nkt; kt++) {
    const int kv0 = kt * 64;
    // stage K [64][64] (swizzled)
#pragma unroll
    for (int i = 0; i < 2; i++) {
      int c = tid + 256 * i;
      int row = c >> 3, col = (c & 7) * 8;
      short8 kv = *(const short8*)(k + (size_t)(tok0 + kv0 + row) * QKV_STRIDE + hoff + col);
      *(short8*)&Ks[row * 64 + (col ^ ((row & 7) << 3))] = kv;
    }
    // stage V^T: Vt[d][t] (swizzled)
    {
      int d = tid & 63, t4 = (tid >> 6) * 8;
#pragma unroll
      for (int half = 0; half < 2; half++) {
        int t0 = t4 + half * 32;
        short8 pk;
#pragma unroll
        for (int jj = 0; jj < 8; jj++)
          pk[jj] = (short)v[(size_t)(tok0 + kv0 + t0 + jj) * QKV_STRIDE + hoff + d];
        *(short8*)&Vt[d * 64 + (t0 ^ ((d & 7) << 3))] = pk;
      }
    }
    __syncthreads();
    f32x4 sc[2][4] = {};
#pragma unroll
    for (int ks = 0; ks < 2; ks++) {
      short8 bk[4];
      int kcol = ks * 32 + qg * 8;
#pragma unroll
      for (int ni = 0; ni < 4; ni++) {
        int r = ni * 16 + l15;
        bk[ni] = *(const short8*)&Ks[r * 64 + (kcol ^ ((r & 7) << 3))];
      }
#pragma unroll
      for (int mi = 0; mi < 2; mi++)
#pragma unroll
        for (int ni = 0; ni < 4; ni++)
          sc[mi][ni] = __builtin_amdgcn_mfma_f32_16x16x32_bf16(aq[mi][ks], bk[ni], sc[mi][ni], 0, 0, 0);
    }
    float pm[2][4];
#pragma unroll
    for (int mi = 0; mi < 2; mi++)
#pragma unroll
      for (int j = 0; j < 4; j++) pm[mi][j] = -1e30f;
#pragma unroll
    for (int mi = 0; mi < 2; mi++)
#pragma unroll
      for (int ni = 0; ni < 4; ni++)
#pragma unroll
        for (int j = 0; j < 4; j++) {
          int rq = qrow0 + mi * 16 + qg * 4 + j;
          int ck = kv0 + ni * 16 + l15;
          float s = sc[mi][ni][j] * 0.125f;
          if (ck > rq) s = -1e30f;
          sc[mi][ni][j] = s;
          pm[mi][j] = fmaxf(pm[mi][j], s);
        }
#pragma unroll
    for (int mi = 0; mi < 2; mi++)
#pragma unroll
      for (int j = 0; j < 4; j++) {
        float t = pm[mi][j];
        t = fmaxf(t, __shfl_xor(t, 1, 64));
        t = fmaxf(t, __shfl_xor(t, 2, 64));
        t = fmaxf(t, __shfl_xor(t, 4, 64));
        t = fmaxf(t, __shfl_xor(t, 8, 64));
        pm[mi][j] = t;
      }
#pragma unroll
    for (int mi = 0; mi < 2; mi++)
#pragma unroll
      for (int j = 0; j < 4; j++) {
        float mn = fmaxf(mrow[mi][j], pm[mi][j]);
        float fac = expf(mrow[mi][j] - mn);
        lrow[mi][j] *= fac;
#pragma unroll
        for (int df = 0; df < 4; df++) oacc[mi][df][j] *= fac;
        mrow[mi][j] = mn;
      }
    float psum[2][4] = {};
#pragma unroll
    for (int mi = 0; mi < 2; mi++)
#pragma unroll
      for (int ni = 0; ni < 4; ni++)
#pragma unroll
        for (int j = 0; j < 4; j++) {
          float p = expf(sc[mi][ni][j] - mrow[mi][j]);
          psum[mi][j] += p;
          int r32 = mi * 16 + qg * 4 + j;
          int cc = ni * 16 + l15;
          Ps[wid][r32 * 64 + (cc ^ ((r32 & 7) << 3))] = f2bf(p);
        }
#pragma unroll
    for (int mi = 0; mi < 2; mi++)
#pragma unroll
      for (int j = 0; j < 4; j++) {
        float t = psum[mi][j];
        t += __shfl_xor(t, 1, 64);
        t += __shfl_xor(t, 2, 64);
        t += __shfl_xor(t, 4, 64);
        t += __shfl_xor(t, 8, 64);
        lrow[mi][j] += t;
      }
#pragma unroll
    for (int kf = 0; kf < 2; kf++) {
      short8 pa[2], bv[4];
      int kcol = kf * 32 + qg * 8;
#pragma unroll
      for (int mi = 0; mi < 2; mi++) {
        int r = mi * 16 + l15;
        pa[mi] = *(const short8*)&Ps[wid][r * 64 + (kcol ^ ((r & 7) << 3))];
      }
#pragma unroll
      for (int df = 0; df < 4; df++) {
        int r = df * 16 + l15;
        bv[df] = *(const short8*)&Vt[r * 64 + (kcol ^ ((r & 7) << 3))];
      }
#pragma unroll
      for (int mi = 0; mi < 2; mi++)
#pragma unroll
        for (int df = 0; df < 4; df++)
          oacc[mi][df] = __builtin_amdgcn_mfma_f32_16x16x32_bf16(pa[mi], bv[df], oacc[mi][df], 0, 0, 0);
    }
    __syncthreads();
  }
#pragma unroll
  for (int mi = 0; mi < 2; mi++)
#pragma unroll
    for (int df = 0; df < 4; df++)
#pragma unroll
      for (int j = 0; j < 4; j++) {
        int r = qrow0 + mi * 16 + qg * 4 + j;
        int d = df * 16 + l15;
        float val = oacc[mi][df][j] / lrow[mi][j];
        o[(size_t)(tok0 + r) * D_MODEL + hoff + d] = f2bf(val);
      }
}

// ---------------- loss ----------------

__global__ void nll_finalize_kernel(const float* __restrict__ partM, const float* __restrict__ partS,
                                    const float* __restrict__ logits, const int* __restrict__ targets,
                                    float* __restrict__ nll) {
  int tok = blockIdx.x;
  int lane = threadIdx.x;    // 64
  const int NTL = V_SIZE >> 6;  // 500
  float m = -1e30f, s = 0.f;
  for (int i = lane; i < NTL; i += 64) {
    float m2 = partM[(size_t)tok * NTL + i];
    float s2 = partS[(size_t)tok * NTL + i];
    float nm = fmaxf(m, m2);
    s = s * expf(m - nm) + s2 * expf(m2 - nm);
    m = nm;
  }
#pragma unroll
  for (int mask = 1; mask < 64; mask <<= 1) {
    float m2 = __shfl_xor(m, mask, 64);
    float s2 = __shfl_xor(s, mask, 64);
    float nm = fmaxf(m, m2);
    s = s * expf(m - nm) + s2 * expf(m2 - nm);
    m = nm;
  }
  if (lane == 0)
    nll[tok] = m + logf(s) - logits[(size_t)tok * V_SIZE + targets[tok]];
}

__global__ void loss_reduce_kernel(const float* __restrict__ nll, float* __restrict__ out) {
  float s = 0.f;
  for (int i = threadIdx.x; i < BT; i += 256) s += nll[i];
#pragma unroll
  for (int mask = 1; mask < 64; mask <<= 1) s += __shfl_xor(s, mask, 64);
  __shared__ float sm[4];
  if ((threadIdx.x & 63) == 0) sm[threadIdx.x >> 6] = s;
  __syncthreads();
  if (threadIdx.x == 0) out[0] = (sm[0] + sm[1] + sm[2] + sm[3]) / (float)BT;
}

// ---------------- host launcher ----------------

extern "C" void kernel_launch(void* const* d_in, const int* in_sizes, int n_in,
                              void* d_out, int out_size, void* d_ws, size_t ws_size,
                              hipStream_t stream) {
  const int* idx = (const int*)d_in[0];
  const int* targets = (const int*)d_in[1];
  const float* embed = (const float*)d_in[2];
  const float* wq = (const float*)d_in[3];
  const float* wk = (const float*)d_in[4];
  const float* wv = (const float*)d_in[5];
  const float* wo = (const float*)d_in[6];
  const float* w_gate = (const float*)d_in[7];
  const float* w_up = (const float*)d_in[8];
  const float* w_down = (const float*)d_in[9];
  const float* attn_norm = (const float*)d_in[10];
  const float* mlp_norm = (const float*)d_in[11];
  const float* final_norm = (const float*)d_in[12];
  const float* lm_head = (const float*)d_in[13];
  float* out = (float*)d_out;

  char* ws = (char*)d_ws;
  size_t off = 0;
  auto alloc = [&](size_t bytes) {
    void* p = ws + off;
    off += (bytes + 255) & ~(size_t)255;
    return p;
  };
  const size_t DD = (size_t)D_MODEL * D_MODEL;
  float* rope_cos = (float*)alloc((size_t)TSEQ * 32 * 4);
  float* rope_sin = (float*)alloc((size_t)TSEQ * 32 * 4);
  float* X = (float*)alloc((size_t)BT * D_MODEL * 4);
  u16* Hb = (u16*)alloc((size_t)BT * D_MODEL * 2);
  u16* QKVb = (u16*)alloc((size_t)BT * QKV_STRIDE * 2);
  u16* Ob = (u16*)alloc((size_t)BT * D_MODEL * 2);
  u16* GUb = (u16*)alloc((size_t)BT * GU_STRIDE * 2);
  u16* Gb = (u16*)alloc((size_t)BT * HFF * 2);
  u16* WQKVT = (u16*)alloc((size_t)NLAYER * QKV_STRIDE * D_MODEL * 2);
  u16* WOT = (u16*)alloc((size_t)NLAYER * DD * 2);
  u16* WGU = (u16*)alloc((size_t)NLAYER * GU_STRIDE * D_MODEL * 2);
  u16* WDT = (u16*)alloc((size_t)NLAYER * D_MODEL * HFF * 2);
  u16* LMH = (u16*)alloc((size_t)V_SIZE * D_MODEL * 2);
  float* NLLb = (float*)alloc((size_t)BT * 4);
  float* PartM = (float*)alloc((size_t)BT * (V_SIZE >> 6) * 4);
  float* PartS = (float*)alloc((size_t)BT * (V_SIZE >> 6) * 4);

  rope_table_kernel<<<256, 256, 0, stream>>>(rope_cos, rope_sin);
  convert_bf16_kernel<<<4096, 256, 0, stream>>>(lm_head, LMH, (long)V_SIZE * D_MODEL / 8);
  embed_gather_kernel<<<BT, 256, 0, stream>>>(idx, embed, X);

  const long QKVW = (long)QKV_STRIDE * D_MODEL;
  const long GUW = (long)GU_STRIDE * D_MODEL;
  const long DW = (long)D_MODEL * HFF;
  transpose_bf16_kernel<<<dim3(32, 32, NLAYER), 256, 0, stream>>>(wq, WQKVT, D_MODEL, D_MODEL, DD, QKVW);
  transpose_bf16_kernel<<<dim3(32, 32, NLAYER), 256, 0, stream>>>(wk, WQKVT + DD, D_MODEL, D_MODEL, DD, QKVW);
  transpose_bf16_kernel<<<dim3(32, 32, NLAYER), 256, 0, stream>>>(wv, WQKVT + 2 * DD, D_MODEL, D_MODEL, DD, QKVW);
  transpose_bf16_kernel<<<dim3(32, 32, NLAYER), 256, 0, stream>>>(wo, WOT, D_MODEL, D_MODEL, DD, DD);
  transpose_bf16_kernel<<<dim3(128, 32, NLAYER), 256, 0, stream>>>(w_gate, WGU, D_MODEL, HFF, DW, GUW);
  transpose_bf16_kernel<<<dim3(128, 32, NLAYER), 256, 0, stream>>>(w_up, WGU + (size_t)HFF * D_MODEL, D_MODEL, HFF, DW, GUW);
  transpose_bf16_kernel<<<dim3(32, 128, NLAYER), 256, 0, stream>>>(w_down, WDT, HFF, D_MODEL, DW, DW);

  for (int l = 0; l < NLAYER; l++) {
    rmsnorm_kernel<<<BT, 256, 0, stream>>>(X, attn_norm + (size_t)l * D_MODEL, Hb);
    gemm128_kernel<1><<<(QKV_STRIDE / 128) * (BT / 128), 256, 0, stream>>>(
        Hb, WQKVT + (size_t)l * QKVW, QKVb, nullptr, nullptr, nullptr, BT, QKV_STRIDE, D_MODEL);
    rope_apply_kernel<<<8192, 256, 0, stream>>>(QKVb, rope_cos, rope_sin);
    attn_kernel<<<dim3(16, 32), 256, 0, stream>>>(QKVb, Ob);
    gemm128_kernel<2><<<(D_MODEL / 128) * (BT / 128), 256, 0, stream>>>(
        Ob, WOT + (size_t)l * DD, X, X, nullptr, nullptr, BT, D_MODEL, D_MODEL);

    rmsnorm_kernel<<<BT, 256, 0, stream>>>(X, mlp_norm + (size_t)l * D_MODEL, Hb);
    gemm128_kernel<1><<<(GU_STRIDE / 128) * (BT / 128), 256, 0, stream>>>(
        Hb, WGU + (size_t)l * GUW, GUb, nullptr, nullptr, nullptr, BT, GU_STRIDE, D_MODEL);
    silu_mul_kernel<<<8192, 256, 0, stream>>>(GUb, Gb);
    gemm128_kernel<2><<<(D_MODEL / 128) * (BT / 128), 256, 0, stream>>>(
        Gb, WDT + (size_t)l * DW, X, X, nullptr, nullptr, BT, D_MODEL, HFF);
  }

  rmsnorm_kernel<<<BT, 256, 0, stream>>>(X, final_norm, Hb);
  gemm128_kernel<0><<<(V_SIZE / 128) * (BT / 128), 256, 0, stream>>>(
      Hb, LMH, out, nullptr, PartM, PartS, BT, V_SIZE, D_MODEL);
  nll_finalize_kernel<<<BT, 64, 0, stream>>>(PartM, PartS, out, targets, NLLb);
  loss_reduce_kernel<<<1, 256, 0, stream>>>(NLLb, out + (size_t)BT * V_SIZE);
}

// Round 9
// 2276.303 us; speedup vs baseline: 1.2074x; 1.0364x over previous
//
#include <hip/hip_runtime.h>

typedef __attribute__((ext_vector_type(8))) short short8;
typedef __attribute__((ext_vector_type(4))) float f32x4;
typedef __attribute__((ext_vector_type(8))) unsigned short u16x8;
typedef unsigned short u16;

#define V_SIZE 32000
#define D_MODEL 1024
#define HFF 4096
#define NHEAD 16
#define HDIM 64
#define NLAYER 4
#define BT 4096   // B*T tokens
#define TSEQ 2048
#define QKV_STRIDE 3072
#define GU_STRIDE 8192

__device__ __forceinline__ u16 f2bf(float f) {
  union { float f; unsigned u; } v; v.f = f;
  unsigned r = v.u + 0x7fffu + ((v.u >> 16) & 1u);
  return (u16)(r >> 16);
}
__device__ __forceinline__ float bf2f(u16 h) {
  union { unsigned u; float f; } v; v.u = ((unsigned)h) << 16;
  return v.f;
}

__device__ __forceinline__ void gload_lds16(const void* g, void* l) {
  __builtin_amdgcn_global_load_lds((__attribute__((address_space(1))) void*)g,
                                   (__attribute__((address_space(3))) void*)l, 16, 0, 0);
}

// ---------------- elementwise / small kernels ----------------

__global__ void rope_table_kernel(float* __restrict__ cosb, float* __restrict__ sinb) {
  int i = blockIdx.x * 256 + threadIdx.x;       // 2048*32 = 65536 items
  int t = i >> 5, fi = i & 31;
  float freq = exp2f(-(2.0f * (float)fi / 64.0f) * log2f(10000.0f));
  float ang = (float)t * freq;
  cosb[i] = cosf(ang);
  sinb[i] = sinf(ang);
}

__global__ void convert_bf16_kernel(const float* __restrict__ src, u16* __restrict__ dst, long n8) {
  long i = (long)blockIdx.x * 256 + threadIdx.x;
  long stride = (long)gridDim.x * 256;
  for (; i < n8; i += stride) {
    const float4* s = (const float4*)(src + i * 8);
    float4 a = s[0], b = s[1];
    u16x8 r;
    r[0] = f2bf(a.x); r[1] = f2bf(a.y); r[2] = f2bf(a.z); r[3] = f2bf(a.w);
    r[4] = f2bf(b.x); r[5] = f2bf(b.y); r[6] = f2bf(b.z); r[7] = f2bf(b.w);
    *(u16x8*)(dst + i * 8) = r;
  }
}

// src [R][C] fp32 -> dst bf16 at dst[c*R + r], batched over blockIdx.z
__global__ __launch_bounds__(256) void transpose_bf16_kernel(const float* __restrict__ src0,
                                                             u16* __restrict__ dst0, int R, int C,
                                                             long srcStride, long dstStride) {
  __shared__ float tile[32][33];
  const float* src = src0 + (size_t)blockIdx.z * srcStride;
  u16* dst = dst0 + (size_t)blockIdx.z * dstStride;
  int tx = threadIdx.x & 31, ty = threadIdx.x >> 5;  // 32 x 8
  int bx = blockIdx.x, by = blockIdx.y;
#pragma unroll
  for (int i = 0; i < 32; i += 8) {
    int r = by * 32 + ty + i, c = bx * 32 + tx;
    tile[ty + i][tx] = src[(size_t)r * C + c];
  }
  __syncthreads();
#pragma unroll
  for (int i = 0; i < 32; i += 8) {
    int c = bx * 32 + ty + i;   // dst row (source col)
    int r = by * 32 + tx;       // dst col (source row)
    dst[(size_t)c * R + r] = f2bf(tile[tx][ty + i]);
  }
}

__global__ void embed_gather_kernel(const int* __restrict__ idx, const float* __restrict__ embed,
                                    float* __restrict__ x) {
  int t = blockIdx.x;
  int id = idx[t];
  ((float4*)x)[(size_t)t * 256 + threadIdx.x] = ((const float4*)embed)[(size_t)id * 256 + threadIdx.x];
}

// x fp32 [4096][1024] -> h bf16, h = x * rsqrt(mean(x^2)+eps) * w
__global__ __launch_bounds__(256) void rmsnorm_kernel(const float* __restrict__ x,
                                                      const float* __restrict__ w,
                                                      u16* __restrict__ h) {
  int row = blockIdx.x;
  const float4* xr = (const float4*)(x + (size_t)row * D_MODEL);
  float4 v = xr[threadIdx.x];
  float ss = v.x * v.x + v.y * v.y + v.z * v.z + v.w * v.w;
#pragma unroll
  for (int m = 32; m > 0; m >>= 1) ss += __shfl_xor(ss, m, 64);
  __shared__ float wsum[4];
  if ((threadIdx.x & 63) == 0) wsum[threadIdx.x >> 6] = ss;
  __syncthreads();
  float tot = wsum[0] + wsum[1] + wsum[2] + wsum[3];
  float rinv = rsqrtf(tot * (1.0f / (float)D_MODEL) + 1e-6f);
  float4 wv = ((const float4*)w)[threadIdx.x];
  u16 out[4];
  out[0] = f2bf(v.x * rinv * wv.x);
  out[1] = f2bf(v.y * rinv * wv.y);
  out[2] = f2bf(v.z * rinv * wv.z);
  out[3] = f2bf(v.w * rinv * wv.w);
  u16* hp = h + (size_t)row * D_MODEL + threadIdx.x * 4;
  hp[0] = out[0]; hp[1] = out[1]; hp[2] = out[2]; hp[3] = out[3];
}

// in-place RoPE on q and k inside the fused QKV buffer (row stride 3072)
__global__ void rope_apply_kernel(u16* __restrict__ qkv,
                                  const float* __restrict__ cosb, const float* __restrict__ sinb) {
  int i = blockIdx.x * 256 + threadIdx.x;   // 4096*16*32 = 2097152
  int fi = i & 31;
  int h = (i >> 5) & 15;
  int tok = i >> 9;
  int t = tok & (TSEQ - 1);
  float c = cosb[t * 32 + fi], s = sinb[t * 32 + fi];
  size_t base = (size_t)tok * QKV_STRIDE + h * HDIM + fi;
  float q1 = bf2f(qkv[base]), q2 = bf2f(qkv[base + 32]);
  qkv[base] = f2bf(q1 * c - q2 * s);
  qkv[base + 32] = f2bf(q2 * c + q1 * s);
  size_t kb = base + D_MODEL;
  float k1 = bf2f(qkv[kb]), k2 = bf2f(qkv[kb + 32]);
  qkv[kb] = f2bf(k1 * c - k2 * s);
  qkv[kb + 32] = f2bf(k2 * c + k1 * s);
}

// gu [4096][8192] (gate | up halves) -> out [4096][4096] = silu(gate)*up
__global__ void silu_mul_kernel(const u16* __restrict__ gu, u16* __restrict__ out) {
  long i = (long)blockIdx.x * 256 + threadIdx.x;   // 4096*4096/8 items
  int tok = (int)(i >> 9);
  int col = ((int)i & 511) * 8;
  short8 gv = *(const short8*)(gu + (size_t)tok * GU_STRIDE + col);
  short8 uv = *(const short8*)(gu + (size_t)tok * GU_STRIDE + HFF + col);
  u16x8 r;
#pragma unroll
  for (int j = 0; j < 8; j++) {
    float gf = bf2f((u16)gv[j]);
    float uf = bf2f((u16)uv[j]);
    float sl = gf / (1.0f + expf(-gf));
    r[j] = f2bf(sl * uf);
  }
  *(u16x8*)(out + (size_t)tok * HFF + col) = r;
}

// ---------------- GEMM 128x128 (m97 structure, both-sides swizzle, 4 blocks/CU) ----
// C[M,N] = A[M,K](bf16) * B[N,K](bf16)^T. 256 threads = 4 waves (2x2).
// Grid is processed in bn-CHUNKS of chunkBn columns (cs = nbm*chunkBn blocks per
// chunk): the B-chunk (chunkBn*256KB) is fetched from HBM once and stays
// L3-resident across all nbm re-reads (reuse distance << the eviction horizon
// imposed by the C write stream). Within a chunk, the bijective XCD swizzle
// pins each XCD to 4 consecutive bm rows -> A panels L2-resident.
// Requires: nbn % chunkBn == 0 (all call sites comply).
// EPI: 0 = fp32 nontemporal store + per-(row,64col) LSE partials (lm-head)
//      1 = bf16 store (QKV / GU)
//      2 = fp32 residual add (o-proj / down-proj)
template <int EPI>
__global__ __launch_bounds__(256, 4) void gemm128_kernel(const u16* __restrict__ A,
                                                         const u16* __restrict__ B, void* Cp,
                                                         const float* __restrict__ resid,
                                                         float* __restrict__ partM,
                                                         float* __restrict__ partS,
                                                         int M, int N, int K, int chunkBn) {
  __shared__ u16 As[128 * 64];
  __shared__ u16 Bs[128 * 64];
  const int tid = threadIdx.x;
  const int lane = tid & 63, wid = tid >> 6;
  const int wr = wid >> 1, wc = wid & 1;
  const int q = lane >> 4, l15 = lane & 15;
  const int nbm = M >> 7;
  // chunked + XCD-swizzled block mapping
  const int cs = nbm * chunkBn;            // blocks per chunk (nbm=32 -> cs%8==0)
  const int chunk = (int)blockIdx.x / cs;
  const int r0 = (int)blockIdx.x - chunk * cs;
  const int swz = (r0 & 7) * (cs >> 3) + (r0 >> 3);
  const int bm = swz / chunkBn;
  const int bn = chunk * chunkBn + (swz - bm * chunkBn);
  const size_t abase = (size_t)bm * 128 * K;
  const size_t bbase = (size_t)bn * 128 * K;
  f32x4 acc[4][4] = {};
  for (int k0 = 0; k0 < K; k0 += 64) {
#pragma unroll
    for (int i = 0; i < 4; i++) {
      int idx8 = i * 256 + tid;
      int row = idx8 >> 3, ch = idx8 & 7;
      int sc = (ch ^ (row & 7)) << 3;
      gload_lds16(A + abase + (size_t)row * K + k0 + sc, As + idx8 * 8);
      gload_lds16(B + bbase + (size_t)row * K + k0 + sc, Bs + idx8 * 8);
    }
    __syncthreads();
#pragma unroll
    for (int ks = 0; ks < 2; ks++) {
      short8 af[4], bfr[4];
      int chunkc = ks * 4 + q;
#pragma unroll
      for (int mi = 0; mi < 4; mi++) {
        int row = wr * 64 + mi * 16 + l15;
        af[mi] = *(const short8*)&As[row * 64 + ((chunkc ^ (row & 7)) << 3)];
      }
#pragma unroll
      for (int ni = 0; ni < 4; ni++) {
        int row = wc * 64 + ni * 16 + l15;
        bfr[ni] = *(const short8*)&Bs[row * 64 + ((chunkc ^ (row & 7)) << 3)];
      }
#pragma unroll
      for (int mi = 0; mi < 4; mi++)
#pragma unroll
        for (int ni = 0; ni < 4; ni++)
          acc[mi][ni] = __builtin_amdgcn_mfma_f32_16x16x32_bf16(af[mi], bfr[ni], acc[mi][ni], 0, 0, 0);
    }
    __syncthreads();
  }
  // epilogue
#pragma unroll
  for (int mi = 0; mi < 4; mi++)
#pragma unroll
    for (int j = 0; j < 4; j++) {
      int rr = bm * 128 + wr * 64 + mi * 16 + q * 4 + j;
      if (EPI == 0) {
        // LSE partial over this wave's 64 cols
        float mx = -1e30f;
#pragma unroll
        for (int ni = 0; ni < 4; ni++) mx = fmaxf(mx, acc[mi][ni][j]);
        mx = fmaxf(mx, __shfl_xor(mx, 1, 64));
        mx = fmaxf(mx, __shfl_xor(mx, 2, 64));
        mx = fmaxf(mx, __shfl_xor(mx, 4, 64));
        mx = fmaxf(mx, __shfl_xor(mx, 8, 64));
        float sm = 0.f;
#pragma unroll
        for (int ni = 0; ni < 4; ni++) sm += expf(acc[mi][ni][j] - mx);
        sm += __shfl_xor(sm, 1, 64);
        sm += __shfl_xor(sm, 2, 64);
        sm += __shfl_xor(sm, 4, 64);
        sm += __shfl_xor(sm, 8, 64);
        if (l15 == 0) {
          int nt = (N >> 6);
          partM[(size_t)rr * nt + (bn << 1) + wc] = mx;
          partS[(size_t)rr * nt + (bn << 1) + wc] = sm;
        }
      }
#pragma unroll
      for (int ni = 0; ni < 4; ni++) {
        int cn = bn * 128 + wc * 64 + ni * 16 + l15;
        size_t off = (size_t)rr * N + cn;
        float vv = acc[mi][ni][j];
        if (EPI == 0) {
          __builtin_nontemporal_store(vv, (float*)Cp + off);
        } else if (EPI == 1) {
          ((u16*)Cp)[off] = f2bf(vv);
        } else if (EPI == 2) {
          ((float*)Cp)[off] = resid[off] + vv;
        }
      }
    }
}

// ---------------- flash attention ----------------
// q/k/v live in the fused QKV buffer (row stride 3072, offsets 0/1024/2048), POST-rope.
// grid: (qtile 0..15, bh 0..31), block 256 (4 waves x 32 q-rows)
__global__ __launch_bounds__(256) void attn_kernel(const u16* __restrict__ qkv,
                                                   u16* __restrict__ o) {
  __shared__ u16 Ks[64 * 64];
  __shared__ u16 Vt[64 * 64];
  __shared__ u16 Ps[4][32 * 64];
  const u16* q = qkv;
  const u16* k = qkv + D_MODEL;
  const u16* v = qkv + 2 * D_MODEL;
  const int tid = threadIdx.x, lane = tid & 63, wid = tid >> 6;
  const int qg = lane >> 4, l15 = lane & 15;
  const int qt = blockIdx.x;
  const int bh = blockIdx.y;
  const int b = bh >> 4, h = bh & 15;
  const int tok0 = b * TSEQ;
  const int hoff = h * HDIM;
  const int qrow0 = qt * 128 + wid * 32;

  short8 aq[2][2];
#pragma unroll
  for (int mi = 0; mi < 2; mi++)
#pragma unroll
    for (int ks = 0; ks < 2; ks++) {
      int r = qrow0 + mi * 16 + l15;
      int d = ks * 32 + qg * 8;
      aq[mi][ks] = *(const short8*)(q + (size_t)(tok0 + r) * QKV_STRIDE + hoff + d);
    }
  f32x4 oacc[2][4] = {};
  float mrow[2][4], lrow[2][4];
#pragma unroll
  for (int mi = 0; mi < 2; mi++)
#pragma unroll
    for (int j = 0; j < 4; j++) { mrow[mi][j] = -1e30f; lrow[mi][j] = 0.f; }

  const int nkt = (qt + 1) * 2;
  for (int kt = 0; kt < nkt; kt++) {
    const int kv0 = kt * 64;
    // stage K [64][64] (swizzled)
#pragma unroll
    for (int i = 0; i < 2; i++) {
      int c = tid + 256 * i;
      int row = c >> 3, col = (c & 7) * 8;
      short8 kv = *(const short8*)(k + (size_t)(tok0 + kv0 + row) * QKV_STRIDE + hoff + col);
      *(short8*)&Ks[row * 64 + (col ^ ((row & 7) << 3))] = kv;
    }
    // stage V^T: Vt[d][t] (swizzled)
    {
      int d = tid & 63, t4 = (tid >> 6) * 8;
#pragma unroll
      for (int half = 0; half < 2; half++) {
        int t0 = t4 + half * 32;
        short8 pk;
#pragma unroll
        for (int jj = 0; jj < 8; jj++)
          pk[jj] = (short)v[(size_t)(tok0 + kv0 + t0 + jj) * QKV_STRIDE + hoff + d];
        *(short8*)&Vt[d * 64 + (t0 ^ ((d & 7) << 3))] = pk;
      }
    }
    __syncthreads();
    f32x4 sc[2][4] = {};
#pragma unroll
    for (int ks = 0; ks < 2; ks++) {
      short8 bk[4];
      int kcol = ks * 32 + qg * 8;
#pragma unroll
      for (int ni = 0; ni < 4; ni++) {
        int r = ni * 16 + l15;
        bk[ni] = *(const short8*)&Ks[r * 64 + (kcol ^ ((r & 7) << 3))];
      }
#pragma unroll
      for (int mi = 0; mi < 2; mi++)
#pragma unroll
        for (int ni = 0; ni < 4; ni++)
          sc[mi][ni] = __builtin_amdgcn_mfma_f32_16x16x32_bf16(aq[mi][ks], bk[ni], sc[mi][ni], 0, 0, 0);
    }
    float pm[2][4];
#pragma unroll
    for (int mi = 0; mi < 2; mi++)
#pragma unroll
      for (int j = 0; j < 4; j++) pm[mi][j] = -1e30f;
#pragma unroll
    for (int mi = 0; mi < 2; mi++)
#pragma unroll
      for (int ni = 0; ni < 4; ni++)
#pragma unroll
        for (int j = 0; j < 4; j++) {
          int rq = qrow0 + mi * 16 + qg * 4 + j;
          int ck = kv0 + ni * 16 + l15;
          float s = sc[mi][ni][j] * 0.125f;
          if (ck > rq) s = -1e30f;
          sc[mi][ni][j] = s;
          pm[mi][j] = fmaxf(pm[mi][j], s);
        }
#pragma unroll
    for (int mi = 0; mi < 2; mi++)
#pragma unroll
      for (int j = 0; j < 4; j++) {
        float t = pm[mi][j];
        t = fmaxf(t, __shfl_xor(t, 1, 64));
        t = fmaxf(t, __shfl_xor(t, 2, 64));
        t = fmaxf(t, __shfl_xor(t, 4, 64));
        t = fmaxf(t, __shfl_xor(t, 8, 64));
        pm[mi][j] = t;
      }
#pragma unroll
    for (int mi = 0; mi < 2; mi++)
#pragma unroll
      for (int j = 0; j < 4; j++) {
        float mn = fmaxf(mrow[mi][j], pm[mi][j]);
        float fac = expf(mrow[mi][j] - mn);
        lrow[mi][j] *= fac;
#pragma unroll
        for (int df = 0; df < 4; df++) oacc[mi][df][j] *= fac;
        mrow[mi][j] = mn;
      }
    float psum[2][4] = {};
#pragma unroll
    for (int mi = 0; mi < 2; mi++)
#pragma unroll
      for (int ni = 0; ni < 4; ni++)
#pragma unroll
        for (int j = 0; j < 4; j++) {
          float p = expf(sc[mi][ni][j] - mrow[mi][j]);
          psum[mi][j] += p;
          int r32 = mi * 16 + qg * 4 + j;
          int cc = ni * 16 + l15;
          Ps[wid][r32 * 64 + (cc ^ ((r32 & 7) << 3))] = f2bf(p);
        }
#pragma unroll
    for (int mi = 0; mi < 2; mi++)
#pragma unroll
      for (int j = 0; j < 4; j++) {
        float t = psum[mi][j];
        t += __shfl_xor(t, 1, 64);
        t += __shfl_xor(t, 2, 64);
        t += __shfl_xor(t, 4, 64);
        t += __shfl_xor(t, 8, 64);
        lrow[mi][j] += t;
      }
#pragma unroll
    for (int kf = 0; kf < 2; kf++) {
      short8 pa[2], bv[4];
      int kcol = kf * 32 + qg * 8;
#pragma unroll
      for (int mi = 0; mi < 2; mi++) {
        int r = mi * 16 + l15;
        pa[mi] = *(const short8*)&Ps[wid][r * 64 + (kcol ^ ((r & 7) << 3))];
      }
#pragma unroll
      for (int df = 0; df < 4; df++) {
        int r = df * 16 + l15;
        bv[df] = *(const short8*)&Vt[r * 64 + (kcol ^ ((r & 7) << 3))];
      }
#pragma unroll
      for (int mi = 0; mi < 2; mi++)
#pragma unroll
        for (int df = 0; df < 4; df++)
          oacc[mi][df] = __builtin_amdgcn_mfma_f32_16x16x32_bf16(pa[mi], bv[df], oacc[mi][df], 0, 0, 0);
    }
    __syncthreads();
  }
#pragma unroll
  for (int mi = 0; mi < 2; mi++)
#pragma unroll
    for (int df = 0; df < 4; df++)
#pragma unroll
      for (int j = 0; j < 4; j++) {
        int r = qrow0 + mi * 16 + qg * 4 + j;
        int d = df * 16 + l15;
        float val = oacc[mi][df][j] / lrow[mi][j];
        o[(size_t)(tok0 + r) * D_MODEL + hoff + d] = f2bf(val);
      }
}

// ---------------- loss ----------------

__global__ void nll_finalize_kernel(const float* __restrict__ partM, const float* __restrict__ partS,
                                    const float* __restrict__ logits, const int* __restrict__ targets,
                                    float* __restrict__ nll) {
  int tok = blockIdx.x;
  int lane = threadIdx.x;    // 64
  const int NTL = V_SIZE >> 6;  // 500
  float m = -1e30f, s = 0.f;
  for (int i = lane; i < NTL; i += 64) {
    float m2 = partM[(size_t)tok * NTL + i];
    float s2 = partS[(size_t)tok * NTL + i];
    float nm = fmaxf(m, m2);
    s = s * expf(m - nm) + s2 * expf(m2 - nm);
    m = nm;
  }
#pragma unroll
  for (int mask = 1; mask < 64; mask <<= 1) {
    float m2 = __shfl_xor(m, mask, 64);
    float s2 = __shfl_xor(s, mask, 64);
    float nm = fmaxf(m, m2);
    s = s * expf(m - nm) + s2 * expf(m2 - nm);
    m = nm;
  }
  if (lane == 0)
    nll[tok] = m + logf(s) - logits[(size_t)tok * V_SIZE + targets[tok]];
}

__global__ void loss_reduce_kernel(const float* __restrict__ nll, float* __restrict__ out) {
  float s = 0.f;
  for (int i = threadIdx.x; i < BT; i += 256) s += nll[i];
#pragma unroll
  for (int mask = 1; mask < 64; mask <<= 1) s += __shfl_xor(s, mask, 64);
  __shared__ float sm[4];
  if ((threadIdx.x & 63) == 0) sm[threadIdx.x >> 6] = s;
  __syncthreads();
  if (threadIdx.x == 0) out[0] = (sm[0] + sm[1] + sm[2] + sm[3]) / (float)BT;
}

// ---------------- host launcher ----------------

extern "C" void kernel_launch(void* const* d_in, const int* in_sizes, int n_in,
                              void* d_out, int out_size, void* d_ws, size_t ws_size,
                              hipStream_t stream) {
  const int* idx = (const int*)d_in[0];
  const int* targets = (const int*)d_in[1];
  const float* embed = (const float*)d_in[2];
  const float* wq = (const float*)d_in[3];
  const float* wk = (const float*)d_in[4];
  const float* wv = (const float*)d_in[5];
  const float* wo = (const float*)d_in[6];
  const float* w_gate = (const float*)d_in[7];
  const float* w_up = (const float*)d_in[8];
  const float* w_down = (const float*)d_in[9];
  const float* attn_norm = (const float*)d_in[10];
  const float* mlp_norm = (const float*)d_in[11];
  const float* final_norm = (const float*)d_in[12];
  const float* lm_head = (const float*)d_in[13];
  float* out = (float*)d_out;

  char* ws = (char*)d_ws;
  size_t off = 0;
  auto alloc = [&](size_t bytes) {
    void* p = ws + off;
    off += (bytes + 255) & ~(size_t)255;
    return p;
  };
  const size_t DD = (size_t)D_MODEL * D_MODEL;
  float* rope_cos = (float*)alloc((size_t)TSEQ * 32 * 4);
  float* rope_sin = (float*)alloc((size_t)TSEQ * 32 * 4);
  float* X = (float*)alloc((size_t)BT * D_MODEL * 4);
  u16* Hb = (u16*)alloc((size_t)BT * D_MODEL * 2);
  u16* QKVb = (u16*)alloc((size_t)BT * QKV_STRIDE * 2);
  u16* Ob = (u16*)alloc((size_t)BT * D_MODEL * 2);
  u16* GUb = (u16*)alloc((size_t)BT * GU_STRIDE * 2);
  u16* Gb = (u16*)alloc((size_t)BT * HFF * 2);
  u16* WQKVT = (u16*)alloc((size_t)NLAYER * QKV_STRIDE * D_MODEL * 2);
  u16* WOT = (u16*)alloc((size_t)NLAYER * DD * 2);
  u16* WGU = (u16*)alloc((size_t)NLAYER * GU_STRIDE * D_MODEL * 2);
  u16* WDT = (u16*)alloc((size_t)NLAYER * D_MODEL * HFF * 2);
  u16* LMH = (u16*)alloc((size_t)V_SIZE * D_MODEL * 2);
  float* NLLb = (float*)alloc((size_t)BT * 4);
  float* PartM = (float*)alloc((size_t)BT * (V_SIZE >> 6) * 4);
  float* PartS = (float*)alloc((size_t)BT * (V_SIZE >> 6) * 4);

  rope_table_kernel<<<256, 256, 0, stream>>>(rope_cos, rope_sin);
  convert_bf16_kernel<<<4096, 256, 0, stream>>>(lm_head, LMH, (long)V_SIZE * D_MODEL / 8);
  embed_gather_kernel<<<BT, 256, 0, stream>>>(idx, embed, X);

  const long QKVW = (long)QKV_STRIDE * D_MODEL;
  const long GUW = (long)GU_STRIDE * D_MODEL;
  const long DW = (long)D_MODEL * HFF;
  transpose_bf16_kernel<<<dim3(32, 32, NLAYER), 256, 0, stream>>>(wq, WQKVT, D_MODEL, D_MODEL, DD, QKVW);
  transpose_bf16_kernel<<<dim3(32, 32, NLAYER), 256, 0, stream>>>(wk, WQKVT + DD, D_MODEL, D_MODEL, DD, QKVW);
  transpose_bf16_kernel<<<dim3(32, 32, NLAYER), 256, 0, stream>>>(wv, WQKVT + 2 * DD, D_MODEL, D_MODEL, DD, QKVW);
  transpose_bf16_kernel<<<dim3(32, 32, NLAYER), 256, 0, stream>>>(wo, WOT, D_MODEL, D_MODEL, DD, DD);
  transpose_bf16_kernel<<<dim3(128, 32, NLAYER), 256, 0, stream>>>(w_gate, WGU, D_MODEL, HFF, DW, GUW);
  transpose_bf16_kernel<<<dim3(128, 32, NLAYER), 256, 0, stream>>>(w_up, WGU + (size_t)HFF * D_MODEL, D_MODEL, HFF, DW, GUW);
  transpose_bf16_kernel<<<dim3(32, 128, NLAYER), 256, 0, stream>>>(w_down, WDT, HFF, D_MODEL, DW, DW);

  for (int l = 0; l < NLAYER; l++) {
    rmsnorm_kernel<<<BT, 256, 0, stream>>>(X, attn_norm + (size_t)l * D_MODEL, Hb);
    gemm128_kernel<1><<<(QKV_STRIDE / 128) * (BT / 128), 256, 0, stream>>>(
        Hb, WQKVT + (size_t)l * QKVW, QKVb, nullptr, nullptr, nullptr, BT, QKV_STRIDE, D_MODEL,
        QKV_STRIDE / 128);
    rope_apply_kernel<<<8192, 256, 0, stream>>>(QKVb, rope_cos, rope_sin);
    attn_kernel<<<dim3(16, 32), 256, 0, stream>>>(QKVb, Ob);
    gemm128_kernel<2><<<(D_MODEL / 128) * (BT / 128), 256, 0, stream>>>(
        Ob, WOT + (size_t)l * DD, X, X, nullptr, nullptr, BT, D_MODEL, D_MODEL,
        D_MODEL / 128);

    rmsnorm_kernel<<<BT, 256, 0, stream>>>(X, mlp_norm + (size_t)l * D_MODEL, Hb);
    gemm128_kernel<1><<<(GU_STRIDE / 128) * (BT / 128), 256, 0, stream>>>(
        Hb, WGU + (size_t)l * GUW, GUb, nullptr, nullptr, nullptr, BT, GU_STRIDE, D_MODEL,
        32);
    silu_mul_kernel<<<8192, 256, 0, stream>>>(GUb, Gb);
    gemm128_kernel<2><<<(D_MODEL / 128) * (BT / 128), 256, 0, stream>>>(
        Gb, WDT + (size_t)l * DW, X, X, nullptr, nullptr, BT, D_MODEL, HFF,
        D_MODEL / 128);
  }

  rmsnorm_kernel<<<BT, 256, 0, stream>>>(X, final_norm, Hb);
  gemm128_kernel<0><<<(V_SIZE / 128) * (BT / 128), 256, 0, stream>>>(
      Hb, LMH, out, nullptr, PartM, PartS, BT, V_SIZE, D_MODEL,
      50);
  nll_finalize_kernel<<<BT, 64, 0, stream>>>(PartM, PartS, out, targets, NLLb);
  loss_reduce_kernel<<<1, 256, 0, stream>>>(NLLb, out + (size_t)BT * V_SIZE);
}

// Round 10
// 2166.558 us; speedup vs baseline: 1.2686x; 1.0507x over previous
//
#include <hip/hip_runtime.h>

typedef __attribute__((ext_vector_type(8))) short short8;
typedef __attribute__((ext_vector_type(4))) float f32x4;
typedef __attribute__((ext_vector_type(8))) unsigned short u16x8;
typedef unsigned short u16;

#define V_SIZE 32000
#define D_MODEL 1024
#define HFF 4096
#define NHEAD 16
#define HDIM 64
#define NLAYER 4
#define BT 4096   // B*T tokens
#define TSEQ 2048
#define QKV_STRIDE 3072
#define GU_STRIDE 8192

__device__ __forceinline__ u16 f2bf(float f) {
  union { float f; unsigned u; } v; v.f = f;
  unsigned r = v.u + 0x7fffu + ((v.u >> 16) & 1u);
  return (u16)(r >> 16);
}
__device__ __forceinline__ float bf2f(u16 h) {
  union { unsigned u; float f; } v; v.u = ((unsigned)h) << 16;
  return v.f;
}

__device__ __forceinline__ void gload_lds16(const void* g, void* l) {
  __builtin_amdgcn_global_load_lds((__attribute__((address_space(1))) void*)g,
                                   (__attribute__((address_space(3))) void*)l, 16, 0, 0);
}

// ---------------- elementwise / small kernels ----------------

__global__ void rope_table_kernel(float* __restrict__ cosb, float* __restrict__ sinb) {
  int i = blockIdx.x * 256 + threadIdx.x;       // 2048*32 = 65536 items
  int t = i >> 5, fi = i & 31;
  float freq = exp2f(-(2.0f * (float)fi / 64.0f) * log2f(10000.0f));
  float ang = (float)t * freq;
  cosb[i] = cosf(ang);
  sinb[i] = sinf(ang);
}

__global__ void convert_bf16_kernel(const float* __restrict__ src, u16* __restrict__ dst, long n8) {
  long i = (long)blockIdx.x * 256 + threadIdx.x;
  long stride = (long)gridDim.x * 256;
  for (; i < n8; i += stride) {
    const float4* s = (const float4*)(src + i * 8);
    float4 a = s[0], b = s[1];
    u16x8 r;
    r[0] = f2bf(a.x); r[1] = f2bf(a.y); r[2] = f2bf(a.z); r[3] = f2bf(a.w);
    r[4] = f2bf(b.x); r[5] = f2bf(b.y); r[6] = f2bf(b.z); r[7] = f2bf(b.w);
    *(u16x8*)(dst + i * 8) = r;
  }
}

// src [R][C] fp32 -> dst bf16. rowMode: 0 -> dst row = c (plain transpose)
//   1 -> row = ((c>>6)<<7) | (c&63)        (gate cols interleaved at 64-granularity)
//   2 -> row = ((c>>6)<<7) | 64 | (c&63)   (up cols, partner rows)
__global__ __launch_bounds__(256) void transpose_bf16_kernel(const float* __restrict__ src0,
                                                             u16* __restrict__ dst0, int R, int C,
                                                             long srcStride, long dstStride,
                                                             int rowMode) {
  __shared__ float tile[32][33];
  const float* src = src0 + (size_t)blockIdx.z * srcStride;
  u16* dst = dst0 + (size_t)blockIdx.z * dstStride;
  int tx = threadIdx.x & 31, ty = threadIdx.x >> 5;  // 32 x 8
  int bx = blockIdx.x, by = blockIdx.y;
#pragma unroll
  for (int i = 0; i < 32; i += 8) {
    int r = by * 32 + ty + i, c = bx * 32 + tx;
    tile[ty + i][tx] = src[(size_t)r * C + c];
  }
  __syncthreads();
#pragma unroll
  for (int i = 0; i < 32; i += 8) {
    int c = bx * 32 + ty + i;   // source col
    int r = by * 32 + tx;       // source row -> dst col
    int drow = c;
    if (rowMode == 1) drow = ((c >> 6) << 7) | (c & 63);
    else if (rowMode == 2) drow = ((c >> 6) << 7) | 64 | (c & 63);
    dst[(size_t)drow * R + r] = f2bf(tile[tx][ty + i]);
  }
}

__global__ void embed_gather_kernel(const int* __restrict__ idx, const float* __restrict__ embed,
                                    float* __restrict__ x) {
  int t = blockIdx.x;
  int id = idx[t];
  ((float4*)x)[(size_t)t * 256 + threadIdx.x] = ((const float4*)embed)[(size_t)id * 256 + threadIdx.x];
}

// x fp32 [4096][1024] -> h bf16, h = x * rsqrt(mean(x^2)+eps) * w
__global__ __launch_bounds__(256) void rmsnorm_kernel(const float* __restrict__ x,
                                                      const float* __restrict__ w,
                                                      u16* __restrict__ h) {
  int row = blockIdx.x;
  const float4* xr = (const float4*)(x + (size_t)row * D_MODEL);
  float4 v = xr[threadIdx.x];
  float ss = v.x * v.x + v.y * v.y + v.z * v.z + v.w * v.w;
#pragma unroll
  for (int m = 32; m > 0; m >>= 1) ss += __shfl_xor(ss, m, 64);
  __shared__ float wsum[4];
  if ((threadIdx.x & 63) == 0) wsum[threadIdx.x >> 6] = ss;
  __syncthreads();
  float tot = wsum[0] + wsum[1] + wsum[2] + wsum[3];
  float rinv = rsqrtf(tot * (1.0f / (float)D_MODEL) + 1e-6f);
  float4 wv = ((const float4*)w)[threadIdx.x];
  u16 out[4];
  out[0] = f2bf(v.x * rinv * wv.x);
  out[1] = f2bf(v.y * rinv * wv.y);
  out[2] = f2bf(v.z * rinv * wv.z);
  out[3] = f2bf(v.w * rinv * wv.w);
  u16* hp = h + (size_t)row * D_MODEL + threadIdx.x * 4;
  hp[0] = out[0]; hp[1] = out[1]; hp[2] = out[2]; hp[3] = out[3];
}

// ---------------- GEMM 128x128 (m97 structure, both-sides swizzle, 4 blocks/CU) ----
// C[M,N] = A[M,K](bf16) * B[N,K](bf16)^T. 256 threads = 4 waves (2x2).
// bn-chunked + XCD-swizzled block mapping (R9): B chunk stays L3-resident.
// EPI: 0 = fp32 nontemporal store + per-(row,64col) LSE partials (lm-head)
//      1 = bf16 store
//      2 = fp32 residual add (o-proj / down-proj)
//      4 = bf16 store with fused RoPE on cols < 2048 (QKV; wave block == one head,
//          rotation pair (fi, fi+32) == acc[ni] / acc[ni+2])
//      5 = fused silu-mul (B rows 64-col-interleaved gate/up; wc=1 waves pass `up`
//          to wc=0 via LDS; bf16 store at N/2 width)
template <int EPI>
__global__ __launch_bounds__(256, 4) void gemm128_kernel(const u16* __restrict__ A,
                                                         const u16* __restrict__ B, void* Cp,
                                                         const float* __restrict__ resid,
                                                         float* __restrict__ partM,
                                                         float* __restrict__ partS,
                                                         const float* __restrict__ cosb,
                                                         const float* __restrict__ sinb,
                                                         int M, int N, int K, int chunkBn) {
  __shared__ __align__(16) u16 smem_ab[2][128 * 64];   // 32 KiB total
  u16* As = smem_ab[0];
  u16* Bs = smem_ab[1];
  const int tid = threadIdx.x;
  const int lane = tid & 63, wid = tid >> 6;
  const int wr = wid >> 1, wc = wid & 1;
  const int q = lane >> 4, l15 = lane & 15;
  const int nbm = M >> 7;
  // chunked + XCD-swizzled block mapping
  const int cs = nbm * chunkBn;            // blocks per chunk (nbm=32 -> cs%8==0)
  const int chunk = (int)blockIdx.x / cs;
  const int r0 = (int)blockIdx.x - chunk * cs;
  const int swz = (r0 & 7) * (cs >> 3) + (r0 >> 3);
  const int bm = swz / chunkBn;
  const int bn = chunk * chunkBn + (swz - bm * chunkBn);
  const size_t abase = (size_t)bm * 128 * K;
  const size_t bbase = (size_t)bn * 128 * K;
  f32x4 acc[4][4] = {};
  for (int k0 = 0; k0 < K; k0 += 64) {
#pragma unroll
    for (int i = 0; i < 4; i++) {
      int idx8 = i * 256 + tid;
      int row = idx8 >> 3, ch = idx8 & 7;
      int sc = (ch ^ (row & 7)) << 3;
      gload_lds16(A + abase + (size_t)row * K + k0 + sc, As + idx8 * 8);
      gload_lds16(B + bbase + (size_t)row * K + k0 + sc, Bs + idx8 * 8);
    }
    __syncthreads();
#pragma unroll
    for (int ks = 0; ks < 2; ks++) {
      short8 af[4], bfr[4];
      int chunkc = ks * 4 + q;
#pragma unroll
      for (int mi = 0; mi < 4; mi++) {
        int row = wr * 64 + mi * 16 + l15;
        af[mi] = *(const short8*)&As[row * 64 + ((chunkc ^ (row & 7)) << 3)];
      }
#pragma unroll
      for (int ni = 0; ni < 4; ni++) {
        int row = wc * 64 + ni * 16 + l15;
        bfr[ni] = *(const short8*)&Bs[row * 64 + ((chunkc ^ (row & 7)) << 3)];
      }
#pragma unroll
      for (int mi = 0; mi < 4; mi++)
#pragma unroll
        for (int ni = 0; ni < 4; ni++)
          acc[mi][ni] = __builtin_amdgcn_mfma_f32_16x16x32_bf16(af[mi], bfr[ni], acc[mi][ni], 0, 0, 0);
    }
    __syncthreads();
  }

  // ---- EPI 5: fused silu-mul via cross-wave LDS exchange ----
  if (EPI == 5) {
    float* upf = (float*)&smem_ab[0][0];   // 128x64 floats = 32 KiB (reuses As+Bs)
    if (wc == 1) {
#pragma unroll
      for (int mi = 0; mi < 4; mi++)
#pragma unroll
        for (int ni = 0; ni < 4; ni++)
#pragma unroll
          for (int j = 0; j < 4; j++) {
            int r = wr * 64 + mi * 16 + q * 4 + j;
            int cswz = (ni ^ ((r >> 2) & 3)) * 16 + l15;   // bank-spread across q
            upf[r * 64 + cswz] = acc[mi][ni][j];
          }
    }
    __syncthreads();
    if (wc == 0) {
#pragma unroll
      for (int mi = 0; mi < 4; mi++)
#pragma unroll
        for (int j = 0; j < 4; j++) {
          int rloc = wr * 64 + mi * 16 + q * 4 + j;
          int rr = bm * 128 + rloc;
#pragma unroll
          for (int ni = 0; ni < 4; ni++) {
            int cswz = (ni ^ ((rloc >> 2) & 3)) * 16 + l15;
            float g = acc[mi][ni][j];
            float u = upf[rloc * 64 + cswz];
            float rsl = g / (1.0f + expf(-g)) * u;
            ((u16*)Cp)[(size_t)rr * (N >> 1) + bn * 64 + ni * 16 + l15] = f2bf(rsl);
          }
        }
    }
    return;
  }

  // ---- standard epilogues ----
#pragma unroll
  for (int mi = 0; mi < 4; mi++)
#pragma unroll
    for (int j = 0; j < 4; j++) {
      int rr = bm * 128 + wr * 64 + mi * 16 + q * 4 + j;
      float vv[4];
#pragma unroll
      for (int ni = 0; ni < 4; ni++) vv[ni] = acc[mi][ni][j];
      if (EPI == 0) {
        float mx = fmaxf(fmaxf(vv[0], vv[1]), fmaxf(vv[2], vv[3]));
        mx = fmaxf(mx, __shfl_xor(mx, 1, 64));
        mx = fmaxf(mx, __shfl_xor(mx, 2, 64));
        mx = fmaxf(mx, __shfl_xor(mx, 4, 64));
        mx = fmaxf(mx, __shfl_xor(mx, 8, 64));
        float sm = 0.f;
#pragma unroll
        for (int ni = 0; ni < 4; ni++) sm += expf(vv[ni] - mx);
        sm += __shfl_xor(sm, 1, 64);
        sm += __shfl_xor(sm, 2, 64);
        sm += __shfl_xor(sm, 4, 64);
        sm += __shfl_xor(sm, 8, 64);
        if (l15 == 0) {
          int nt = (N >> 6);
          partM[(size_t)rr * nt + (bn << 1) + wc] = mx;
          partS[(size_t)rr * nt + (bn << 1) + wc] = sm;
        }
      }
      if (EPI == 4) {
        // RoPE for Q (cols 0..1023) and K (1024..2047); V untouched.
        if (((bn << 1) + wc) < 32) {   // wave-uniform
          int t = rr & (TSEQ - 1);
#pragma unroll
          for (int ni = 0; ni < 2; ni++) {
            int fi = ni * 16 + l15;
            float c = cosb[t * 32 + fi], s = sinb[t * 32 + fi];
            float x1 = vv[ni], x2 = vv[ni + 2];
            vv[ni] = x1 * c - x2 * s;
            vv[ni + 2] = x2 * c + x1 * s;
          }
        }
      }
#pragma unroll
      for (int ni = 0; ni < 4; ni++) {
        int cn = bn * 128 + wc * 64 + ni * 16 + l15;
        size_t off = (size_t)rr * N + cn;
        if (EPI == 0) {
          __builtin_nontemporal_store(vv[ni], (float*)Cp + off);
        } else if (EPI == 1 || EPI == 4) {
          ((u16*)Cp)[off] = f2bf(vv[ni]);
        } else if (EPI == 2) {
          ((float*)Cp)[off] = resid[off] + vv[ni];
        }
      }
    }
}

// ---------------- flash attention ----------------
// q/k/v live in the fused QKV buffer (row stride 3072, offsets 0/1024/2048), POST-rope.
// grid: (qtile 0..15, bh 0..31), block 256 (4 waves x 32 q-rows)
__global__ __launch_bounds__(256) void attn_kernel(const u16* __restrict__ qkv,
                                                   u16* __restrict__ o) {
  __shared__ u16 Ks[64 * 64];
  __shared__ u16 Vt[64 * 64];
  __shared__ u16 Ps[4][32 * 64];
  const u16* q = qkv;
  const u16* k = qkv + D_MODEL;
  const u16* v = qkv + 2 * D_MODEL;
  const int tid = threadIdx.x, lane = tid & 63, wid = tid >> 6;
  const int qg = lane >> 4, l15 = lane & 15;
  const int qt = blockIdx.x;
  const int bh = blockIdx.y;
  const int b = bh >> 4, h = bh & 15;
  const int tok0 = b * TSEQ;
  const int hoff = h * HDIM;
  const int qrow0 = qt * 128 + wid * 32;

  short8 aq[2][2];
#pragma unroll
  for (int mi = 0; mi < 2; mi++)
#pragma unroll
    for (int ks = 0; ks < 2; ks++) {
      int r = qrow0 + mi * 16 + l15;
      int d = ks * 32 + qg * 8;
      aq[mi][ks] = *(const short8*)(q + (size_t)(tok0 + r) * QKV_STRIDE + hoff + d);
    }
  f32x4 oacc[2][4] = {};
  float mrow[2][4], lrow[2][4];
#pragma unroll
  for (int mi = 0; mi < 2; mi++)
#pragma unroll
    for (int j = 0; j < 4; j++) { mrow[mi][j] = -1e30f; lrow[mi][j] = 0.f; }

  const int nkt = (qt + 1) * 2;
  for (int kt = 0; kt < nkt; kt++) {
    const int kv0 = kt * 64;
    // stage K [64][64] (swizzled)
#pragma unroll
    for (int i = 0; i < 2; i++) {
      int c = tid + 256 * i;
      int row = c >> 3, col = (c & 7) * 8;
      short8 kv = *(const short8*)(k + (size_t)(tok0 + kv0 + row) * QKV_STRIDE + hoff + col);
      *(short8*)&Ks[row * 64 + (col ^ ((row & 7) << 3))] = kv;
    }
    // stage V^T: Vt[d][t] (swizzled)
    {
      int d = tid & 63, t4 = (tid >> 6) * 8;
#pragma unroll
      for (int half = 0; half < 2; half++) {
        int t0 = t4 + half * 32;
        short8 pk;
#pragma unroll
        for (int jj = 0; jj < 8; jj++)
          pk[jj] = (short)v[(size_t)(tok0 + kv0 + t0 + jj) * QKV_STRIDE + hoff + d];
        *(short8*)&Vt[d * 64 + (t0 ^ ((d & 7) << 3))] = pk;
      }
    }
    __syncthreads();
    f32x4 sc[2][4] = {};
#pragma unroll
    for (int ks = 0; ks < 2; ks++) {
      short8 bk[4];
      int kcol = ks * 32 + qg * 8;
#pragma unroll
      for (int ni = 0; ni < 4; ni++) {
        int r = ni * 16 + l15;
        bk[ni] = *(const short8*)&Ks[r * 64 + (kcol ^ ((r & 7) << 3))];
      }
#pragma unroll
      for (int mi = 0; mi < 2; mi++)
#pragma unroll
        for (int ni = 0; ni < 4; ni++)
          sc[mi][ni] = __builtin_amdgcn_mfma_f32_16x16x32_bf16(aq[mi][ks], bk[ni], sc[mi][ni], 0, 0, 0);
    }
    float pm[2][4];
#pragma unroll
    for (int mi = 0; mi < 2; mi++)
#pragma unroll
      for (int j = 0; j < 4; j++) pm[mi][j] = -1e30f;
#pragma unroll
    for (int mi = 0; mi < 2; mi++)
#pragma unroll
      for (int ni = 0; ni < 4; ni++)
#pragma unroll
        for (int j = 0; j < 4; j++) {
          int rq = qrow0 + mi * 16 + qg * 4 + j;
          int ck = kv0 + ni * 16 + l15;
          float s = sc[mi][ni][j] * 0.125f;
          if (ck > rq) s = -1e30f;
          sc[mi][ni][j] = s;
          pm[mi][j] = fmaxf(pm[mi][j], s);
        }
#pragma unroll
    for (int mi = 0; mi < 2; mi++)
#pragma unroll
      for (int j = 0; j < 4; j++) {
        float t = pm[mi][j];
        t = fmaxf(t, __shfl_xor(t, 1, 64));
        t = fmaxf(t, __shfl_xor(t, 2, 64));
        t = fmaxf(t, __shfl_xor(t, 4, 64));
        t = fmaxf(t, __shfl_xor(t, 8, 64));
        pm[mi][j] = t;
      }
#pragma unroll
    for (int mi = 0; mi < 2; mi++)
#pragma unroll
      for (int j = 0; j < 4; j++) {
        float mn = fmaxf(mrow[mi][j], pm[mi][j]);
        float fac = expf(mrow[mi][j] - mn);
        lrow[mi][j] *= fac;
#pragma unroll
        for (int df = 0; df < 4; df++) oacc[mi][df][j] *= fac;
        mrow[mi][j] = mn;
      }
    float psum[2][4] = {};
#pragma unroll
    for (int mi = 0; mi < 2; mi++)
#pragma unroll
      for (int ni = 0; ni < 4; ni++)
#pragma unroll
        for (int j = 0; j < 4; j++) {
          float p = expf(sc[mi][ni][j] - mrow[mi][j]);
          psum[mi][j] += p;
          int r32 = mi * 16 + qg * 4 + j;
          int cc = ni * 16 + l15;
          Ps[wid][r32 * 64 + (cc ^ ((r32 & 7) << 3))] = f2bf(p);
        }
#pragma unroll
    for (int mi = 0; mi < 2; mi++)
#pragma unroll
      for (int j = 0; j < 4; j++) {
        float t = psum[mi][j];
        t += __shfl_xor(t, 1, 64);
        t += __shfl_xor(t, 2, 64);
        t += __shfl_xor(t, 4, 64);
        t += __shfl_xor(t, 8, 64);
        lrow[mi][j] += t;
      }
#pragma unroll
    for (int kf = 0; kf < 2; kf++) {
      short8 pa[2], bv[4];
      int kcol = kf * 32 + qg * 8;
#pragma unroll
      for (int mi = 0; mi < 2; mi++) {
        int r = mi * 16 + l15;
        pa[mi] = *(const short8*)&Ps[wid][r * 64 + (kcol ^ ((r & 7) << 3))];
      }
#pragma unroll
      for (int df = 0; df < 4; df++) {
        int r = df * 16 + l15;
        bv[df] = *(const short8*)&Vt[r * 64 + (kcol ^ ((r & 7) << 3))];
      }
#pragma unroll
      for (int mi = 0; mi < 2; mi++)
#pragma unroll
        for (int df = 0; df < 4; df++)
          oacc[mi][df] = __builtin_amdgcn_mfma_f32_16x16x32_bf16(pa[mi], bv[df], oacc[mi][df], 0, 0, 0);
    }
    __syncthreads();
  }
#pragma unroll
  for (int mi = 0; mi < 2; mi++)
#pragma unroll
    for (int df = 0; df < 4; df++)
#pragma unroll
      for (int j = 0; j < 4; j++) {
        int r = qrow0 + mi * 16 + qg * 4 + j;
        int d = df * 16 + l15;
        float val = oacc[mi][df][j] / lrow[mi][j];
        o[(size_t)(tok0 + r) * D_MODEL + hoff + d] = f2bf(val);
      }
}

// ---------------- loss ----------------

__global__ void nll_finalize_kernel(const float* __restrict__ partM, const float* __restrict__ partS,
                                    const float* __restrict__ logits, const int* __restrict__ targets,
                                    float* __restrict__ nll) {
  int tok = blockIdx.x;
  int lane = threadIdx.x;    // 64
  const int NTL = V_SIZE >> 6;  // 500
  float m = -1e30f, s = 0.f;
  for (int i = lane; i < NTL; i += 64) {
    float m2 = partM[(size_t)tok * NTL + i];
    float s2 = partS[(size_t)tok * NTL + i];
    float nm = fmaxf(m, m2);
    s = s * expf(m - nm) + s2 * expf(m2 - nm);
    m = nm;
  }
#pragma unroll
  for (int mask = 1; mask < 64; mask <<= 1) {
    float m2 = __shfl_xor(m, mask, 64);
    float s2 = __shfl_xor(s, mask, 64);
    float nm = fmaxf(m, m2);
    s = s * expf(m - nm) + s2 * expf(m2 - nm);
    m = nm;
  }
  if (lane == 0)
    nll[tok] = m + logf(s) - logits[(size_t)tok * V_SIZE + targets[tok]];
}

__global__ void loss_reduce_kernel(const float* __restrict__ nll, float* __restrict__ out) {
  float s = 0.f;
  for (int i = threadIdx.x; i < BT; i += 256) s += nll[i];
#pragma unroll
  for (int mask = 1; mask < 64; mask <<= 1) s += __shfl_xor(s, mask, 64);
  __shared__ float sm[4];
  if ((threadIdx.x & 63) == 0) sm[threadIdx.x >> 6] = s;
  __syncthreads();
  if (threadIdx.x == 0) out[0] = (sm[0] + sm[1] + sm[2] + sm[3]) / (float)BT;
}

// ---------------- host launcher ----------------

extern "C" void kernel_launch(void* const* d_in, const int* in_sizes, int n_in,
                              void* d_out, int out_size, void* d_ws, size_t ws_size,
                              hipStream_t stream) {
  const int* idx = (const int*)d_in[0];
  const int* targets = (const int*)d_in[1];
  const float* embed = (const float*)d_in[2];
  const float* wq = (const float*)d_in[3];
  const float* wk = (const float*)d_in[4];
  const float* wv = (const float*)d_in[5];
  const float* wo = (const float*)d_in[6];
  const float* w_gate = (const float*)d_in[7];
  const float* w_up = (const float*)d_in[8];
  const float* w_down = (const float*)d_in[9];
  const float* attn_norm = (const float*)d_in[10];
  const float* mlp_norm = (const float*)d_in[11];
  const float* final_norm = (const float*)d_in[12];
  const float* lm_head = (const float*)d_in[13];
  float* out = (float*)d_out;

  char* ws = (char*)d_ws;
  size_t off = 0;
  auto alloc = [&](size_t bytes) {
    void* p = ws + off;
    off += (bytes + 255) & ~(size_t)255;
    return p;
  };
  const size_t DD = (size_t)D_MODEL * D_MODEL;
  float* rope_cos = (float*)alloc((size_t)TSEQ * 32 * 4);
  float* rope_sin = (float*)alloc((size_t)TSEQ * 32 * 4);
  float* X = (float*)alloc((size_t)BT * D_MODEL * 4);
  u16* Hb = (u16*)alloc((size_t)BT * D_MODEL * 2);
  u16* QKVb = (u16*)alloc((size_t)BT * QKV_STRIDE * 2);
  u16* Ob = (u16*)alloc((size_t)BT * D_MODEL * 2);
  u16* Gb = (u16*)alloc((size_t)BT * HFF * 2);
  u16* WQKVT = (u16*)alloc((size_t)NLAYER * QKV_STRIDE * D_MODEL * 2);
  u16* WOT = (u16*)alloc((size_t)NLAYER * DD * 2);
  u16* WGU = (u16*)alloc((size_t)NLAYER * GU_STRIDE * D_MODEL * 2);
  u16* WDT = (u16*)alloc((size_t)NLAYER * D_MODEL * HFF * 2);
  u16* LMH = (u16*)alloc((size_t)V_SIZE * D_MODEL * 2);
  float* NLLb = (float*)alloc((size_t)BT * 4);
  float* PartM = (float*)alloc((size_t)BT * (V_SIZE >> 6) * 4);
  float* PartS = (float*)alloc((size_t)BT * (V_SIZE >> 6) * 4);

  rope_table_kernel<<<256, 256, 0, stream>>>(rope_cos, rope_sin);
  convert_bf16_kernel<<<4096, 256, 0, stream>>>(lm_head, LMH, (long)V_SIZE * D_MODEL / 8);
  embed_gather_kernel<<<BT, 256, 0, stream>>>(idx, embed, X);

  const long QKVW = (long)QKV_STRIDE * D_MODEL;
  const long GUW = (long)GU_STRIDE * D_MODEL;
  const long DW = (long)D_MODEL * HFF;
  transpose_bf16_kernel<<<dim3(32, 32, NLAYER), 256, 0, stream>>>(wq, WQKVT, D_MODEL, D_MODEL, DD, QKVW, 0);
  transpose_bf16_kernel<<<dim3(32, 32, NLAYER), 256, 0, stream>>>(wk, WQKVT + DD, D_MODEL, D_MODEL, DD, QKVW, 0);
  transpose_bf16_kernel<<<dim3(32, 32, NLAYER), 256, 0, stream>>>(wv, WQKVT + 2 * DD, D_MODEL, D_MODEL, DD, QKVW, 0);
  transpose_bf16_kernel<<<dim3(32, 32, NLAYER), 256, 0, stream>>>(wo, WOT, D_MODEL, D_MODEL, DD, DD, 0);
  // gate/up interleaved at 64-col granularity: rows [128g..128g+63]=gate, [+64..+127]=up
  transpose_bf16_kernel<<<dim3(128, 32, NLAYER), 256, 0, stream>>>(w_gate, WGU, D_MODEL, HFF, DW, GUW, 1);
  transpose_bf16_kernel<<<dim3(128, 32, NLAYER), 256, 0, stream>>>(w_up, WGU, D_MODEL, HFF, DW, GUW, 2);
  transpose_bf16_kernel<<<dim3(32, 128, NLAYER), 256, 0, stream>>>(w_down, WDT, HFF, D_MODEL, DW, DW, 0);

  for (int l = 0; l < NLAYER; l++) {
    rmsnorm_kernel<<<BT, 256, 0, stream>>>(X, attn_norm + (size_t)l * D_MODEL, Hb);
    gemm128_kernel<4><<<(QKV_STRIDE / 128) * (BT / 128), 256, 0, stream>>>(
        Hb, WQKVT + (size_t)l * QKVW, QKVb, nullptr, nullptr, nullptr, rope_cos, rope_sin,
        BT, QKV_STRIDE, D_MODEL, QKV_STRIDE / 128);
    attn_kernel<<<dim3(16, 32), 256, 0, stream>>>(QKVb, Ob);
    gemm128_kernel<2><<<(D_MODEL / 128) * (BT / 128), 256, 0, stream>>>(
        Ob, WOT + (size_t)l * DD, X, X, nullptr, nullptr, nullptr, nullptr,
        BT, D_MODEL, D_MODEL, D_MODEL / 128);

    rmsnorm_kernel<<<BT, 256, 0, stream>>>(X, mlp_norm + (size_t)l * D_MODEL, Hb);
    gemm128_kernel<5><<<(GU_STRIDE / 128) * (BT / 128), 256, 0, stream>>>(
        Hb, WGU + (size_t)l * GUW, Gb, nullptr, nullptr, nullptr, nullptr, nullptr,
        BT, GU_STRIDE, D_MODEL, 32);
    gemm128_kernel<2><<<(D_MODEL / 128) * (BT / 128), 256, 0, stream>>>(
        Gb, WDT + (size_t)l * DW, X, X, nullptr, nullptr, nullptr, nullptr,
        BT, D_MODEL, HFF, D_MODEL / 128);
  }

  rmsnorm_kernel<<<BT, 256, 0, stream>>>(X, final_norm, Hb);
  gemm128_kernel<0><<<(V_SIZE / 128) * (BT / 128), 256, 0, stream>>>(
      Hb, LMH, out, nullptr, PartM, PartS, nullptr, nullptr,
      BT, V_SIZE, D_MODEL, 50);
  nll_finalize_kernel<<<BT, 64, 0, stream>>>(PartM, PartS, out, targets, NLLb);
  loss_reduce_kernel<<<1, 256, 0, stream>>>(NLLb, out + (size_t)BT * V_SIZE);
}

// Round 11
// 2119.618 us; speedup vs baseline: 1.2967x; 1.0221x over previous
//
#include <hip/hip_runtime.h>

typedef __attribute__((ext_vector_type(8))) short short8;
typedef __attribute__((ext_vector_type(4))) float f32x4;
typedef __attribute__((ext_vector_type(8))) unsigned short u16x8;
typedef unsigned short u16;

#define V_SIZE 32000
#define D_MODEL 1024
#define HFF 4096
#define NHEAD 16
#define HDIM 64
#define NLAYER 4
#define BT 4096   // B*T tokens
#define TSEQ 2048
#define QKV_STRIDE 3072
#define GU_STRIDE 8192

__device__ __forceinline__ u16 f2bf(float f) {
  union { float f; unsigned u; } v; v.f = f;
  unsigned r = v.u + 0x7fffu + ((v.u >> 16) & 1u);
  return (u16)(r >> 16);
}
__device__ __forceinline__ float bf2f(u16 h) {
  union { unsigned u; float f; } v; v.u = ((unsigned)h) << 16;
  return v.f;
}

__device__ __forceinline__ void gload_lds16(const void* g, void* l) {
  __builtin_amdgcn_global_load_lds((__attribute__((address_space(1))) void*)g,
                                   (__attribute__((address_space(3))) void*)l, 16, 0, 0);
}

// ---------------- elementwise / small kernels ----------------

__global__ void rope_table_kernel(float* __restrict__ cosb, float* __restrict__ sinb) {
  int i = blockIdx.x * 256 + threadIdx.x;       // 2048*32 = 65536 items
  int t = i >> 5, fi = i & 31;
  float freq = exp2f(-(2.0f * (float)fi / 64.0f) * log2f(10000.0f));
  float ang = (float)t * freq;
  cosb[i] = cosf(ang);
  sinb[i] = sinf(ang);
}

__global__ void convert_bf16_kernel(const float* __restrict__ src, u16* __restrict__ dst, long n8) {
  long i = (long)blockIdx.x * 256 + threadIdx.x;
  long stride = (long)gridDim.x * 256;
  for (; i < n8; i += stride) {
    const float4* s = (const float4*)(src + i * 8);
    float4 a = s[0], b = s[1];
    u16x8 r;
    r[0] = f2bf(a.x); r[1] = f2bf(a.y); r[2] = f2bf(a.z); r[3] = f2bf(a.w);
    r[4] = f2bf(b.x); r[5] = f2bf(b.y); r[6] = f2bf(b.z); r[7] = f2bf(b.w);
    *(u16x8*)(dst + i * 8) = r;
  }
}

// src [R][C] fp32 -> dst bf16. rowMode: 0 -> dst row = c (plain transpose)
//   1 -> row = ((c>>6)<<7) | (c&63)        (gate cols interleaved at 64-granularity)
//   2 -> row = ((c>>6)<<7) | 64 | (c&63)   (up cols, partner rows)
__global__ __launch_bounds__(256) void transpose_bf16_kernel(const float* __restrict__ src0,
                                                             u16* __restrict__ dst0, int R, int C,
                                                             long srcStride, long dstStride,
                                                             int rowMode) {
  __shared__ float tile[32][33];
  const float* src = src0 + (size_t)blockIdx.z * srcStride;
  u16* dst = dst0 + (size_t)blockIdx.z * dstStride;
  int tx = threadIdx.x & 31, ty = threadIdx.x >> 5;  // 32 x 8
  int bx = blockIdx.x, by = blockIdx.y;
#pragma unroll
  for (int i = 0; i < 32; i += 8) {
    int r = by * 32 + ty + i, c = bx * 32 + tx;
    tile[ty + i][tx] = src[(size_t)r * C + c];
  }
  __syncthreads();
#pragma unroll
  for (int i = 0; i < 32; i += 8) {
    int c = bx * 32 + ty + i;   // source col
    int r = by * 32 + tx;       // source row -> dst col
    int drow = c;
    if (rowMode == 1) drow = ((c >> 6) << 7) | (c & 63);
    else if (rowMode == 2) drow = ((c >> 6) << 7) | 64 | (c & 63);
    dst[(size_t)drow * R + r] = f2bf(tile[tx][ty + i]);
  }
}

__global__ void embed_gather_kernel(const int* __restrict__ idx, const float* __restrict__ embed,
                                    float* __restrict__ x) {
  int t = blockIdx.x;
  int id = idx[t];
  ((float4*)x)[(size_t)t * 256 + threadIdx.x] = ((const float4*)embed)[(size_t)id * 256 + threadIdx.x];
}

// x fp32 [4096][1024] -> h bf16, h = x * rsqrt(mean(x^2)+eps) * w
__global__ __launch_bounds__(256) void rmsnorm_kernel(const float* __restrict__ x,
                                                      const float* __restrict__ w,
                                                      u16* __restrict__ h) {
  int row = blockIdx.x;
  const float4* xr = (const float4*)(x + (size_t)row * D_MODEL);
  float4 v = xr[threadIdx.x];
  float ss = v.x * v.x + v.y * v.y + v.z * v.z + v.w * v.w;
#pragma unroll
  for (int m = 32; m > 0; m >>= 1) ss += __shfl_xor(ss, m, 64);
  __shared__ float wsum[4];
  if ((threadIdx.x & 63) == 0) wsum[threadIdx.x >> 6] = ss;
  __syncthreads();
  float tot = wsum[0] + wsum[1] + wsum[2] + wsum[3];
  float rinv = rsqrtf(tot * (1.0f / (float)D_MODEL) + 1e-6f);
  float4 wv = ((const float4*)w)[threadIdx.x];
  u16 out[4];
  out[0] = f2bf(v.x * rinv * wv.x);
  out[1] = f2bf(v.y * rinv * wv.y);
  out[2] = f2bf(v.z * rinv * wv.z);
  out[3] = f2bf(v.w * rinv * wv.w);
  u16* hp = h + (size_t)row * D_MODEL + threadIdx.x * 4;
  hp[0] = out[0]; hp[1] = out[1]; hp[2] = out[2]; hp[3] = out[3];
}

// V (in QKV buffer) -> Vt [bh][64 d][TSEQ t] bf16, tile-transposed via LDS.
// grid: (32 t-tiles, 32 bh), 256 threads.
__global__ __launch_bounds__(256) void vtrans_kernel(const u16* __restrict__ qkv,
                                                     u16* __restrict__ vt) {
  __shared__ u16 lds[64 * 64];
  const int tid = threadIdx.x;
  const int bh = blockIdx.y, tt = blockIdx.x;
  const int b = bh >> 4, h = bh & 15;
  const int tok0 = b * TSEQ + tt * 64;
  const int hoff = 2 * D_MODEL + h * HDIM;
#pragma unroll
  for (int it = 0; it < 2; it++) {
    int idx = it * 256 + tid;
    int row = idx >> 3, c = (idx & 7) * 8;   // row = t-local, c = d base
    short8 v = *(const short8*)(qkv + (size_t)(tok0 + row) * QKV_STRIDE + hoff + c);
    *(short8*)&lds[row * 64 + (c ^ ((row & 7) << 3))] = v;
  }
  __syncthreads();
#pragma unroll
  for (int it = 0; it < 2; it++) {
    int idx = it * 256 + tid;
    int d = idx >> 3, t0 = (idx & 7) * 8;
    u16x8 pk;
#pragma unroll
    for (int j = 0; j < 8; j++) {
      int t = t0 + j;
      pk[j] = lds[t * 64 + (((d & ~7) ^ ((t & 7) << 3)) | (d & 7))];
    }
    *(u16x8*)(vt + ((size_t)bh * 64 + d) * TSEQ + tt * 64 + t0) = pk;
  }
}

// ---------------- GEMM 128x128 (m97 structure, both-sides swizzle, 4 blocks/CU) ----
// C[M,N] = A[M,K](bf16) * B[N,K](bf16)^T. 256 threads = 4 waves (2x2).
// bn-chunked; within a chunk, bm-FAST XCD-local order: bm = xcd*nbmx + s2%nbmx,
// bn = s2/nbmx -> the nbmx blocks sharing a B-panel are dispatch-adjacent on one
// XCD, so one L2 fill serves all of them. Requires nbm % 8 == 0 (nbm = 32 here).
// EPI: 0 = fp32 nontemporal store + per-(row,64col) LSE partials (lm-head)
//      1 = bf16 store
//      2 = fp32 residual add (o-proj / down-proj)
//      4 = bf16 store with fused RoPE on cols < 2048 (QKV)
//      5 = fused silu-mul (B rows 64-col-interleaved gate/up; LDS exchange)
template <int EPI>
__global__ __launch_bounds__(256, 4) void gemm128_kernel(const u16* __restrict__ A,
                                                         const u16* __restrict__ B, void* Cp,
                                                         const float* __restrict__ resid,
                                                         float* __restrict__ partM,
                                                         float* __restrict__ partS,
                                                         const float* __restrict__ cosb,
                                                         const float* __restrict__ sinb,
                                                         int M, int N, int K, int chunkBn) {
  __shared__ __align__(16) u16 smem_ab[2][128 * 64];   // 32 KiB total
  u16* As = smem_ab[0];
  u16* Bs = smem_ab[1];
  const int tid = threadIdx.x;
  const int lane = tid & 63, wid = tid >> 6;
  const int wr = wid >> 1, wc = wid & 1;
  const int q = lane >> 4, l15 = lane & 15;
  const int nbm = M >> 7;
  const int nbmx = nbm >> 3;               // bm rows per XCD (4)
  const int cs = nbm * chunkBn;            // blocks per chunk
  const int chunk = (int)blockIdx.x / cs;
  const int r0 = (int)blockIdx.x - chunk * cs;
  const int s2 = r0 >> 3;
  const int bm = (r0 & 7) * nbmx + (s2 % nbmx);
  const int bn = chunk * chunkBn + (s2 / nbmx);
  const size_t abase = (size_t)bm * 128 * K;
  const size_t bbase = (size_t)bn * 128 * K;
  f32x4 acc[4][4] = {};
  for (int k0 = 0; k0 < K; k0 += 64) {
#pragma unroll
    for (int i = 0; i < 4; i++) {
      int idx8 = i * 256 + tid;
      int row = idx8 >> 3, ch = idx8 & 7;
      int sc = (ch ^ (row & 7)) << 3;
      gload_lds16(A + abase + (size_t)row * K + k0 + sc, As + idx8 * 8);
      gload_lds16(B + bbase + (size_t)row * K + k0 + sc, Bs + idx8 * 8);
    }
    __syncthreads();
#pragma unroll
    for (int ks = 0; ks < 2; ks++) {
      short8 af[4], bfr[4];
      int chunkc = ks * 4 + q;
#pragma unroll
      for (int mi = 0; mi < 4; mi++) {
        int row = wr * 64 + mi * 16 + l15;
        af[mi] = *(const short8*)&As[row * 64 + ((chunkc ^ (row & 7)) << 3)];
      }
#pragma unroll
      for (int ni = 0; ni < 4; ni++) {
        int row = wc * 64 + ni * 16 + l15;
        bfr[ni] = *(const short8*)&Bs[row * 64 + ((chunkc ^ (row & 7)) << 3)];
      }
#pragma unroll
      for (int mi = 0; mi < 4; mi++)
#pragma unroll
        for (int ni = 0; ni < 4; ni++)
          acc[mi][ni] = __builtin_amdgcn_mfma_f32_16x16x32_bf16(af[mi], bfr[ni], acc[mi][ni], 0, 0, 0);
    }
    __syncthreads();
  }

  // ---- EPI 5: fused silu-mul via cross-wave LDS exchange ----
  if (EPI == 5) {
    float* upf = (float*)&smem_ab[0][0];   // 128x64 floats = 32 KiB (reuses As+Bs)
    if (wc == 1) {
#pragma unroll
      for (int mi = 0; mi < 4; mi++)
#pragma unroll
        for (int ni = 0; ni < 4; ni++)
#pragma unroll
          for (int j = 0; j < 4; j++) {
            int r = wr * 64 + mi * 16 + q * 4 + j;
            int cswz = (ni ^ ((r >> 2) & 3)) * 16 + l15;   // bank-spread across q
            upf[r * 64 + cswz] = acc[mi][ni][j];
          }
    }
    __syncthreads();
    if (wc == 0) {
#pragma unroll
      for (int mi = 0; mi < 4; mi++)
#pragma unroll
        for (int j = 0; j < 4; j++) {
          int rloc = wr * 64 + mi * 16 + q * 4 + j;
          int rr = bm * 128 + rloc;
#pragma unroll
          for (int ni = 0; ni < 4; ni++) {
            int cswz = (ni ^ ((rloc >> 2) & 3)) * 16 + l15;
            float g = acc[mi][ni][j];
            float u = upf[rloc * 64 + cswz];
            float rsl = g / (1.0f + expf(-g)) * u;
            ((u16*)Cp)[(size_t)rr * (N >> 1) + bn * 64 + ni * 16 + l15] = f2bf(rsl);
          }
        }
    }
    return;
  }

  // ---- standard epilogues ----
#pragma unroll
  for (int mi = 0; mi < 4; mi++)
#pragma unroll
    for (int j = 0; j < 4; j++) {
      int rr = bm * 128 + wr * 64 + mi * 16 + q * 4 + j;
      float vv[4];
#pragma unroll
      for (int ni = 0; ni < 4; ni++) vv[ni] = acc[mi][ni][j];
      if (EPI == 0) {
        float mx = fmaxf(fmaxf(vv[0], vv[1]), fmaxf(vv[2], vv[3]));
        mx = fmaxf(mx, __shfl_xor(mx, 1, 64));
        mx = fmaxf(mx, __shfl_xor(mx, 2, 64));
        mx = fmaxf(mx, __shfl_xor(mx, 4, 64));
        mx = fmaxf(mx, __shfl_xor(mx, 8, 64));
        float sm = 0.f;
#pragma unroll
        for (int ni = 0; ni < 4; ni++) sm += expf(vv[ni] - mx);
        sm += __shfl_xor(sm, 1, 64);
        sm += __shfl_xor(sm, 2, 64);
        sm += __shfl_xor(sm, 4, 64);
        sm += __shfl_xor(sm, 8, 64);
        if (l15 == 0) {
          int nt = (N >> 6);
          partM[(size_t)rr * nt + (bn << 1) + wc] = mx;
          partS[(size_t)rr * nt + (bn << 1) + wc] = sm;
        }
      }
      if (EPI == 4) {
        // RoPE for Q (cols 0..1023) and K (1024..2047); V untouched.
        if (((bn << 1) + wc) < 32) {   // wave-uniform
          int t = rr & (TSEQ - 1);
#pragma unroll
          for (int ni = 0; ni < 2; ni++) {
            int fi = ni * 16 + l15;
            float c = cosb[t * 32 + fi], s = sinb[t * 32 + fi];
            float x1 = vv[ni], x2 = vv[ni + 2];
            vv[ni] = x1 * c - x2 * s;
            vv[ni + 2] = x2 * c + x1 * s;
          }
        }
      }
#pragma unroll
      for (int ni = 0; ni < 4; ni++) {
        int cn = bn * 128 + wc * 64 + ni * 16 + l15;
        size_t off = (size_t)rr * N + cn;
        if (EPI == 0) {
          __builtin_nontemporal_store(vv[ni], (float*)Cp + off);
        } else if (EPI == 1 || EPI == 4) {
          ((u16*)Cp)[off] = f2bf(vv[ni]);
        } else if (EPI == 2) {
          ((float*)Cp)[off] = resid[off] + vv[ni];
        }
      }
    }
}

// ---------------- flash attention ----------------
// q/k live in the fused QKV buffer (row stride 3072), POST-rope; V^T precomputed
// in vt [bh][64 d][TSEQ]. K and V^T tiles staged via global_load_lds with
// pre-swizzled per-lane source + linear LDS dest (both-sides rule).
// grid: (qtile 0..15, bh 0..31), block 256 (4 waves x 32 q-rows)
__global__ __launch_bounds__(256) void attn_kernel(const u16* __restrict__ qkv,
                                                   const u16* __restrict__ vt,
                                                   u16* __restrict__ o) {
  __shared__ __align__(16) u16 Ks[64 * 64];
  __shared__ __align__(16) u16 Vt[64 * 64];
  __shared__ u16 Ps[4][32 * 64];
  const u16* q = qkv;
  const u16* k = qkv + D_MODEL;
  const int tid = threadIdx.x, lane = tid & 63, wid = tid >> 6;
  const int qg = lane >> 4, l15 = lane & 15;
  const int qt = blockIdx.x;
  const int bh = blockIdx.y;
  const int b = bh >> 4, h = bh & 15;
  const int tok0 = b * TSEQ;
  const int hoff = h * HDIM;
  const int qrow0 = qt * 128 + wid * 32;
  const u16* vtb = vt + (size_t)bh * 64 * TSEQ;

  short8 aq[2][2];
#pragma unroll
  for (int mi = 0; mi < 2; mi++)
#pragma unroll
    for (int ks = 0; ks < 2; ks++) {
      int r = qrow0 + mi * 16 + l15;
      int d = ks * 32 + qg * 8;
      aq[mi][ks] = *(const short8*)(q + (size_t)(tok0 + r) * QKV_STRIDE + hoff + d);
    }
  f32x4 oacc[2][4] = {};
  float mrow[2][4], lrow[2][4];
#pragma unroll
  for (int mi = 0; mi < 2; mi++)
#pragma unroll
    for (int j = 0; j < 4; j++) { mrow[mi][j] = -1e30f; lrow[mi][j] = 0.f; }

  const int nkt = (qt + 1) * 2;
  for (int kt = 0; kt < nkt; kt++) {
    const int kv0 = kt * 64;
    // stage K [64 t][64 d] and V^T [64 d][64 t] via global_load_lds (pre-swizzled src)
#pragma unroll
    for (int it = 0; it < 2; it++) {
      int idx = it * 256 + tid;
      int row = idx >> 3, ch = idx & 7;
      int sc = (ch ^ (row & 7)) << 3;
      gload_lds16(k + (size_t)(tok0 + kv0 + row) * QKV_STRIDE + hoff + sc, Ks + idx * 8);
      gload_lds16(vtb + (size_t)row * TSEQ + kv0 + sc, Vt + idx * 8);
    }
    __syncthreads();
    f32x4 sc[2][4] = {};
#pragma unroll
    for (int ks = 0; ks < 2; ks++) {
      short8 bk[4];
      int kcol = ks * 32 + qg * 8;
#pragma unroll
      for (int ni = 0; ni < 4; ni++) {
        int r = ni * 16 + l15;
        bk[ni] = *(const short8*)&Ks[r * 64 + (kcol ^ ((r & 7) << 3))];
      }
#pragma unroll
      for (int mi = 0; mi < 2; mi++)
#pragma unroll
        for (int ni = 0; ni < 4; ni++)
          sc[mi][ni] = __builtin_amdgcn_mfma_f32_16x16x32_bf16(aq[mi][ks], bk[ni], sc[mi][ni], 0, 0, 0);
    }
    float pm[2][4];
#pragma unroll
    for (int mi = 0; mi < 2; mi++)
#pragma unroll
      for (int j = 0; j < 4; j++) pm[mi][j] = -1e30f;
#pragma unroll
    for (int mi = 0; mi < 2; mi++)
#pragma unroll
      for (int ni = 0; ni < 4; ni++)
#pragma unroll
        for (int j = 0; j < 4; j++) {
          int rq = qrow0 + mi * 16 + qg * 4 + j;
          int ck = kv0 + ni * 16 + l15;
          float s = sc[mi][ni][j] * 0.125f;
          if (ck > rq) s = -1e30f;
          sc[mi][ni][j] = s;
          pm[mi][j] = fmaxf(pm[mi][j], s);
        }
#pragma unroll
    for (int mi = 0; mi < 2; mi++)
#pragma unroll
      for (int j = 0; j < 4; j++) {
        float t = pm[mi][j];
        t = fmaxf(t, __shfl_xor(t, 1, 64));
        t = fmaxf(t, __shfl_xor(t, 2, 64));
        t = fmaxf(t, __shfl_xor(t, 4, 64));
        t = fmaxf(t, __shfl_xor(t, 8, 64));
        pm[mi][j] = t;
      }
#pragma unroll
    for (int mi = 0; mi < 2; mi++)
#pragma unroll
      for (int j = 0; j < 4; j++) {
        float mn = fmaxf(mrow[mi][j], pm[mi][j]);
        float fac = expf(mrow[mi][j] - mn);
        lrow[mi][j] *= fac;
#pragma unroll
        for (int df = 0; df < 4; df++) oacc[mi][df][j] *= fac;
        mrow[mi][j] = mn;
      }
    float psum[2][4] = {};
#pragma unroll
    for (int mi = 0; mi < 2; mi++)
#pragma unroll
      for (int ni = 0; ni < 4; ni++)
#pragma unroll
        for (int j = 0; j < 4; j++) {
          float p = expf(sc[mi][ni][j] - mrow[mi][j]);
          psum[mi][j] += p;
          int r32 = mi * 16 + qg * 4 + j;
          int cc = ni * 16 + l15;
          Ps[wid][r32 * 64 + (cc ^ ((r32 & 7) << 3))] = f2bf(p);
        }
#pragma unroll
    for (int mi = 0; mi < 2; mi++)
#pragma unroll
      for (int j = 0; j < 4; j++) {
        float t = psum[mi][j];
        t += __shfl_xor(t, 1, 64);
        t += __shfl_xor(t, 2, 64);
        t += __shfl_xor(t, 4, 64);
        t += __shfl_xor(t, 8, 64);
        lrow[mi][j] += t;
      }
#pragma unroll
    for (int kf = 0; kf < 2; kf++) {
      short8 pa[2], bv[4];
      int kcol = kf * 32 + qg * 8;
#pragma unroll
      for (int mi = 0; mi < 2; mi++) {
        int r = mi * 16 + l15;
        pa[mi] = *(const short8*)&Ps[wid][r * 64 + (kcol ^ ((r & 7) << 3))];
      }
#pragma unroll
      for (int df = 0; df < 4; df++) {
        int r = df * 16 + l15;
        bv[df] = *(const short8*)&Vt[r * 64 + (kcol ^ ((r & 7) << 3))];
      }
#pragma unroll
      for (int mi = 0; mi < 2; mi++)
#pragma unroll
        for (int df = 0; df < 4; df++)
          oacc[mi][df] = __builtin_amdgcn_mfma_f32_16x16x32_bf16(pa[mi], bv[df], oacc[mi][df], 0, 0, 0);
    }
    __syncthreads();
  }
#pragma unroll
  for (int mi = 0; mi < 2; mi++)
#pragma unroll
    for (int df = 0; df < 4; df++)
#pragma unroll
      for (int j = 0; j < 4; j++) {
        int r = qrow0 + mi * 16 + qg * 4 + j;
        int d = df * 16 + l15;
        float val = oacc[mi][df][j] / lrow[mi][j];
        o[(size_t)(tok0 + r) * D_MODEL + hoff + d] = f2bf(val);
      }
}

// ---------------- loss ----------------

__global__ void nll_finalize_kernel(const float* __restrict__ partM, const float* __restrict__ partS,
                                    const float* __restrict__ logits, const int* __restrict__ targets,
                                    float* __restrict__ nll) {
  int tok = blockIdx.x;
  int lane = threadIdx.x;    // 64
  const int NTL = V_SIZE >> 6;  // 500
  float m = -1e30f, s = 0.f;
  for (int i = lane; i < NTL; i += 64) {
    float m2 = partM[(size_t)tok * NTL + i];
    float s2 = partS[(size_t)tok * NTL + i];
    float nm = fmaxf(m, m2);
    s = s * expf(m - nm) + s2 * expf(m2 - nm);
    m = nm;
  }
#pragma unroll
  for (int mask = 1; mask < 64; mask <<= 1) {
    float m2 = __shfl_xor(m, mask, 64);
    float s2 = __shfl_xor(s, mask, 64);
    float nm = fmaxf(m, m2);
    s = s * expf(m - nm) + s2 * expf(m2 - nm);
    m = nm;
  }
  if (lane == 0)
    nll[tok] = m + logf(s) - logits[(size_t)tok * V_SIZE + targets[tok]];
}

__global__ void loss_reduce_kernel(const float* __restrict__ nll, float* __restrict__ out) {
  float s = 0.f;
  for (int i = threadIdx.x; i < BT; i += 256) s += nll[i];
#pragma unroll
  for (int mask = 1; mask < 64; mask <<= 1) s += __shfl_xor(s, mask, 64);
  __shared__ float sm[4];
  if ((threadIdx.x & 63) == 0) sm[threadIdx.x >> 6] = s;
  __syncthreads();
  if (threadIdx.x == 0) out[0] = (sm[0] + sm[1] + sm[2] + sm[3]) / (float)BT;
}

// ---------------- host launcher ----------------

extern "C" void kernel_launch(void* const* d_in, const int* in_sizes, int n_in,
                              void* d_out, int out_size, void* d_ws, size_t ws_size,
                              hipStream_t stream) {
  const int* idx = (const int*)d_in[0];
  const int* targets = (const int*)d_in[1];
  const float* embed = (const float*)d_in[2];
  const float* wq = (const float*)d_in[3];
  const float* wk = (const float*)d_in[4];
  const float* wv = (const float*)d_in[5];
  const float* wo = (const float*)d_in[6];
  const float* w_gate = (const float*)d_in[7];
  const float* w_up = (const float*)d_in[8];
  const float* w_down = (const float*)d_in[9];
  const float* attn_norm = (const float*)d_in[10];
  const float* mlp_norm = (const float*)d_in[11];
  const float* final_norm = (const float*)d_in[12];
  const float* lm_head = (const float*)d_in[13];
  float* out = (float*)d_out;

  char* ws = (char*)d_ws;
  size_t off = 0;
  auto alloc = [&](size_t bytes) {
    void* p = ws + off;
    off += (bytes + 255) & ~(size_t)255;
    return p;
  };
  const size_t DD = (size_t)D_MODEL * D_MODEL;
  float* rope_cos = (float*)alloc((size_t)TSEQ * 32 * 4);
  float* rope_sin = (float*)alloc((size_t)TSEQ * 32 * 4);
  float* X = (float*)alloc((size_t)BT * D_MODEL * 4);
  u16* Hb = (u16*)alloc((size_t)BT * D_MODEL * 2);
  u16* QKVb = (u16*)alloc((size_t)BT * QKV_STRIDE * 2);
  u16* Vtb = (u16*)alloc((size_t)32 * 64 * TSEQ * 2);
  u16* Ob = (u16*)alloc((size_t)BT * D_MODEL * 2);
  u16* Gb = (u16*)alloc((size_t)BT * HFF * 2);
  u16* WQKVT = (u16*)alloc((size_t)NLAYER * QKV_STRIDE * D_MODEL * 2);
  u16* WOT = (u16*)alloc((size_t)NLAYER * DD * 2);
  u16* WGU = (u16*)alloc((size_t)NLAYER * GU_STRIDE * D_MODEL * 2);
  u16* WDT = (u16*)alloc((size_t)NLAYER * D_MODEL * HFF * 2);
  u16* LMH = (u16*)alloc((size_t)V_SIZE * D_MODEL * 2);
  float* NLLb = (float*)alloc((size_t)BT * 4);
  float* PartM = (float*)alloc((size_t)BT * (V_SIZE >> 6) * 4);
  float* PartS = (float*)alloc((size_t)BT * (V_SIZE >> 6) * 4);

  rope_table_kernel<<<256, 256, 0, stream>>>(rope_cos, rope_sin);
  convert_bf16_kernel<<<4096, 256, 0, stream>>>(lm_head, LMH, (long)V_SIZE * D_MODEL / 8);
  embed_gather_kernel<<<BT, 256, 0, stream>>>(idx, embed, X);

  const long QKVW = (long)QKV_STRIDE * D_MODEL;
  const long GUW = (long)GU_STRIDE * D_MODEL;
  const long DW = (long)D_MODEL * HFF;
  transpose_bf16_kernel<<<dim3(32, 32, NLAYER), 256, 0, stream>>>(wq, WQKVT, D_MODEL, D_MODEL, DD, QKVW, 0);
  transpose_bf16_kernel<<<dim3(32, 32, NLAYER), 256, 0, stream>>>(wk, WQKVT + DD, D_MODEL, D_MODEL, DD, QKVW, 0);
  transpose_bf16_kernel<<<dim3(32, 32, NLAYER), 256, 0, stream>>>(wv, WQKVT + 2 * DD, D_MODEL, D_MODEL, DD, QKVW, 0);
  transpose_bf16_kernel<<<dim3(32, 32, NLAYER), 256, 0, stream>>>(wo, WOT, D_MODEL, D_MODEL, DD, DD, 0);
  // gate/up interleaved at 64-col granularity: rows [128g..128g+63]=gate, [+64..+127]=up
  transpose_bf16_kernel<<<dim3(128, 32, NLAYER), 256, 0, stream>>>(w_gate, WGU, D_MODEL, HFF, DW, GUW, 1);
  transpose_bf16_kernel<<<dim3(128, 32, NLAYER), 256, 0, stream>>>(w_up, WGU, D_MODEL, HFF, DW, GUW, 2);
  transpose_bf16_kernel<<<dim3(32, 128, NLAYER), 256, 0, stream>>>(w_down, WDT, HFF, D_MODEL, DW, DW, 0);

  for (int l = 0; l < NLAYER; l++) {
    rmsnorm_kernel<<<BT, 256, 0, stream>>>(X, attn_norm + (size_t)l * D_MODEL, Hb);
    gemm128_kernel<4><<<(QKV_STRIDE / 128) * (BT / 128), 256, 0, stream>>>(
        Hb, WQKVT + (size_t)l * QKVW, QKVb, nullptr, nullptr, nullptr, rope_cos, rope_sin,
        BT, QKV_STRIDE, D_MODEL, QKV_STRIDE / 128);
    vtrans_kernel<<<dim3(32, 32), 256, 0, stream>>>(QKVb, Vtb);
    attn_kernel<<<dim3(16, 32), 256, 0, stream>>>(QKVb, Vtb, Ob);
    gemm128_kernel<2><<<(D_MODEL / 128) * (BT / 128), 256, 0, stream>>>(
        Ob, WOT + (size_t)l * DD, X, X, nullptr, nullptr, nullptr, nullptr,
        BT, D_MODEL, D_MODEL, D_MODEL / 128);

    rmsnorm_kernel<<<BT, 256, 0, stream>>>(X, mlp_norm + (size_t)l * D_MODEL, Hb);
    gemm128_kernel<5><<<(GU_STRIDE / 128) * (BT / 128), 256, 0, stream>>>(
        Hb, WGU + (size_t)l * GUW, Gb, nullptr, nullptr, nullptr, nullptr, nullptr,
        BT, GU_STRIDE, D_MODEL, 32);
    gemm128_kernel<2><<<(D_MODEL / 128) * (BT / 128), 256, 0, stream>>>(
        Gb, WDT + (size_t)l * DW, X, X, nullptr, nullptr, nullptr, nullptr,
        BT, D_MODEL, HFF, D_MODEL / 128);
  }

  rmsnorm_kernel<<<BT, 256, 0, stream>>>(X, final_norm, Hb);
  gemm128_kernel<0><<<(V_SIZE / 128) * (BT / 128), 256, 0, stream>>>(
      Hb, LMH, out, nullptr, PartM, PartS, nullptr, nullptr,
      BT, V_SIZE, D_MODEL, 50);
  nll_finalize_kernel<<<BT, 64, 0, stream>>>(PartM, PartS, out, targets, NLLb);
  loss_reduce_kernel<<<1, 256, 0, stream>>>(NLLb, out + (size_t)BT * V_SIZE);
}